// Round 5
// baseline (747.633 us; speedup 1.0000x reference)
//
#include <hip/hip_runtime.h>

typedef __attribute__((ext_vector_type(8))) short short8;
typedef __attribute__((ext_vector_type(4))) float f32x4;

#define BB 8
#define TT 1024
#define NN 64
#define HH 8
#define LL 2
#define KSS 3
#define DD1 64
#define EPSV 1e-6f

#define MFMA16(a, b, c) __builtin_amdgcn_mfma_f32_16x16x32_bf16(a, b, c, 0, 0, 0)
#define BAR() __builtin_amdgcn_s_barrier()
#define WAIT_VM8() asm volatile("s_waitcnt vmcnt(8)" ::: "memory")
#define WAIT_VM4() asm volatile("s_waitcnt vmcnt(4)" ::: "memory")
#define WAIT_VM0() asm volatile("s_waitcnt vmcnt(0)" ::: "memory")
#define WAIT_LGKM0() asm volatile("s_waitcnt lgkmcnt(0)" ::: "memory")

// ---- truncation-based hi/lo bf16 split (hi error lands exactly in lo) ----
__device__ __forceinline__ void split1(float x, ushort& hi, ushort& lo) {
  uint u = __float_as_uint(x);
  hi = (ushort)(u >> 16);
  float hf = __uint_as_float(u & 0xffff0000u);
  lo = (ushort)(__float_as_uint(x - hf) >> 16);
}
__device__ __forceinline__ uint pack2(float a, float b, uint& lo) {
  uint ua = __float_as_uint(a), ub = __float_as_uint(b);
  float ra = __uint_as_float(ua & 0xffff0000u);
  float rb = __uint_as_float(ub & 0xffff0000u);
  lo = (__float_as_uint(a - ra) >> 16) | (__float_as_uint(b - rb) & 0xffff0000u);
  return (ua >> 16) | (ub & 0xffff0000u);
}

// ---- async global->LDS staging of a 64x64 bf16 tile, swizzled via source ----
__device__ __forceinline__ void gl2lds16(const ushort* g, ushort* l) {
  __builtin_amdgcn_global_load_lds(
      (const __attribute__((address_space(1))) void*)g,
      (__attribute__((address_space(3))) void*)l, 16, 0, 0);
}
// LDS[row][ch] = G[row][ch ^ (row&7)] (16B chunks); 2 gl_lds per wave
__device__ __forceinline__ void stage_async(ushort* __restrict__ s,
                                            const ushort* __restrict__ g,
                                            int stride, int tid) {
  int w = tid >> 6;
  int sub = (tid & 63) >> 3, c = tid & 7;
#pragma unroll
  for (int i = 0; i < 2; ++i) {
    int rb = (i * 4 + w) * 8;
    gl2lds16(g + (size_t)(rb + sub) * stride + ((c ^ sub) << 3), s + rb * 64);
  }
}
__device__ __forceinline__ short8 frag(const ushort* __restrict__ s, int row, int ch) {
  return *(const short8*)(s + row * 64 + ((ch ^ (row & 7)) << 3));
}

// ---------- small kernels ----------

__global__ void k_addpos(const float* __restrict__ in, const float* __restrict__ pe,
                         float* __restrict__ x, int total) {
  int idx = blockIdx.x * 256 + threadIdx.x;
  if (idx < total) {
    int tn = idx & (TT * NN - 1);
    x[idx] = in[idx] + pe[tn];
  }
}

__global__ void k_k3s(const float* __restrict__ K3, const float* __restrict__ sclwl,
                      float* __restrict__ K3s) {
  int idx = blockIdx.x * 256 + threadIdx.x;
  int n = idx >> 6, m = idx & 63;
  K3s[idx] = K3[n * 192 + m] * sclwl[0] + K3[n * 192 + 64 + m] * sclwl[1] +
             K3[n * 192 + 128 + m] * sclwl[2];
}

// transpose+split: src [mat][1024][64] f32 -> dh/dl [mat][64][1024] bf16 hi/lo
__global__ __launch_bounds__(256) void k_tsplit(const float* __restrict__ src,
                                                ushort* __restrict__ dh,
                                                ushort* __restrict__ dl) {
  __shared__ float st[64][65];
  int blk = blockIdx.x;
  int mat = blk >> 4, rt = blk & 15;
  int tid = threadIdx.x;
  size_t sbase = ((size_t)mat * TT + rt * 64) * 64;
#pragma unroll
  for (int i = 0; i < 4; ++i) {
    int idx = tid + i * 256;
    int r = idx >> 4, c4 = idx & 15;
    float4 v = *(const float4*)(src + sbase + r * 64 + c4 * 4);
    st[r][c4 * 4 + 0] = v.x; st[r][c4 * 4 + 1] = v.y;
    st[r][c4 * 4 + 2] = v.z; st[r][c4 * 4 + 3] = v.w;
  }
  __syncthreads();
  size_t obase = (size_t)mat * (64 * (size_t)TT) + rt * 64;
#pragma unroll
  for (int i = 0; i < 2; ++i) {
    int idx = tid + i * 256;
    int n = idx >> 3, c = idx & 7;
    uint hw[4], lw[4];
#pragma unroll
    for (int j = 0; j < 4; ++j) hw[j] = pack2(st[c * 8 + 2 * j][n], st[c * 8 + 2 * j + 1][n], lw[j]);
    *(uint4*)(dh + obase + (size_t)n * TT + c * 8) = make_uint4(hw[0], hw[1], hw[2], hw[3]);
    *(uint4*)(dl + obase + (size_t)n * TT + c * 8) = make_uint4(lw[0], lw[1], lw[2], lw[3]);
  }
}

// transpose+split Wlt: [L][512][64] f32 -> [L][64][512] bf16 hi/lo
__global__ __launch_bounds__(256) void k_tsplitW(const float* __restrict__ Wlt,
                                                 ushort* __restrict__ dh,
                                                 ushort* __restrict__ dl) {
  __shared__ float st[64][65];
  int blk = blockIdx.x;
  int l = blk >> 3, rt = blk & 7;
  int tid = threadIdx.x;
  size_t sbase = ((size_t)l * 512 + rt * 64) * 64;
#pragma unroll
  for (int i = 0; i < 4; ++i) {
    int idx = tid + i * 256;
    int r = idx >> 4, c4 = idx & 15;
    float4 v = *(const float4*)(Wlt + sbase + r * 64 + c4 * 4);
    st[r][c4 * 4 + 0] = v.x; st[r][c4 * 4 + 1] = v.y;
    st[r][c4 * 4 + 2] = v.z; st[r][c4 * 4 + 3] = v.w;
  }
  __syncthreads();
  size_t obase = (size_t)l * 64 * 512 + rt * 64;
#pragma unroll
  for (int i = 0; i < 2; ++i) {
    int idx = tid + i * 256;
    int n = idx >> 3, c = idx & 7;
    uint hw[4], lw[4];
#pragma unroll
    for (int j = 0; j < 4; ++j) hw[j] = pack2(st[c * 8 + 2 * j][n], st[c * 8 + 2 * j + 1][n], lw[j]);
    *(uint4*)(dh + obase + (size_t)n * 512 + c * 8) = make_uint4(hw[0], hw[1], hw[2], hw[3]);
    *(uint4*)(dl + obase + (size_t)n * 512 + c * 8) = make_uint4(lw[0], lw[1], lw[2], lw[3]);
  }
}

// gconv: 256-thread blocks, K3 staged in LDS, 4 (b,t) rows per block
__global__ __launch_bounds__(256) void k_gconv(
    const float* __restrict__ x, const float* __restrict__ K3,
    const float* __restrict__ qwl, const float* __restrict__ qbl,
    const float* __restrict__ kwl, const float* __restrict__ kbl,
    const float* __restrict__ vwl, const float* __restrict__ vbl,
    ushort* __restrict__ xqh, ushort* __restrict__ xql,
    ushort* __restrict__ xkh, ushort* __restrict__ xkl, float* __restrict__ xv) {
  __shared__ float sK3[12288];
  __shared__ float sx[4][64];
  int tid = threadIdx.x;
  int w = tid >> 6, lane = tid & 63;
#pragma unroll
  for (int i = 0; i < 12; ++i)
    ((float4*)sK3)[tid + i * 256] = ((const float4*)K3)[tid + i * 256];
  size_t bt = (size_t)blockIdx.x * 4 + w;
  size_t b = bt >> 10, t = bt & 1023;
  float xm = x[bt * 64 + lane];
  sx[w][lane] = xm;
  __syncthreads();
  float a0 = 0.f, a1 = 0.f, a2 = 0.f;
#pragma unroll 8
  for (int n = 0; n < 64; ++n) {
    float xn = sx[w][n];
    a0 = fmaf(xn, sK3[n * 192 + lane], a0);
    a1 = fmaf(xn, sK3[n * 192 + 64 + lane], a1);
    a2 = fmaf(xn, sK3[n * 192 + 128 + lane], a2);
  }
#pragma unroll
  for (int hh = 0; hh < HH; ++hh) {
    size_t off = (((size_t)b * HH + hh) * TT + t) * 64 + lane;
    float q = fmaf(qwl[hh * 3 + 0], a0,
              fmaf(qwl[hh * 3 + 1], a1, fmaf(qwl[hh * 3 + 2], a2, qbl[hh] + xm)));
    q = fmaxf(q, 0.f) * 0.015625f;  // fold 1/N into Q
    ushort h_, l_;
    split1(q, h_, l_); xqh[off] = h_; xql[off] = l_;
    float k = fmaf(kwl[hh * 3 + 0], a0,
              fmaf(kwl[hh * 3 + 1], a1, fmaf(kwl[hh * 3 + 2], a2, kbl[hh] + xm)));
    k = fmaxf(k, 0.f);
    split1(k, h_, l_); xkh[off] = h_; xkl[off] = l_;
    float v = fmaf(vwl[hh * 3 + 0], a0,
              fmaf(vwl[hh * 3 + 1], a1, fmaf(vwl[hh * 3 + 2], a2, vbl[hh] + xm)));
    xv[off] = fmaxf(v, 0.f);
  }
}

// ---------- pass A: flash attention; Q direct-from-global, V async dbuf ----------
__global__ __launch_bounds__(256, 3) void k_attn(
    const ushort* __restrict__ xkh, const ushort* __restrict__ xkl,
    const ushort* __restrict__ xqh, const ushort* __restrict__ xql,
    const ushort* __restrict__ xvTh, const ushort* __restrict__ xvTl,
    float* __restrict__ auv, float* __restrict__ lse) {
  __shared__ ushort sVh[2][4096], sVl[2][4096], sPh[4096], sPl[4096];
  int tid = threadIdx.x;
  int lane = tid & 63, w = tid >> 6;
  int l15 = lane & 15, g = lane >> 4;
  int nb = gridDim.x, chunk = nb >> 3, bid = blockIdx.x;
  int blk = (bid & 7) * chunk + (bid >> 3);  // XCD swizzle (nb % 8 == 0)
  int bh = blk >> 4, t0 = (blk & 15) << 6;
  size_t bhTT = (size_t)bh * TT;
  int trow = 16 * w + l15, swz = trow & 7;

  // persistent K B-frags, direct from global (cols t = t0+trow)
  short8 fKh[2], fKl[2];
#pragma unroll
  for (int ks = 0; ks < 2; ++ks) {
    fKh[ks] = *(const short8*)(xkh + (bhTT + t0 + trow) * NN + (g + 4 * ks) * 8);
    fKl[ks] = *(const short8*)(xkl + (bhTT + t0 + trow) * NN + (g + 4 * ks) * 8);
  }
  // Q A-frags for tile 0, direct from global
  short8 qh[4][2], ql[4][2];
#pragma unroll
  for (int rt = 0; rt < 4; ++rt) {
    const ushort* qrh = xqh + (bhTT + 16 * rt + l15) * NN;
    const ushort* qrl = xql + (bhTT + 16 * rt + l15) * NN;
#pragma unroll
    for (int ks = 0; ks < 2; ++ks) {
      qh[rt][ks] = *(const short8*)(qrh + (g + 4 * ks) * 8);
      ql[rt][ks] = *(const short8*)(qrl + (g + 4 * ks) * 8);
    }
  }
  // V tiles 0,1 -> LDS dbuf (4 gl_lds per tile per wave)
  stage_async(sVh[0], xvTh + bhTT * NN, 1024, tid);
  stage_async(sVl[0], xvTl + bhTT * NN, 1024, tid);
  stage_async(sVh[1], xvTh + bhTT * NN + 64, 1024, tid);
  stage_async(sVl[1], xvTl + bhTT * NN + 64, 1024, tid);

  float m = -3.0e38f, lsum = 0.f;
  f32x4 O[4];
#pragma unroll
  for (int ct = 0; ct < 4; ++ct)
#pragma unroll
    for (int r = 0; r < 4; ++r) O[ct][r] = 0.f;

  for (int ut = 0; ut < 16; ++ut) {
    int cur = ut & 1;
    if (ut < 15) WAIT_VM4(); else WAIT_VM0();  // V[ut] + q landed; V[ut+1] may fly
    BAR();
    const ushort* cVh = sVh[cur];
    const ushort* cVl = sVl[cur];

    __builtin_amdgcn_s_setprio(1);
    f32x4 S[4];
#pragma unroll
    for (int rt = 0; rt < 4; ++rt) {
      f32x4 a = {0.f, 0.f, 0.f, 0.f};
#pragma unroll
      for (int ks = 0; ks < 2; ++ks) {
        a = MFMA16(qh[rt][ks], fKh[ks], a);
        a = MFMA16(qh[rt][ks], fKl[ks], a);
        a = MFMA16(ql[rt][ks], fKh[ks], a);
      }
      S[rt] = a;
    }
    __builtin_amdgcn_s_setprio(0);

    float tmax = S[0][0];
#pragma unroll
    for (int rt = 0; rt < 4; ++rt)
#pragma unroll
      for (int r = 0; r < 4; ++r) tmax = fmaxf(tmax, S[rt][r]);
    tmax = fmaxf(tmax, __shfl_xor(tmax, 16, 64));
    tmax = fmaxf(tmax, __shfl_xor(tmax, 32, 64));
    if (__ballot(tmax > m + 4.f)) {  // T13 deferred rescale
      float mnew = fmaxf(m, tmax);
      float f = __expf(m - mnew);
      float fr[4];
#pragma unroll
      for (int r = 0; r < 4; ++r) fr[r] = __shfl(f, (lane & 48) | (4 * g + r), 64);
#pragma unroll
      for (int ct = 0; ct < 4; ++ct)
#pragma unroll
        for (int r = 0; r < 4; ++r) O[ct][r] *= fr[r];
      lsum *= f;
      m = mnew;
    }
    float psum = 0.f;
    uint2 ph[4], plo[4];
#pragma unroll
    for (int rt = 0; rt < 4; ++rt) {
      float p0 = __expf(S[rt][0] - m), p1 = __expf(S[rt][1] - m);
      float p2 = __expf(S[rt][2] - m), p3 = __expf(S[rt][3] - m);
      psum += (p0 + p1) + (p2 + p3);
      uint lo0, lo1;
      ph[rt].x = pack2(p0, p1, lo0);
      ph[rt].y = pack2(p2, p3, lo1);
      plo[rt].x = lo0; plo[rt].y = lo1;
    }
    psum += __shfl_xor(psum, 16, 64);
    psum += __shfl_xor(psum, 32, 64);
    lsum += psum;
    // P' write (wave-local rows) then PV — same-wave DS ordering
#pragma unroll
    for (int rt = 0; rt < 4; ++rt) {
      int ch = 2 * rt + (g >> 1);
      int off = trow * 64 + ((ch ^ swz) << 3) + ((g & 1) << 2);
      *(uint2*)(sPh + off) = ph[rt];
      *(uint2*)(sPl + off) = plo[rt];
    }
    WAIT_LGKM0();
    __builtin_amdgcn_sched_barrier(0);
    __builtin_amdgcn_s_setprio(1);
#pragma unroll
    for (int ks = 0; ks < 2; ++ks) {
      short8 aPh = frag(sPh, trow, g + 4 * ks);
      short8 aPl = frag(sPl, trow, g + 4 * ks);
#pragma unroll
      for (int ct = 0; ct < 4; ++ct) {
        short8 bVh = frag(cVh, 16 * ct + l15, g + 4 * ks);
        short8 bVl = frag(cVl, 16 * ct + l15, g + 4 * ks);
        O[ct] = MFMA16(aPh, bVh, O[ct]);
        O[ct] = MFMA16(aPh, bVl, O[ct]);
        O[ct] = MFMA16(aPl, bVh, O[ct]);
      }
    }
    __builtin_amdgcn_s_setprio(0);
    // prefetch next Q tile into the (now dead) q regs — BEFORE the V stage
    if (ut < 15) {
#pragma unroll
      for (int rt = 0; rt < 4; ++rt) {
        const ushort* qrh = xqh + (bhTT + (ut + 1) * 64 + 16 * rt + l15) * NN;
        const ushort* qrl = xql + (bhTT + (ut + 1) * 64 + 16 * rt + l15) * NN;
#pragma unroll
        for (int ks = 0; ks < 2; ++ks) {
          qh[rt][ks] = *(const short8*)(qrh + (g + 4 * ks) * 8);
          ql[rt][ks] = *(const short8*)(qrl + (g + 4 * ks) * 8);
        }
      }
    }
    WAIT_LGKM0();
    BAR();  // all waves done reading V[cur]
    if (ut < 14) {
      int tn = ut + 2;
      stage_async(sVh[cur], xvTh + bhTT * NN + tn * 64, 1024, tid);
      stage_async(sVl[cur], xvTl + bhTT * NN + tn * 64, 1024, tid);
    }
  }
  float il = 1.0f / lsum;
  float ilr[4];
#pragma unroll
  for (int r = 0; r < 4; ++r) ilr[r] = __shfl(il, (lane & 48) | (4 * g + r), 64);
#pragma unroll
  for (int r = 0; r < 4; ++r) {
    size_t row = (bhTT + t0 + 16 * w + 4 * g + r) * NN;
#pragma unroll
    for (int ct = 0; ct < 4; ++ct) auv[row + 16 * ct + l15] = O[ct][r] * ilr[r];
  }
  if (g == 0) lse[bhTT + t0 + 16 * w + l15] = m + __logf(lsum);
}

// ---------- pass B: h1 = relu(P^T @ W1 + b1); K direct, W1 async dbuf ----------
__global__ __launch_bounds__(256, 3) void k_h1(
    const ushort* __restrict__ xkh, const ushort* __restrict__ xkl,
    const ushort* __restrict__ xqh, const ushort* __restrict__ xql,
    const ushort* __restrict__ w1Th, const ushort* __restrict__ w1Tl,
    const float* __restrict__ lse, const float* __restrict__ b1,
    float* __restrict__ h1) {
  __shared__ ushort sWh[2][4096], sWl[2][4096], sPh[4096], sPl[4096];
  __shared__ float sL[1024];
  int tid = threadIdx.x;
  int lane = tid & 63, w = tid >> 6;
  int l15 = lane & 15, g = lane >> 4;
  int nb = gridDim.x, chunk = nb >> 3, bid = blockIdx.x;
  int blk = (bid & 7) * chunk + (bid >> 3);
  int bh = blk >> 4, h = bh & (HH - 1), a0 = (blk & 15) << 6;
  size_t bhTT = (size_t)bh * TT;
  size_t wbase = (size_t)h * NN * TT;
  int arow = 16 * w + l15, swz = arow & 7;

  // persistent Q B-frags (cols a = a0+arow), direct from global
  short8 fQh[2], fQl[2];
#pragma unroll
  for (int ks = 0; ks < 2; ++ks) {
    fQh[ks] = *(const short8*)(xqh + (bhTT + a0 + arow) * NN + (g + 4 * ks) * 8);
    fQl[ks] = *(const short8*)(xql + (bhTT + a0 + arow) * NN + (g + 4 * ks) * 8);
  }
  // K A-frags tile 0
  short8 kh_[4][2], kl_[4][2];
#pragma unroll
  for (int rt = 0; rt < 4; ++rt) {
    const ushort* krh = xkh + (bhTT + 16 * rt + l15) * NN;
    const ushort* krl = xkl + (bhTT + 16 * rt + l15) * NN;
#pragma unroll
    for (int ks = 0; ks < 2; ++ks) {
      kh_[rt][ks] = *(const short8*)(krh + (g + 4 * ks) * 8);
      kl_[rt][ks] = *(const short8*)(krl + (g + 4 * ks) * 8);
    }
  }
  // lse table for whole bh
  for (int i = tid; i < 1024; i += 256) sL[i] = lse[bhTT + i];
  // W1 tiles 0,1
  stage_async(sWh[0], w1Th + wbase, 1024, tid);
  stage_async(sWl[0], w1Tl + wbase, 1024, tid);
  stage_async(sWh[1], w1Th + wbase + 64, 1024, tid);
  stage_async(sWl[1], w1Tl + wbase + 64, 1024, tid);
  WAIT_LGKM0();

  f32x4 acc[4];
#pragma unroll
  for (int ct = 0; ct < 4; ++ct)
#pragma unroll
    for (int r = 0; r < 4; ++r) acc[ct][r] = 0.f;

  for (int tt = 0; tt < 16; ++tt) {
    int cur = tt & 1;
    if (tt < 15) WAIT_VM4(); else WAIT_VM0();
    BAR();
    const ushort* cWh = sWh[cur];
    const ushort* cWl = sWl[cur];

    __builtin_amdgcn_s_setprio(1);
    f32x4 S[4];
#pragma unroll
    for (int rt = 0; rt < 4; ++rt) {
      f32x4 a = {0.f, 0.f, 0.f, 0.f};
#pragma unroll
      for (int ks = 0; ks < 2; ++ks) {
        a = MFMA16(kh_[rt][ks], fQh[ks], a);
        a = MFMA16(kh_[rt][ks], fQl[ks], a);
        a = MFMA16(kl_[rt][ks], fQh[ks], a);
      }
      S[rt] = a;
    }
    __builtin_amdgcn_s_setprio(0);

    uint2 ph[4], plo[4];
#pragma unroll
    for (int rt = 0; rt < 4; ++rt) {
      f32x4 lv = *(const f32x4*)(sL + tt * 64 + 16 * rt + 4 * g);
      float p0 = __expf(S[rt][0] - lv[0]);
      float p1 = __expf(S[rt][1] - lv[1]);
      float p2 = __expf(S[rt][2] - lv[2]);
      float p3 = __expf(S[rt][3] - lv[3]);
      uint lo0, lo1;
      ph[rt].x = pack2(p0, p1, lo0);
      ph[rt].y = pack2(p2, p3, lo1);
      plo[rt].x = lo0; plo[rt].y = lo1;
    }
#pragma unroll
    for (int rt = 0; rt < 4; ++rt) {
      int ch = 2 * rt + (g >> 1);
      int off = arow * 64 + ((ch ^ swz) << 3) + ((g & 1) << 2);
      *(uint2*)(sPh + off) = ph[rt];
      *(uint2*)(sPl + off) = plo[rt];
    }
    WAIT_LGKM0();
    __builtin_amdgcn_sched_barrier(0);
    __builtin_amdgcn_s_setprio(1);
#pragma unroll
    for (int ks = 0; ks < 2; ++ks) {
      short8 aPh = frag(sPh, arow, g + 4 * ks);
      short8 aPl = frag(sPl, arow, g + 4 * ks);
#pragma unroll
      for (int ct = 0; ct < 4; ++ct) {
        short8 bWh = frag(cWh, 16 * ct + l15, g + 4 * ks);
        short8 bWl = frag(cWl, 16 * ct + l15, g + 4 * ks);
        acc[ct] = MFMA16(aPh, bWh, acc[ct]);
        acc[ct] = MFMA16(aPh, bWl, acc[ct]);
        acc[ct] = MFMA16(aPl, bWh, acc[ct]);
      }
    }
    __builtin_amdgcn_s_setprio(0);
    if (tt < 15) {
#pragma unroll
      for (int rt = 0; rt < 4; ++rt) {
        const ushort* krh = xkh + (bhTT + (tt + 1) * 64 + 16 * rt + l15) * NN;
        const ushort* krl = xkl + (bhTT + (tt + 1) * 64 + 16 * rt + l15) * NN;
#pragma unroll
        for (int ks = 0; ks < 2; ++ks) {
          kh_[rt][ks] = *(const short8*)(krh + (g + 4 * ks) * 8);
          kl_[rt][ks] = *(const short8*)(krl + (g + 4 * ks) * 8);
        }
      }
    }
    WAIT_LGKM0();
    BAR();
    if (tt < 14) {
      int tn = tt + 2;
      stage_async(sWh[cur], w1Th + wbase + tn * 64, 1024, tid);
      stage_async(sWl[cur], w1Tl + wbase + tn * 64, 1024, tid);
    }
  }
#pragma unroll
  for (int ct = 0; ct < 4; ++ct) {
    float bb = b1[h * 64 + 16 * ct + l15];
#pragma unroll
    for (int r = 0; r < 4; ++r)
      h1[(bhTT + a0 + 16 * w + 4 * g + r) * NN + 16 * ct + l15] =
          fmaxf(acc[ct][r] + bb, 0.f);
  }
}

// h2=relu(h1@W2+b2); g=softmax(h2@W3+b3); ho = g0*auv + g1*xv -> bf16 hi/lo
__global__ __launch_bounds__(256) void k_gate(
    const float* __restrict__ h1, const float* __restrict__ xv,
    const float* __restrict__ W2l, const float* __restrict__ b2l,
    const float* __restrict__ W3l, const float* __restrict__ b3l,
    const float* __restrict__ auv, ushort* __restrict__ hoh,
    ushort* __restrict__ hol) {
  __shared__ float sh1[4][64];
  int tid = threadIdx.x;
  int w = tid >> 6;
  int d = tid & 63;
  size_t blk = blockIdx.x;
  size_t bh = blk >> 8;
  int t = (int)((blk & 255) << 2) + w;
  int h = (int)(bh & (HH - 1));
  size_t rowoff = (bh * TT + (size_t)t) * 64;
  sh1[w][d] = h1[rowoff + d];
  __syncthreads();
  float acc = b2l[h * 64 + d];
  const float* W2 = W2l + (size_t)h * 64 * 64;
#pragma unroll 8
  for (int e = 0; e < 64; ++e) acc = fmaf(sh1[w][e], W2[e * 64 + d], acc);
  acc = fmaxf(acc, 0.f);
  float z0 = acc * W3l[((size_t)h * 64 + d) * 2 + 0];
  float z1 = acc * W3l[((size_t)h * 64 + d) * 2 + 1];
#pragma unroll
  for (int m = 1; m < 64; m <<= 1) {
    z0 += __shfl_xor(z0, m, 64);
    z1 += __shfl_xor(z1, m, 64);
  }
  z0 += b3l[h * 2 + 0];
  z1 += b3l[h * 2 + 1];
  float g0 = 1.0f / (1.0f + __expf(z1 - z0));
  float g1 = 1.0f - g0;
  float ho = g0 * auv[rowoff + d] + g1 * xv[rowoff + d];
  ushort hb, lb;
  split1(ho, hb, lb);
  hoh[rowoff + d] = hb;
  hol[rowoff + d] = lb;
}

// out1 = LN(x + concat_h(ho) @ Wlt) via MFMA over K=512, async dbuf staging
__global__ __launch_bounds__(256, 2) void k_merge(
    const float* __restrict__ x, const ushort* __restrict__ hoh,
    const ushort* __restrict__ hol, const ushort* __restrict__ wth,
    const ushort* __restrict__ wtl, const float* __restrict__ g1l,
    const float* __restrict__ b1l, float* __restrict__ out1) {
  __shared__ ushort sAh[2][4096], sAl[2][4096], sBh[2][4096], sBl[2][4096];
  __shared__ float sred[2][64][4];
  __shared__ float sfin[64][2];
  int tid = threadIdx.x;
  int lane = tid & 63, w = tid >> 6;
  int l15 = lane & 15, g = lane >> 4;
  int blk = blockIdx.x;
  int b = blk >> 4, t0 = (blk & 15) << 6;

  {
    size_t ab0 = (((size_t)b * HH + 0) * TT + t0) * NN;
    size_t ab1 = (((size_t)b * HH + 1) * TT + t0) * NN;
    stage_async(sAh[0], hoh + ab0, 64, tid);
    stage_async(sAl[0], hol + ab0, 64, tid);
    stage_async(sBh[0], wth, 512, tid);
    stage_async(sBl[0], wtl, 512, tid);
    stage_async(sAh[1], hoh + ab1, 64, tid);
    stage_async(sAl[1], hol + ab1, 64, tid);
    stage_async(sBh[1], wth + 64, 512, tid);
    stage_async(sBl[1], wtl + 64, 512, tid);
  }

  f32x4 acc[4];
#pragma unroll
  for (int rt = 0; rt < 4; ++rt)
#pragma unroll
    for (int r = 0; r < 4; ++r) acc[rt][r] = 0.f;

  for (int h = 0; h < 8; ++h) {
    int cur = h & 1;
    if (h < 7) WAIT_VM8(); else WAIT_VM0();
    BAR();
    __builtin_amdgcn_s_setprio(1);
#pragma unroll
    for (int ks = 0; ks < 2; ++ks) {
      short8 bBh = frag(sBh[cur], 16 * w + l15, g + 4 * ks);
      short8 bBl = frag(sBl[cur], 16 * w + l15, g + 4 * ks);
#pragma unroll
      for (int rt = 0; rt < 4; ++rt) {
        short8 aAh = frag(sAh[cur], 16 * rt + l15, g + 4 * ks);
        short8 aAl = frag(sAl[cur], 16 * rt + l15, g + 4 * ks);
        acc[rt] = MFMA16(aAh, bBh, acc[rt]);
        acc[rt] = MFMA16(aAh, bBl, acc[rt]);
        acc[rt] = MFMA16(aAl, bBh, acc[rt]);
      }
    }
    __builtin_amdgcn_s_setprio(0);
    WAIT_LGKM0();
    BAR();
    if (h < 6) {
      int hn = h + 2;
      size_t ab = (((size_t)b * HH + hn) * TT + t0) * NN;
      stage_async(sAh[cur], hoh + ab, 64, tid);
      stage_async(sAl[cur], hol + ab, 64, tid);
      stage_async(sBh[cur], wth + hn * 64, 512, tid);
      stage_async(sBl[cur], wtl + hn * 64, 512, tid);
    }
  }
  // epilogue: add x, LayerNorm over the 64 columns
  int mcol = 16 * w + l15;
  float vv[4][4];
#pragma unroll
  for (int rt = 0; rt < 4; ++rt)
#pragma unroll
    for (int r = 0; r < 4; ++r) {
      int row = 16 * rt + 4 * g + r;
      vv[rt][r] = acc[rt][r] + x[((size_t)b * TT + t0 + row) * 64 + mcol];
    }
#pragma unroll
  for (int rt = 0; rt < 4; ++rt)
#pragma unroll
    for (int r = 0; r < 4; ++r) {
      float s1 = vv[rt][r], s2 = vv[rt][r] * vv[rt][r];
#pragma unroll
      for (int mm = 1; mm < 16; mm <<= 1) {
        s1 += __shfl_xor(s1, mm, 64);
        s2 += __shfl_xor(s2, mm, 64);
      }
      if (l15 == 0) {
        int row = 16 * rt + 4 * g + r;
        sred[0][row][w] = s1;
        sred[1][row][w] = s2;
      }
    }
  __syncthreads();
  if (tid < 64) {
    float a1 = sred[0][tid][0] + sred[0][tid][1] + sred[0][tid][2] + sred[0][tid][3];
    float a2 = sred[1][tid][0] + sred[1][tid][1] + sred[1][tid][2] + sred[1][tid][3];
    float mean = a1 * (1.0f / 64.0f);
    float var = a2 * (1.0f / 64.0f) - mean * mean;
    sfin[tid][0] = mean;
    sfin[tid][1] = rsqrtf(var + EPSV);
  }
  __syncthreads();
  float gg = g1l[mcol], bb = b1l[mcol];
#pragma unroll
  for (int rt = 0; rt < 4; ++rt)
#pragma unroll
    for (int r = 0; r < 4; ++r) {
      int row = 16 * rt + 4 * g + r;
      float mean = sfin[row][0], rstd = sfin[row][1];
      out1[((size_t)b * TT + t0 + row) * 64 + mcol] =
          (vv[rt][r] - mean) * rstd * gg + bb;
    }
}

__global__ __launch_bounds__(64) void k_ffn(
    const float* __restrict__ out1, const float* __restrict__ K3sl,
    const float* __restrict__ sclb_l, const float* __restrict__ elWl,
    const float* __restrict__ elbl, const float* __restrict__ g2l,
    const float* __restrict__ b2l, float* __restrict__ xout) {
  __shared__ float so[64], sf[64];
  int lane = threadIdx.x;
  size_t bt = blockIdx.x;
  float o1 = out1[bt * 64 + lane];
  so[lane] = o1;
  __syncthreads();
  float gc = 0.f;
#pragma unroll 8
  for (int n = 0; n < 64; ++n) gc = fmaf(so[n], K3sl[n * 64 + lane], gc);
  float f1 = fmaxf(gc + sclb_l[0] + o1, 0.f);
  sf[lane] = f1;
  __syncthreads();
  float f2 = elbl[lane];
#pragma unroll 8
  for (int e = 0; e < 64; ++e) f2 = fmaf(sf[e], elWl[e * 64 + lane], f2);
  float v = o1 + f2;
  float mu = v;
#pragma unroll
  for (int m = 1; m < 64; m <<= 1) mu += __shfl_xor(mu, m, 64);
  mu *= (1.0f / 64.0f);
  float dd = v - mu;
  float var = dd * dd;
#pragma unroll
  for (int m = 1; m < 64; m <<= 1) var += __shfl_xor(var, m, 64);
  var *= (1.0f / 64.0f);
  xout[bt * 64 + lane] = dd * rsqrtf(var + EPSV) * g2l[lane] + b2l[lane];
}

__global__ __launch_bounds__(256) void k_final(
    const float* __restrict__ x, const float* __restrict__ fW1,
    const float* __restrict__ fb1, const float* __restrict__ fW2,
    const float* __restrict__ fb2, float* __restrict__ out) {
  __shared__ float pl[4][64];
  int tid = threadIdx.x;
  int lane = tid & 63, w = tid >> 6;
  size_t b = blockIdx.x;
  float s = 0.f;
  for (int t = 256 * w; t < 256 * w + 256; ++t) s += x[(b * TT + t) * 64 + lane];
  pl[w][lane] = s;
  __syncthreads();
  if (tid < 64) pl[0][tid] = (pl[0][tid] + pl[1][tid] + pl[2][tid] + pl[3][tid]) * (1.0f / TT);
  __syncthreads();
  if (tid < 64) {
    float hv = 0.f;
    if (lane < 32) {
      hv = fb1[lane];
#pragma unroll 8
      for (int n = 0; n < 64; ++n) hv = fmaf(pl[0][n], fW1[n * 32 + lane], hv);
      hv = fmaxf(hv, 0.f) * fW2[lane];
    }
#pragma unroll
    for (int m = 1; m < 64; m <<= 1) hv += __shfl_xor(hv, m, 64);
    if (lane == 0) out[b] = hv + fb2[0];
  }
}

extern "C" void kernel_launch(void* const* d_in, const int* in_sizes, int n_in,
                              void* d_out, int out_size, void* d_ws, size_t ws_size,
                              hipStream_t stream) {
  const float* inputs = (const float*)d_in[0];
  const float* pos_emb = (const float*)d_in[1];
  const float* K3 = (const float*)d_in[2];
  const float* qw = (const float*)d_in[3];
  const float* qb = (const float*)d_in[4];
  const float* kw = (const float*)d_in[5];
  const float* kb = (const float*)d_in[6];
  const float* vw = (const float*)d_in[7];
  const float* vb = (const float*)d_in[8];
  const float* tqW1 = (const float*)d_in[9];
  const float* tqb1 = (const float*)d_in[10];
  const float* tqW2 = (const float*)d_in[11];
  const float* tqb2 = (const float*)d_in[12];
  const float* tqW3 = (const float*)d_in[13];
  const float* tqb3 = (const float*)d_in[14];
  const float* Wlt = (const float*)d_in[15];
  const float* ln1g = (const float*)d_in[16];
  const float* ln1b = (const float*)d_in[17];
  const float* ln2g = (const float*)d_in[18];
  const float* ln2b = (const float*)d_in[19];
  const float* sclw = (const float*)d_in[20];
  const float* sclb = (const float*)d_in[21];
  const float* elW = (const float*)d_in[22];
  const float* elb = (const float*)d_in[23];
  const float* fW1 = (const float*)d_in[24];
  const float* fb1 = (const float*)d_in[25];
  const float* fW2 = (const float*)d_in[26];
  const float* fb2 = (const float*)d_in[27];
  float* out = (float*)d_out;
  float* ws_f = (float*)d_ws;

  const size_t TN = (size_t)TT * NN;
  const size_t HTN = (size_t)HH * TT * NN;
  const size_t W1T_ELEMS = (size_t)LL * HH * NN * TT;  // ushorts
  const size_t WLT_ELEMS = (size_t)LL * 64 * 512;      // ushorts

  float* K3s = ws_f;
  ushort* w1Th = (ushort*)(ws_f + 2 * 4096);
  ushort* w1Tl = w1Th + W1T_ELEMS;
  ushort* wth = w1Tl + W1T_ELEMS;
  ushort* wtl = wth + WLT_ELEMS;
  const size_t base = 2 * 4096 + W1T_ELEMS + WLT_ELEMS;  // words

  for (int l = 0; l < LL; ++l)
    k_k3s<<<16, 256, 0, stream>>>(K3, sclw + l * KSS, K3s + (size_t)l * 4096);
  k_tsplit<<<LL * HH * 16, 256, 0, stream>>>(tqW1, w1Th, w1Tl);
  k_tsplitW<<<LL * 8, 256, 0, stream>>>(Wlt, wth, wtl);

  const size_t per_b = 2 * TN + 3 * HTN + (size_t)HH * TT + 4 * HTN;
  size_t avail = ws_size / sizeof(float);
  avail = (avail > base) ? avail - base : 0;
  int Bc = (int)(avail / per_b);
  if (Bc > BB) Bc = BB;
  if (Bc < 1) Bc = 1;

  for (int b0 = 0; b0 < BB; b0 += Bc) {
    int bc = (BB - b0 < Bc) ? (BB - b0) : Bc;
    float* x = ws_f + base;
    float* out1 = x + (size_t)bc * TN;
    float* xv = out1 + (size_t)bc * TN;
    float* auv = xv + (size_t)bc * HTN;
    float* h1 = auv + (size_t)bc * HTN;
    float* lseb = h1 + (size_t)bc * HTN;
    ushort* xqh = (ushort*)(lseb + (size_t)bc * HH * TT);
    ushort* xql = xqh + (size_t)bc * HTN;
    ushort* xkh = xql + (size_t)bc * HTN;
    ushort* xkl = xkh + (size_t)bc * HTN;
    ushort* xvTh = xkl + (size_t)bc * HTN;
    ushort* xvTl = xvTh + (size_t)bc * HTN;
    ushort* hoh = xvTl + (size_t)bc * HTN;
    ushort* hol = hoh + (size_t)bc * HTN;

    int total = bc * (int)TN;
    k_addpos<<<(total + 255) / 256, 256, 0, stream>>>(inputs + (size_t)b0 * TN, pos_emb, x,
                                                      total);
    for (int l = 0; l < LL; ++l) {
      k_gconv<<<bc * TT / 4, 256, 0, stream>>>(x, K3, qw + l * HH * KSS, qb + l * HH,
                                               kw + l * HH * KSS, kb + l * HH,
                                               vw + l * HH * KSS, vb + l * HH,
                                               xqh, xql, xkh, xkl, xv);
      k_tsplit<<<bc * HH * 16, 256, 0, stream>>>(xv, xvTh, xvTl);
      k_attn<<<bc * HH * 16, 256, 0, stream>>>(xkh, xkl, xqh, xql, xvTh, xvTl, auv, lseb);
      k_h1<<<bc * HH * 16, 256, 0, stream>>>(
          xkh, xkl, xqh, xql, w1Th + (size_t)l * HH * NN * TT,
          w1Tl + (size_t)l * HH * NN * TT, lseb, tqb1 + l * HH * DD1, h1);
      k_gate<<<bc * HH * (TT / 4), 256, 0, stream>>>(
          h1, xv, tqW2 + (size_t)l * HH * DD1 * DD1, tqb2 + l * HH * DD1,
          tqW3 + (size_t)l * HH * DD1 * 2, tqb3 + l * HH * 2, auv, hoh, hol);
      k_merge<<<bc * 16, 256, 0, stream>>>(x, hoh, hol, wth + (size_t)l * 64 * 512,
                                           wtl + (size_t)l * 64 * 512, ln1g + l * NN,
                                           ln1b + l * NN, out1);
      k_ffn<<<bc * TT, 64, 0, stream>>>(out1, K3s + (size_t)l * 4096, sclb + l,
                                        elW + (size_t)l * NN * NN, elb + l * NN,
                                        ln2g + l * NN, ln2b + l * NN, x);
    }
    k_final<<<bc, 256, 0, stream>>>(x, fW1, fb1, fW2, fb2, out + b0);
  }
}

// Round 6
// 464.465 us; speedup vs baseline: 1.6097x; 1.6097x over previous
//
#include <hip/hip_runtime.h>

typedef __attribute__((ext_vector_type(8))) short short8;
typedef __attribute__((ext_vector_type(4))) float f32x4;

#define BB 8
#define TT 1024
#define NN 64
#define HH 8
#define LL 2
#define KSS 3
#define DD1 64
#define EPSV 1e-6f

#define MFMA16(a, b, c) __builtin_amdgcn_mfma_f32_16x16x32_bf16(a, b, c, 0, 0, 0)
#define BAR() __builtin_amdgcn_s_barrier()
#define WAIT_VM8() asm volatile("s_waitcnt vmcnt(8)" ::: "memory")
#define WAIT_VM4() asm volatile("s_waitcnt vmcnt(4)" ::: "memory")
#define WAIT_VM0() asm volatile("s_waitcnt vmcnt(0)" ::: "memory")
#define WAIT_LGKM0() asm volatile("s_waitcnt lgkmcnt(0)" ::: "memory")

// ---- truncation-based hi/lo bf16 split (hi error lands exactly in lo) ----
__device__ __forceinline__ void split1(float x, ushort& hi, ushort& lo) {
  uint u = __float_as_uint(x);
  hi = (ushort)(u >> 16);
  float hf = __uint_as_float(u & 0xffff0000u);
  lo = (ushort)(__float_as_uint(x - hf) >> 16);
}
__device__ __forceinline__ uint pack2(float a, float b, uint& lo) {
  uint ua = __float_as_uint(a), ub = __float_as_uint(b);
  float ra = __uint_as_float(ua & 0xffff0000u);
  float rb = __uint_as_float(ub & 0xffff0000u);
  lo = (__float_as_uint(a - ra) >> 16) | (__float_as_uint(b - rb) & 0xffff0000u);
  return (ua >> 16) | (ub & 0xffff0000u);
}

// ---- async global->LDS staging ----
__device__ __forceinline__ void gl2lds16(const ushort* g, ushort* l) {
  __builtin_amdgcn_global_load_lds(
      (const __attribute__((address_space(1))) void*)g,
      (__attribute__((address_space(3))) void*)l, 16, 0, 0);
}
// 64x64 tile, row-major [r][64], chunk swizzle c ^ (r&7); 2 gl_lds/wave
__device__ __forceinline__ void stage_async(ushort* __restrict__ s,
                                            const ushort* __restrict__ g,
                                            int stride, int tid) {
  int w = tid >> 6;
  int sub = (tid & 63) >> 3, c = tid & 7;
#pragma unroll
  for (int i = 0; i < 2; ++i) {
    int rb = (i * 4 + w) * 8;
    gl2lds16(g + (size_t)(rb + sub) * stride + ((c ^ sub) << 3), s + rb * 64);
  }
}
__device__ __forceinline__ short8 frag(const ushort* __restrict__ s, int row, int ch) {
  return *(const short8*)(s + row * 64 + ((ch ^ (row & 7)) << 3));
}
// 32x64 tile (rows r, 64 cols), same per-row swizzle; 1 gl_lds/wave
__device__ __forceinline__ void stage_q32(ushort* __restrict__ s,
                                          const ushort* __restrict__ g, int tid) {
  int w = tid >> 6;
  int sub = (tid & 63) >> 3, c = tid & 7;
  int rb = w * 8, r = rb + sub;
  gl2lds16(g + (size_t)r * 64 + ((c ^ (r & 7)) << 3), s + rb * 64);
}
// 64x32 tile (rows n, 32 cols), chunk swizzle c ^ ((n>>1)&3); 1 gl_lds/wave
__device__ __forceinline__ void stage_v32(ushort* __restrict__ s,
                                          const ushort* __restrict__ g, int tid) {
  int w = tid >> 6;
  int noff = (tid & 63) >> 2, c = tid & 3;
  int nb = w * 16, n = nb + noff;
  gl2lds16(g + (size_t)n * 1024 + ((c ^ ((n >> 1) & 3)) << 3), s + nb * 32);
}
__device__ __forceinline__ short8 frag32(const ushort* __restrict__ s, int row, int g) {
  return *(const short8*)(s + row * 32 + ((g ^ ((row >> 1) & 3)) << 3));
}

// ---------- small kernels ----------

__global__ void k_addpos(const float* __restrict__ in, const float* __restrict__ pe,
                         float* __restrict__ x, int total) {
  int idx = blockIdx.x * 256 + threadIdx.x;
  if (idx < total) {
    int tn = idx & (TT * NN - 1);
    x[idx] = in[idx] + pe[tn];
  }
}

__global__ void k_k3s(const float* __restrict__ K3, const float* __restrict__ sclwl,
                      float* __restrict__ K3s) {
  int idx = blockIdx.x * 256 + threadIdx.x;
  int n = idx >> 6, m = idx & 63;
  K3s[idx] = K3[n * 192 + m] * sclwl[0] + K3[n * 192 + 64 + m] * sclwl[1] +
             K3[n * 192 + 128 + m] * sclwl[2];
}

// transpose+split: src [mat][1024][64] f32 -> dh/dl [mat][64][1024] bf16 hi/lo
__global__ __launch_bounds__(256) void k_tsplit(const float* __restrict__ src,
                                                ushort* __restrict__ dh,
                                                ushort* __restrict__ dl) {
  __shared__ float st[64][65];
  int blk = blockIdx.x;
  int mat = blk >> 4, rt = blk & 15;
  int tid = threadIdx.x;
  size_t sbase = ((size_t)mat * TT + rt * 64) * 64;
#pragma unroll
  for (int i = 0; i < 4; ++i) {
    int idx = tid + i * 256;
    int r = idx >> 4, c4 = idx & 15;
    float4 v = *(const float4*)(src + sbase + r * 64 + c4 * 4);
    st[r][c4 * 4 + 0] = v.x; st[r][c4 * 4 + 1] = v.y;
    st[r][c4 * 4 + 2] = v.z; st[r][c4 * 4 + 3] = v.w;
  }
  __syncthreads();
  size_t obase = (size_t)mat * (64 * (size_t)TT) + rt * 64;
#pragma unroll
  for (int i = 0; i < 2; ++i) {
    int idx = tid + i * 256;
    int n = idx >> 3, c = idx & 7;
    uint hw[4], lw[4];
#pragma unroll
    for (int j = 0; j < 4; ++j) hw[j] = pack2(st[c * 8 + 2 * j][n], st[c * 8 + 2 * j + 1][n], lw[j]);
    *(uint4*)(dh + obase + (size_t)n * TT + c * 8) = make_uint4(hw[0], hw[1], hw[2], hw[3]);
    *(uint4*)(dl + obase + (size_t)n * TT + c * 8) = make_uint4(lw[0], lw[1], lw[2], lw[3]);
  }
}

// transpose+split Wlt: [L][512][64] f32 -> [L][64][512] bf16 hi/lo
__global__ __launch_bounds__(256) void k_tsplitW(const float* __restrict__ Wlt,
                                                 ushort* __restrict__ dh,
                                                 ushort* __restrict__ dl) {
  __shared__ float st[64][65];
  int blk = blockIdx.x;
  int l = blk >> 3, rt = blk & 7;
  int tid = threadIdx.x;
  size_t sbase = ((size_t)l * 512 + rt * 64) * 64;
#pragma unroll
  for (int i = 0; i < 4; ++i) {
    int idx = tid + i * 256;
    int r = idx >> 4, c4 = idx & 15;
    float4 v = *(const float4*)(Wlt + sbase + r * 64 + c4 * 4);
    st[r][c4 * 4 + 0] = v.x; st[r][c4 * 4 + 1] = v.y;
    st[r][c4 * 4 + 2] = v.z; st[r][c4 * 4 + 3] = v.w;
  }
  __syncthreads();
  size_t obase = (size_t)l * 64 * 512 + rt * 64;
#pragma unroll
  for (int i = 0; i < 2; ++i) {
    int idx = tid + i * 256;
    int n = idx >> 3, c = idx & 7;
    uint hw[4], lw[4];
#pragma unroll
    for (int j = 0; j < 4; ++j) hw[j] = pack2(st[c * 8 + 2 * j][n], st[c * 8 + 2 * j + 1][n], lw[j]);
    *(uint4*)(dh + obase + (size_t)n * 512 + c * 8) = make_uint4(hw[0], hw[1], hw[2], hw[3]);
    *(uint4*)(dl + obase + (size_t)n * 512 + c * 8) = make_uint4(lw[0], lw[1], lw[2], lw[3]);
  }
}

__global__ __launch_bounds__(64) void k_gconv(
    const float* __restrict__ x, const float* __restrict__ K3,
    const float* __restrict__ qwl, const float* __restrict__ qbl,
    const float* __restrict__ kwl, const float* __restrict__ kbl,
    const float* __restrict__ vwl, const float* __restrict__ vbl,
    ushort* __restrict__ xqh, ushort* __restrict__ xql,
    ushort* __restrict__ xkh, ushort* __restrict__ xkl, float* __restrict__ xv) {
  __shared__ float sx[64];
  int lane = threadIdx.x;
  size_t bt = blockIdx.x;
  size_t b = bt >> 10, t = bt & 1023;
  float xm = x[bt * 64 + lane];
  sx[lane] = xm;
  __syncthreads();
  float a0 = 0.f, a1 = 0.f, a2 = 0.f;
#pragma unroll 4
  for (int n = 0; n < 64; ++n) {
    float xn = sx[n];
    a0 = fmaf(xn, K3[n * 192 + lane], a0);
    a1 = fmaf(xn, K3[n * 192 + 64 + lane], a1);
    a2 = fmaf(xn, K3[n * 192 + 128 + lane], a2);
  }
#pragma unroll
  for (int hh = 0; hh < HH; ++hh) {
    size_t off = (((size_t)b * HH + hh) * TT + t) * 64 + lane;
    float q = fmaf(qwl[hh * 3 + 0], a0,
              fmaf(qwl[hh * 3 + 1], a1, fmaf(qwl[hh * 3 + 2], a2, qbl[hh] + xm)));
    q = fmaxf(q, 0.f) * 0.015625f;  // fold 1/N into Q
    ushort h_, l_;
    split1(q, h_, l_); xqh[off] = h_; xql[off] = l_;
    float k = fmaf(kwl[hh * 3 + 0], a0,
              fmaf(kwl[hh * 3 + 1], a1, fmaf(kwl[hh * 3 + 2], a2, kbl[hh] + xm)));
    k = fmaxf(k, 0.f);
    split1(k, h_, l_); xkh[off] = h_; xkl[off] = l_;
    float v = fmaf(vwl[hh * 3 + 0], a0,
              fmaf(vwl[hh * 3 + 1], a1, fmaf(vwl[hh * 3 + 2], a2, vbl[hh] + xm)));
    xv[off] = fmaxf(v, 0.f);
  }
}

// ---------- pass A: flash attention, 32-u chunks, 40KB LDS, 4 blocks/CU ----------
__global__ __launch_bounds__(256, 4) void k_attn(
    const ushort* __restrict__ xkh, const ushort* __restrict__ xkl,
    const ushort* __restrict__ xqh, const ushort* __restrict__ xql,
    const ushort* __restrict__ xvTh, const ushort* __restrict__ xvTl,
    float* __restrict__ auv, float* __restrict__ lse) {
  __shared__ ushort sQh[4096], sQl[4096];  // 2 bufs x 32x64
  __shared__ ushort sVh[4096], sVl[4096];  // 2 bufs x 64x32
  __shared__ ushort sPh[2048], sPl[2048];  // 64x32
  int tid = threadIdx.x;
  int lane = tid & 63, w = tid >> 6;
  int l15 = lane & 15, g = lane >> 4;
  int nb = gridDim.x, chunk = nb >> 3, bid = blockIdx.x;
  int blk = (bid & 7) * chunk + (bid >> 3);  // XCD swizzle (nb % 8 == 0)
  int bh = blk >> 4, t0 = (blk & 15) << 6;
  size_t bhTT = (size_t)bh * TT;
  int trow = 16 * w + l15, psw = (trow >> 1) & 3;

  // prologue: K tile (64x64) into sQ region, extract persistent K B-frags
  stage_async(sQh, xkh + (bhTT + t0) * NN, 64, tid);
  stage_async(sQl, xkl + (bhTT + t0) * NN, 64, tid);
  WAIT_VM0();
  BAR();
  short8 fKh[2], fKl[2];
#pragma unroll
  for (int ks = 0; ks < 2; ++ks) {
    fKh[ks] = frag(sQh, trow, g + 4 * ks);
    fKl[ks] = frag(sQl, trow, g + 4 * ks);
  }
  WAIT_LGKM0();
  BAR();
  // chunks 0,1
  stage_q32(sQh, xqh + bhTT * NN, tid);
  stage_q32(sQl, xql + bhTT * NN, tid);
  stage_v32(sVh, xvTh + bhTT * NN, tid);
  stage_v32(sVl, xvTl + bhTT * NN, tid);
  stage_q32(sQh + 2048, xqh + (bhTT + 32) * NN, tid);
  stage_q32(sQl + 2048, xql + (bhTT + 32) * NN, tid);
  stage_v32(sVh + 2048, xvTh + bhTT * NN + 32, tid);
  stage_v32(sVl + 2048, xvTl + bhTT * NN + 32, tid);

  float m = -3.0e38f, lsum = 0.f;
  f32x4 O[4];
#pragma unroll
  for (int ct = 0; ct < 4; ++ct)
#pragma unroll
    for (int r = 0; r < 4; ++r) O[ct][r] = 0.f;

  for (int ut = 0; ut < 32; ++ut) {
    int cur = ut & 1;
    if (ut < 31) WAIT_VM4(); else WAIT_VM0();
    BAR();
    const ushort* cQh = sQh + cur * 2048;
    const ushort* cQl = sQl + cur * 2048;
    const ushort* cVh = sVh + cur * 2048;
    const ushort* cVl = sVl + cur * 2048;

    __builtin_amdgcn_s_setprio(1);
    f32x4 S[2];
#pragma unroll
    for (int rt = 0; rt < 2; ++rt) {
      f32x4 a = {0.f, 0.f, 0.f, 0.f};
#pragma unroll
      for (int ks = 0; ks < 2; ++ks) {
        short8 aQh = frag(cQh, 16 * rt + l15, g + 4 * ks);
        short8 aQl = frag(cQl, 16 * rt + l15, g + 4 * ks);
        a = MFMA16(aQh, fKh[ks], a);
        a = MFMA16(aQh, fKl[ks], a);
        a = MFMA16(aQl, fKh[ks], a);
      }
      S[rt] = a;
    }
    __builtin_amdgcn_s_setprio(0);

    float tmax = S[0][0];
#pragma unroll
    for (int rt = 0; rt < 2; ++rt)
#pragma unroll
      for (int r = 0; r < 4; ++r) tmax = fmaxf(tmax, S[rt][r]);
    tmax = fmaxf(tmax, __shfl_xor(tmax, 16, 64));
    tmax = fmaxf(tmax, __shfl_xor(tmax, 32, 64));
    if (__ballot(tmax > m + 4.f)) {  // T13 deferred rescale
      float mnew = fmaxf(m, tmax);
      float f = __expf(m - mnew);
      float fr[4];
#pragma unroll
      for (int r = 0; r < 4; ++r) fr[r] = __shfl(f, (lane & 48) | (4 * g + r), 64);
#pragma unroll
      for (int ct = 0; ct < 4; ++ct)
#pragma unroll
        for (int r = 0; r < 4; ++r) O[ct][r] *= fr[r];
      lsum *= f;
      m = mnew;
    }
    float psum = 0.f;
    uint2 ph[2], plo[2];
#pragma unroll
    for (int rt = 0; rt < 2; ++rt) {
      float p0 = __expf(S[rt][0] - m), p1 = __expf(S[rt][1] - m);
      float p2 = __expf(S[rt][2] - m), p3 = __expf(S[rt][3] - m);
      psum += (p0 + p1) + (p2 + p3);
      uint lo0, lo1;
      ph[rt].x = pack2(p0, p1, lo0);
      ph[rt].y = pack2(p2, p3, lo1);
      plo[rt].x = lo0; plo[rt].y = lo1;
    }
    psum += __shfl_xor(psum, 16, 64);
    psum += __shfl_xor(psum, 32, 64);
    lsum += psum;
    // P write (wave-local rows), layout [t 64][u 32] swizzled
#pragma unroll
    for (int rt = 0; rt < 2; ++rt) {
      int ch = 2 * rt + (g >> 1);
      int off = trow * 32 + ((ch ^ psw) << 3) + ((g & 1) << 2);
      *(uint2*)(sPh + off) = ph[rt];
      *(uint2*)(sPl + off) = plo[rt];
    }
    WAIT_LGKM0();
    __builtin_amdgcn_sched_barrier(0);
    __builtin_amdgcn_s_setprio(1);
    {
      short8 aPh = frag32(sPh, trow, g);
      short8 aPl = frag32(sPl, trow, g);
#pragma unroll
      for (int ct = 0; ct < 4; ++ct) {
        short8 bVh = frag32(cVh, 16 * ct + l15, g);
        short8 bVl = frag32(cVl, 16 * ct + l15, g);
        O[ct] = MFMA16(aPh, bVh, O[ct]);
        O[ct] = MFMA16(aPh, bVl, O[ct]);
        O[ct] = MFMA16(aPl, bVh, O[ct]);
      }
    }
    __builtin_amdgcn_s_setprio(0);
    WAIT_LGKM0();
    BAR();
    if (ut < 30) {
      int tn = ut + 2;
      stage_q32(sQh + cur * 2048, xqh + (bhTT + tn * 32) * NN, tid);
      stage_q32(sQl + cur * 2048, xql + (bhTT + tn * 32) * NN, tid);
      stage_v32(sVh + cur * 2048, xvTh + bhTT * NN + tn * 32, tid);
      stage_v32(sVl + cur * 2048, xvTl + bhTT * NN + tn * 32, tid);
    }
  }
  float il = 1.0f / lsum;
  float ilr[4];
#pragma unroll
  for (int r = 0; r < 4; ++r) ilr[r] = __shfl(il, (lane & 48) | (4 * g + r), 64);
#pragma unroll
  for (int r = 0; r < 4; ++r) {
    size_t row = (bhTT + t0 + 16 * w + 4 * g + r) * NN;
#pragma unroll
    for (int ct = 0; ct < 4; ++ct) auv[row + 16 * ct + l15] = O[ct][r] * ilr[r];
  }
  if (g == 0) lse[bhTT + t0 + trow] = m + __logf(lsum);
}

// ---------- pass B: h1 = relu(P^T @ W1 + b1), 32-t chunks, 44KB LDS ----------
__global__ __launch_bounds__(256, 3) void k_h1(
    const ushort* __restrict__ xkh, const ushort* __restrict__ xkl,
    const ushort* __restrict__ xqh, const ushort* __restrict__ xql,
    const ushort* __restrict__ w1Th, const ushort* __restrict__ w1Tl,
    const float* __restrict__ lse, const float* __restrict__ b1,
    float* __restrict__ h1) {
  __shared__ ushort sKh[4096], sKl[4096];  // 2 bufs x 32x64
  __shared__ ushort sWh[4096], sWl[4096];  // prologue: Q tile; loop: 2 bufs x 64x32
  __shared__ ushort sPh[2048], sPl[2048];
  __shared__ float sL[1024];
  int tid = threadIdx.x;
  int lane = tid & 63, w = tid >> 6;
  int l15 = lane & 15, g = lane >> 4;
  int nb = gridDim.x, chunk = nb >> 3, bid = blockIdx.x;
  int blk = (bid & 7) * chunk + (bid >> 3);
  int bh = blk >> 4, h = bh & (HH - 1), a0 = (blk & 15) << 6;
  size_t bhTT = (size_t)bh * TT;
  size_t wbase = (size_t)h * NN * TT;
  int arow = 16 * w + l15, psw = (arow >> 1) & 3;

  // prologue: Q tile into sW region, extract persistent Q B-frags
  stage_async(sWh, xqh + (bhTT + a0) * NN, 64, tid);
  stage_async(sWl, xql + (bhTT + a0) * NN, 64, tid);
  WAIT_VM0();
  BAR();
  short8 fQh[2], fQl[2];
#pragma unroll
  for (int ks = 0; ks < 2; ++ks) {
    fQh[ks] = frag(sWh, arow, g + 4 * ks);
    fQl[ks] = frag(sWl, arow, g + 4 * ks);
  }
  // lse table
#pragma unroll
  for (int i = 0; i < 4; ++i) sL[tid + i * 256] = lse[bhTT + tid + i * 256];
  WAIT_LGKM0();
  BAR();
  stage_q32(sKh, xkh + bhTT * NN, tid);
  stage_q32(sKl, xkl + bhTT * NN, tid);
  stage_v32(sWh, w1Th + wbase, tid);
  stage_v32(sWl, w1Tl + wbase, tid);
  stage_q32(sKh + 2048, xkh + (bhTT + 32) * NN, tid);
  stage_q32(sKl + 2048, xkl + (bhTT + 32) * NN, tid);
  stage_v32(sWh + 2048, w1Th + wbase + 32, tid);
  stage_v32(sWl + 2048, w1Tl + wbase + 32, tid);

  f32x4 acc[4];
#pragma unroll
  for (int ct = 0; ct < 4; ++ct)
#pragma unroll
    for (int r = 0; r < 4; ++r) acc[ct][r] = 0.f;

  for (int tt = 0; tt < 32; ++tt) {
    int cur = tt & 1;
    if (tt < 31) WAIT_VM4(); else WAIT_VM0();
    BAR();
    const ushort* cKh = sKh + cur * 2048;
    const ushort* cKl = sKl + cur * 2048;
    const ushort* cWh = sWh + cur * 2048;
    const ushort* cWl = sWl + cur * 2048;

    __builtin_amdgcn_s_setprio(1);
    f32x4 S[2];
#pragma unroll
    for (int rt = 0; rt < 2; ++rt) {
      f32x4 a = {0.f, 0.f, 0.f, 0.f};
#pragma unroll
      for (int ks = 0; ks < 2; ++ks) {
        short8 aKh = frag(cKh, 16 * rt + l15, g + 4 * ks);
        short8 aKl = frag(cKl, 16 * rt + l15, g + 4 * ks);
        a = MFMA16(aKh, fQh[ks], a);
        a = MFMA16(aKh, fQl[ks], a);
        a = MFMA16(aKl, fQh[ks], a);
      }
      S[rt] = a;
    }
    __builtin_amdgcn_s_setprio(0);

    uint2 ph[2], plo[2];
#pragma unroll
    for (int rt = 0; rt < 2; ++rt) {
      f32x4 lv = *(const f32x4*)(sL + tt * 32 + 16 * rt + 4 * g);
      float p0 = __expf(S[rt][0] - lv[0]);
      float p1 = __expf(S[rt][1] - lv[1]);
      float p2 = __expf(S[rt][2] - lv[2]);
      float p3 = __expf(S[rt][3] - lv[3]);
      uint lo0, lo1;
      ph[rt].x = pack2(p0, p1, lo0);
      ph[rt].y = pack2(p2, p3, lo1);
      plo[rt].x = lo0; plo[rt].y = lo1;
    }
#pragma unroll
    for (int rt = 0; rt < 2; ++rt) {
      int ch = 2 * rt + (g >> 1);
      int off = arow * 32 + ((ch ^ psw) << 3) + ((g & 1) << 2);
      *(uint2*)(sPh + off) = ph[rt];
      *(uint2*)(sPl + off) = plo[rt];
    }
    WAIT_LGKM0();
    __builtin_amdgcn_sched_barrier(0);
    __builtin_amdgcn_s_setprio(1);
    {
      short8 aPh = frag32(sPh, arow, g);
      short8 aPl = frag32(sPl, arow, g);
#pragma unroll
      for (int ct = 0; ct < 4; ++ct) {
        short8 bWh = frag32(cWh, 16 * ct + l15, g);
        short8 bWl = frag32(cWl, 16 * ct + l15, g);
        acc[ct] = MFMA16(aPh, bWh, acc[ct]);
        acc[ct] = MFMA16(aPh, bWl, acc[ct]);
        acc[ct] = MFMA16(aPl, bWh, acc[ct]);
      }
    }
    __builtin_amdgcn_s_setprio(0);
    WAIT_LGKM0();
    BAR();
    if (tt < 30) {
      int tn = tt + 2;
      stage_q32(sKh + cur * 2048, xkh + (bhTT + tn * 32) * NN, tid);
      stage_q32(sKl + cur * 2048, xkl + (bhTT + tn * 32) * NN, tid);
      stage_v32(sWh + cur * 2048, w1Th + wbase + tn * 32, tid);
      stage_v32(sWl + cur * 2048, w1Tl + wbase + tn * 32, tid);
    }
  }
#pragma unroll
  for (int ct = 0; ct < 4; ++ct) {
    float bb = b1[h * 64 + 16 * ct + l15];
#pragma unroll
    for (int r = 0; r < 4; ++r)
      h1[(bhTT + a0 + 16 * w + 4 * g + r) * NN + 16 * ct + l15] =
          fmaxf(acc[ct][r] + bb, 0.f);
  }
}

// h2=relu(h1@W2+b2); g=softmax(h2@W3+b3); ho = g0*auv + g1*xv -> bf16 hi/lo
__global__ __launch_bounds__(256) void k_gate(
    const float* __restrict__ h1, const float* __restrict__ xv,
    const float* __restrict__ W2l, const float* __restrict__ b2l,
    const float* __restrict__ W3l, const float* __restrict__ b3l,
    const float* __restrict__ auv, ushort* __restrict__ hoh,
    ushort* __restrict__ hol) {
  __shared__ float sh1[4][64];
  int tid = threadIdx.x;
  int w = tid >> 6;
  int d = tid & 63;
  size_t blk = blockIdx.x;
  size_t bh = blk >> 8;
  int t = (int)((blk & 255) << 2) + w;
  int h = (int)(bh & (HH - 1));
  size_t rowoff = (bh * TT + (size_t)t) * 64;
  sh1[w][d] = h1[rowoff + d];
  __syncthreads();
  float acc = b2l[h * 64 + d];
  const float* W2 = W2l + (size_t)h * 64 * 64;
#pragma unroll 8
  for (int e = 0; e < 64; ++e) acc = fmaf(sh1[w][e], W2[e * 64 + d], acc);
  acc = fmaxf(acc, 0.f);
  float z0 = acc * W3l[((size_t)h * 64 + d) * 2 + 0];
  float z1 = acc * W3l[((size_t)h * 64 + d) * 2 + 1];
#pragma unroll
  for (int m = 1; m < 64; m <<= 1) {
    z0 += __shfl_xor(z0, m, 64);
    z1 += __shfl_xor(z1, m, 64);
  }
  z0 += b3l[h * 2 + 0];
  z1 += b3l[h * 2 + 1];
  float g0 = 1.0f / (1.0f + __expf(z1 - z0));
  float g1 = 1.0f - g0;
  float ho = g0 * auv[rowoff + d] + g1 * xv[rowoff + d];
  ushort hb, lb;
  split1(ho, hb, lb);
  hoh[rowoff + d] = hb;
  hol[rowoff + d] = lb;
}

// out1 = LN(x + concat_h(ho) @ Wlt) via MFMA over K=512, async dbuf staging
__global__ __launch_bounds__(256, 2) void k_merge(
    const float* __restrict__ x, const ushort* __restrict__ hoh,
    const ushort* __restrict__ hol, const ushort* __restrict__ wth,
    const ushort* __restrict__ wtl, const float* __restrict__ g1l,
    const float* __restrict__ b1l, float* __restrict__ out1) {
  __shared__ ushort sAh[2][4096], sAl[2][4096], sBh[2][4096], sBl[2][4096];
  __shared__ float sred[2][64][4];
  __shared__ float sfin[64][2];
  int tid = threadIdx.x;
  int lane = tid & 63, w = tid >> 6;
  int l15 = lane & 15, g = lane >> 4;
  int blk = blockIdx.x;
  int b = blk >> 4, t0 = (blk & 15) << 6;

  {
    size_t ab0 = (((size_t)b * HH + 0) * TT + t0) * NN;
    size_t ab1 = (((size_t)b * HH + 1) * TT + t0) * NN;
    stage_async(sAh[0], hoh + ab0, 64, tid);
    stage_async(sAl[0], hol + ab0, 64, tid);
    stage_async(sBh[0], wth, 512, tid);
    stage_async(sBl[0], wtl, 512, tid);
    stage_async(sAh[1], hoh + ab1, 64, tid);
    stage_async(sAl[1], hol + ab1, 64, tid);
    stage_async(sBh[1], wth + 64, 512, tid);
    stage_async(sBl[1], wtl + 64, 512, tid);
  }

  f32x4 acc[4];
#pragma unroll
  for (int rt = 0; rt < 4; ++rt)
#pragma unroll
    for (int r = 0; r < 4; ++r) acc[rt][r] = 0.f;

  for (int h = 0; h < 8; ++h) {
    int cur = h & 1;
    if (h < 7) WAIT_VM8(); else WAIT_VM0();
    BAR();
    __builtin_amdgcn_s_setprio(1);
#pragma unroll
    for (int ks = 0; ks < 2; ++ks) {
      short8 bBh = frag(sBh[cur], 16 * w + l15, g + 4 * ks);
      short8 bBl = frag(sBl[cur], 16 * w + l15, g + 4 * ks);
#pragma unroll
      for (int rt = 0; rt < 4; ++rt) {
        short8 aAh = frag(sAh[cur], 16 * rt + l15, g + 4 * ks);
        short8 aAl = frag(sAl[cur], 16 * rt + l15, g + 4 * ks);
        acc[rt] = MFMA16(aAh, bBh, acc[rt]);
        acc[rt] = MFMA16(aAh, bBl, acc[rt]);
        acc[rt] = MFMA16(aAl, bBh, acc[rt]);
      }
    }
    __builtin_amdgcn_s_setprio(0);
    WAIT_LGKM0();
    BAR();
    if (h < 6) {
      int hn = h + 2;
      size_t ab = (((size_t)b * HH + hn) * TT + t0) * NN;
      stage_async(sAh[cur], hoh + ab, 64, tid);
      stage_async(sAl[cur], hol + ab, 64, tid);
      stage_async(sBh[cur], wth + hn * 64, 512, tid);
      stage_async(sBl[cur], wtl + hn * 64, 512, tid);
    }
  }
  // epilogue: add x, LayerNorm over the 64 columns
  int mcol = 16 * w + l15;
  float vv[4][4];
#pragma unroll
  for (int rt = 0; rt < 4; ++rt)
#pragma unroll
    for (int r = 0; r < 4; ++r) {
      int row = 16 * rt + 4 * g + r;
      vv[rt][r] = acc[rt][r] + x[((size_t)b * TT + t0 + row) * 64 + mcol];
    }
#pragma unroll
  for (int rt = 0; rt < 4; ++rt)
#pragma unroll
    for (int r = 0; r < 4; ++r) {
      float s1 = vv[rt][r], s2 = vv[rt][r] * vv[rt][r];
#pragma unroll
      for (int mm = 1; mm < 16; mm <<= 1) {
        s1 += __shfl_xor(s1, mm, 64);
        s2 += __shfl_xor(s2, mm, 64);
      }
      if (l15 == 0) {
        int row = 16 * rt + 4 * g + r;
        sred[0][row][w] = s1;
        sred[1][row][w] = s2;
      }
    }
  __syncthreads();
  if (tid < 64) {
    float a1 = sred[0][tid][0] + sred[0][tid][1] + sred[0][tid][2] + sred[0][tid][3];
    float a2 = sred[1][tid][0] + sred[1][tid][1] + sred[1][tid][2] + sred[1][tid][3];
    float mean = a1 * (1.0f / 64.0f);
    float var = a2 * (1.0f / 64.0f) - mean * mean;
    sfin[tid][0] = mean;
    sfin[tid][1] = rsqrtf(var + EPSV);
  }
  __syncthreads();
  float gg = g1l[mcol], bb = b1l[mcol];
#pragma unroll
  for (int rt = 0; rt < 4; ++rt)
#pragma unroll
    for (int r = 0; r < 4; ++r) {
      int row = 16 * rt + 4 * g + r;
      float mean = sfin[row][0], rstd = sfin[row][1];
      out1[((size_t)b * TT + t0 + row) * 64 + mcol] =
          (vv[rt][r] - mean) * rstd * gg + bb;
    }
}

__global__ __launch_bounds__(64) void k_ffn(
    const float* __restrict__ out1, const float* __restrict__ K3sl,
    const float* __restrict__ sclb_l, const float* __restrict__ elWl,
    const float* __restrict__ elbl, const float* __restrict__ g2l,
    const float* __restrict__ b2l, float* __restrict__ xout) {
  __shared__ float so[64], sf[64];
  int lane = threadIdx.x;
  size_t bt = blockIdx.x;
  float o1 = out1[bt * 64 + lane];
  so[lane] = o1;
  __syncthreads();
  float gc = 0.f;
#pragma unroll 8
  for (int n = 0; n < 64; ++n) gc = fmaf(so[n], K3sl[n * 64 + lane], gc);
  float f1 = fmaxf(gc + sclb_l[0] + o1, 0.f);
  sf[lane] = f1;
  __syncthreads();
  float f2 = elbl[lane];
#pragma unroll 8
  for (int e = 0; e < 64; ++e) f2 = fmaf(sf[e], elWl[e * 64 + lane], f2);
  float v = o1 + f2;
  float mu = v;
#pragma unroll
  for (int m = 1; m < 64; m <<= 1) mu += __shfl_xor(mu, m, 64);
  mu *= (1.0f / 64.0f);
  float dd = v - mu;
  float var = dd * dd;
#pragma unroll
  for (int m = 1; m < 64; m <<= 1) var += __shfl_xor(var, m, 64);
  var *= (1.0f / 64.0f);
  xout[bt * 64 + lane] = dd * rsqrtf(var + EPSV) * g2l[lane] + b2l[lane];
}

__global__ __launch_bounds__(256) void k_final(
    const float* __restrict__ x, const float* __restrict__ fW1,
    const float* __restrict__ fb1, const float* __restrict__ fW2,
    const float* __restrict__ fb2, float* __restrict__ out) {
  __shared__ float pl[4][64];
  int tid = threadIdx.x;
  int lane = tid & 63, w = tid >> 6;
  size_t b = blockIdx.x;
  float s = 0.f;
  for (int t = 256 * w; t < 256 * w + 256; ++t) s += x[(b * TT + t) * 64 + lane];
  pl[w][lane] = s;
  __syncthreads();
  if (tid < 64) pl[0][tid] = (pl[0][tid] + pl[1][tid] + pl[2][tid] + pl[3][tid]) * (1.0f / TT);
  __syncthreads();
  if (tid < 64) {
    float hv = 0.f;
    if (lane < 32) {
      hv = fb1[lane];
#pragma unroll 8
      for (int n = 0; n < 64; ++n) hv = fmaf(pl[0][n], fW1[n * 32 + lane], hv);
      hv = fmaxf(hv, 0.f) * fW2[lane];
    }
#pragma unroll
    for (int m = 1; m < 64; m <<= 1) hv += __shfl_xor(hv, m, 64);
    if (lane == 0) out[b] = hv + fb2[0];
  }
}

extern "C" void kernel_launch(void* const* d_in, const int* in_sizes, int n_in,
                              void* d_out, int out_size, void* d_ws, size_t ws_size,
                              hipStream_t stream) {
  const float* inputs = (const float*)d_in[0];
  const float* pos_emb = (const float*)d_in[1];
  const float* K3 = (const float*)d_in[2];
  const float* qw = (const float*)d_in[3];
  const float* qb = (const float*)d_in[4];
  const float* kw = (const float*)d_in[5];
  const float* kb = (const float*)d_in[6];
  const float* vw = (const float*)d_in[7];
  const float* vb = (const float*)d_in[8];
  const float* tqW1 = (const float*)d_in[9];
  const float* tqb1 = (const float*)d_in[10];
  const float* tqW2 = (const float*)d_in[11];
  const float* tqb2 = (const float*)d_in[12];
  const float* tqW3 = (const float*)d_in[13];
  const float* tqb3 = (const float*)d_in[14];
  const float* Wlt = (const float*)d_in[15];
  const float* ln1g = (const float*)d_in[16];
  const float* ln1b = (const float*)d_in[17];
  const float* ln2g = (const float*)d_in[18];
  const float* ln2b = (const float*)d_in[19];
  const float* sclw = (const float*)d_in[20];
  const float* sclb = (const float*)d_in[21];
  const float* elW = (const float*)d_in[22];
  const float* elb = (const float*)d_in[23];
  const float* fW1 = (const float*)d_in[24];
  const float* fb1 = (const float*)d_in[25];
  const float* fW2 = (const float*)d_in[26];
  const float* fb2 = (const float*)d_in[27];
  float* out = (float*)d_out;
  float* ws_f = (float*)d_ws;

  const size_t TN = (size_t)TT * NN;
  const size_t HTN = (size_t)HH * TT * NN;
  const size_t W1T_ELEMS = (size_t)LL * HH * NN * TT;  // ushorts
  const size_t WLT_ELEMS = (size_t)LL * 64 * 512;      // ushorts

  float* K3s = ws_f;
  ushort* w1Th = (ushort*)(ws_f + 2 * 4096);
  ushort* w1Tl = w1Th + W1T_ELEMS;
  ushort* wth = w1Tl + W1T_ELEMS;
  ushort* wtl = wth + WLT_ELEMS;
  const size_t base = 2 * 4096 + W1T_ELEMS + WLT_ELEMS;  // words

  for (int l = 0; l < LL; ++l)
    k_k3s<<<16, 256, 0, stream>>>(K3, sclw + l * KSS, K3s + (size_t)l * 4096);
  k_tsplit<<<LL * HH * 16, 256, 0, stream>>>(tqW1, w1Th, w1Tl);
  k_tsplitW<<<LL * 8, 256, 0, stream>>>(Wlt, wth, wtl);

  const size_t per_b = 2 * TN + 3 * HTN + (size_t)HH * TT + 4 * HTN;
  size_t avail = ws_size / sizeof(float);
  avail = (avail > base) ? avail - base : 0;
  int Bc = (int)(avail / per_b);
  if (Bc > BB) Bc = BB;
  if (Bc < 1) Bc = 1;

  for (int b0 = 0; b0 < BB; b0 += Bc) {
    int bc = (BB - b0 < Bc) ? (BB - b0) : Bc;
    float* x = ws_f + base;
    float* out1 = x + (size_t)bc * TN;
    float* xv = out1 + (size_t)bc * TN;
    float* auv = xv + (size_t)bc * HTN;
    float* h1 = auv + (size_t)bc * HTN;
    float* lseb = h1 + (size_t)bc * HTN;
    ushort* xqh = (ushort*)(lseb + (size_t)bc * HH * TT);
    ushort* xql = xqh + (size_t)bc * HTN;
    ushort* xkh = xql + (size_t)bc * HTN;
    ushort* xkl = xkh + (size_t)bc * HTN;
    ushort* xvTh = xkl + (size_t)bc * HTN;
    ushort* xvTl = xvTh + (size_t)bc * HTN;
    ushort* hoh = xvTl + (size_t)bc * HTN;
    ushort* hol = hoh + (size_t)bc * HTN;

    int total = bc * (int)TN;
    k_addpos<<<(total + 255) / 256, 256, 0, stream>>>(inputs + (size_t)b0 * TN, pos_emb, x,
                                                      total);
    for (int l = 0; l < LL; ++l) {
      k_gconv<<<bc * TT, 64, 0, stream>>>(x, K3, qw + l * HH * KSS, qb + l * HH,
                                          kw + l * HH * KSS, kb + l * HH,
                                          vw + l * HH * KSS, vb + l * HH,
                                          xqh, xql, xkh, xkl, xv);
      k_tsplit<<<bc * HH * 16, 256, 0, stream>>>(xv, xvTh, xvTl);
      k_attn<<<bc * HH * 16, 256, 0, stream>>>(xkh, xkl, xqh, xql, xvTh, xvTl, auv, lseb);
      k_h1<<<bc * HH * 16, 256, 0, stream>>>(
          xkh, xkl, xqh, xql, w1Th + (size_t)l * HH * NN * TT,
          w1Tl + (size_t)l * HH * NN * TT, lseb, tqb1 + l * HH * DD1, h1);
      k_gate<<<bc * HH * (TT / 4), 256, 0, stream>>>(
          h1, xv, tqW2 + (size_t)l * HH * DD1 * DD1, tqb2 + l * HH * DD1,
          tqW3 + (size_t)l * HH * DD1 * 2, tqb3 + l * HH * 2, auv, hoh, hol);
      k_merge<<<bc * 16, 256, 0, stream>>>(x, hoh, hol, wth + (size_t)l * 64 * 512,
                                           wtl + (size_t)l * 64 * 512, ln1g + l * NN,
                                           ln1b + l * NN, out1);
      k_ffn<<<bc * TT, 64, 0, stream>>>(out1, K3s + (size_t)l * 4096, sclb + l,
                                        elW + (size_t)l * NN * NN, elb + l * NN,
                                        ln2g + l * NN, ln2b + l * NN, x);
    }
    k_final<<<bc, 256, 0, stream>>>(x, fW1, fb1, fW2, fb2, out + b0);
  }
}

// Round 8
// 344.102 us; speedup vs baseline: 2.1727x; 1.3498x over previous
//
#include <hip/hip_runtime.h>

typedef __attribute__((ext_vector_type(8))) short short8;
typedef __attribute__((ext_vector_type(4))) float f32x4;

#define BB 8
#define TT 1024
#define NN 64
#define HH 8
#define LL 2
#define KSS 3
#define DD1 64
#define EPSV 1e-6f
#define LOG2E 1.4426950408889634f

#define MFMA16(a, b, c) __builtin_amdgcn_mfma_f32_16x16x32_bf16(a, b, c, 0, 0, 0)
#define BAR() __builtin_amdgcn_s_barrier()
#define WAIT_VM8() asm volatile("s_waitcnt vmcnt(8)" ::: "memory")
#define WAIT_VM3() asm volatile("s_waitcnt vmcnt(3)" ::: "memory")
#define WAIT_VM0() asm volatile("s_waitcnt vmcnt(0)" ::: "memory")
#define WAIT_LGKM0() asm volatile("s_waitcnt lgkmcnt(0)" ::: "memory")

__device__ __forceinline__ float exp2_(float x) { return __builtin_amdgcn_exp2f(x); }
__device__ __forceinline__ float log2_(float x) { return __builtin_amdgcn_logf(x); }

// ---- truncation-based hi/lo bf16 split (hi error lands exactly in lo) ----
__device__ __forceinline__ void split1(float x, ushort& hi, ushort& lo) {
  uint u = __float_as_uint(x);
  hi = (ushort)(u >> 16);
  float hf = __uint_as_float(u & 0xffff0000u);
  lo = (ushort)(__float_as_uint(x - hf) >> 16);
}
__device__ __forceinline__ uint pack2(float a, float b, uint& lo) {
  uint ua = __float_as_uint(a), ub = __float_as_uint(b);
  float ra = __uint_as_float(ua & 0xffff0000u);
  float rb = __uint_as_float(ub & 0xffff0000u);
  lo = (__float_as_uint(a - ra) >> 16) | (__float_as_uint(b - rb) & 0xffff0000u);
  return (ua >> 16) | (ub & 0xffff0000u);
}
// round-to-nearest-even bf16 (for hi-only quantities)
__device__ __forceinline__ ushort f2bfr(float x) {
  union { float f; uint u; } v; v.f = x;
  uint r = (v.u + 0x7fffu + ((v.u >> 16) & 1u)) >> 16;
  return (ushort)r;
}
__device__ __forceinline__ float bf2f(ushort b) {
  union { uint u; float f; } v; v.u = ((uint)b) << 16; return v.f;
}

// ---- async global->LDS staging ----
__device__ __forceinline__ void gl2lds16(const ushort* g, ushort* l) {
  __builtin_amdgcn_global_load_lds(
      (const __attribute__((address_space(1))) void*)g,
      (__attribute__((address_space(3))) void*)l, 16, 0, 0);
}
// 64x64 tile, chunk swizzle c ^ (r&7); 2 gl_lds/wave
__device__ __forceinline__ void stage_async(ushort* __restrict__ s,
                                            const ushort* __restrict__ g,
                                            int stride, int tid) {
  int w = tid >> 6;
  int sub = (tid & 63) >> 3, c = tid & 7;
#pragma unroll
  for (int i = 0; i < 2; ++i) {
    int rb = (i * 4 + w) * 8;
    gl2lds16(g + (size_t)(rb + sub) * stride + ((c ^ sub) << 3), s + rb * 64);
  }
}
__device__ __forceinline__ short8 frag(const ushort* __restrict__ s, int row, int ch) {
  return *(const short8*)(s + row * 64 + ((ch ^ (row & 7)) << 3));
}
// 32x64 tile; 1 gl_lds/wave
__device__ __forceinline__ void stage_q32(ushort* __restrict__ s,
                                          const ushort* __restrict__ g, int tid) {
  int w = tid >> 6;
  int sub = (tid & 63) >> 3, c = tid & 7;
  int rb = w * 8, r = rb + sub;
  gl2lds16(g + (size_t)r * 64 + ((c ^ (r & 7)) << 3), s + rb * 64);
}
// 64x32 tile (stride 1024), chunk swizzle c ^ ((n>>1)&3); 1 gl_lds/wave
__device__ __forceinline__ void stage_v32(ushort* __restrict__ s,
                                          const ushort* __restrict__ g, int tid) {
  int w = tid >> 6;
  int noff = (tid & 63) >> 2, c = tid & 3;
  int nb = w * 16, n = nb + noff;
  gl2lds16(g + (size_t)n * 1024 + ((c ^ ((n >> 1) & 3)) << 3), s + nb * 32);
}
__device__ __forceinline__ short8 frag32(const ushort* __restrict__ s, int row, int g) {
  return *(const short8*)(s + row * 32 + ((g ^ ((row >> 1) & 3)) << 3));
}

// ---------- small kernels ----------

__global__ void k_addpos(const float* __restrict__ in, const float* __restrict__ pe,
                         float* __restrict__ x, int total) {
  int idx = blockIdx.x * 256 + threadIdx.x;
  if (idx < total) {
    int tn = idx & (TT * NN - 1);
    x[idx] = in[idx] + pe[tn];
  }
}

// K3s^T (bf16 RNE): out[m*64+n] = sum_k K3[n,k,m]*sclw[k]
__global__ void k_k3s(const float* __restrict__ K3, const float* __restrict__ sclwl,
                      ushort* __restrict__ dh) {
  int idx = blockIdx.x * 256 + threadIdx.x;  // < 4096
  int n = idx >> 6, m = idx & 63;
  float v = K3[n * 192 + m] * sclwl[0] + K3[n * 192 + 64 + m] * sclwl[1] +
            K3[n * 192 + 128 + m] * sclwl[2];
  dh[m * 64 + n] = f2bfr(v);
}

// transpose, hi-only RNE: src [mat][1024][64] f32 -> dh [mat][64][1024] bf16
__global__ __launch_bounds__(256) void k_tsplit(const float* __restrict__ src,
                                                ushort* __restrict__ dh) {
  __shared__ float st[64][65];
  int blk = blockIdx.x;
  int mat = blk >> 4, rt = blk & 15;
  int tid = threadIdx.x;
  size_t sbase = ((size_t)mat * TT + rt * 64) * 64;
#pragma unroll
  for (int i = 0; i < 4; ++i) {
    int idx = tid + i * 256;
    int r = idx >> 4, c4 = idx & 15;
    float4 v = *(const float4*)(src + sbase + r * 64 + c4 * 4);
    st[r][c4 * 4 + 0] = v.x; st[r][c4 * 4 + 1] = v.y;
    st[r][c4 * 4 + 2] = v.z; st[r][c4 * 4 + 3] = v.w;
  }
  __syncthreads();
  size_t obase = (size_t)mat * (64 * (size_t)TT) + rt * 64;
#pragma unroll
  for (int i = 0; i < 2; ++i) {
    int idx = tid + i * 256;
    int n = idx >> 3, c = idx & 7;
    uint hw[4];
#pragma unroll
    for (int j = 0; j < 4; ++j)
      hw[j] = (uint)f2bfr(st[c * 8 + 2 * j][n]) | ((uint)f2bfr(st[c * 8 + 2 * j + 1][n]) << 16);
    *(uint4*)(dh + obase + (size_t)n * TT + c * 8) = make_uint4(hw[0], hw[1], hw[2], hw[3]);
  }
}

// transpose+split Wlt (hi/lo)
__global__ __launch_bounds__(256) void k_tsplitW(const float* __restrict__ Wlt,
                                                 ushort* __restrict__ dh,
                                                 ushort* __restrict__ dl) {
  __shared__ float st[64][65];
  int blk = blockIdx.x;
  int l = blk >> 3, rt = blk & 7;
  int tid = threadIdx.x;
  size_t sbase = ((size_t)l * 512 + rt * 64) * 64;
#pragma unroll
  for (int i = 0; i < 4; ++i) {
    int idx = tid + i * 256;
    int r = idx >> 4, c4 = idx & 15;
    float4 v = *(const float4*)(Wlt + sbase + r * 64 + c4 * 4);
    st[r][c4 * 4 + 0] = v.x; st[r][c4 * 4 + 1] = v.y;
    st[r][c4 * 4 + 2] = v.z; st[r][c4 * 4 + 3] = v.w;
  }
  __syncthreads();
  size_t obase = (size_t)l * 64 * 512 + rt * 64;
#pragma unroll
  for (int i = 0; i < 2; ++i) {
    int idx = tid + i * 256;
    int n = idx >> 3, c = idx & 7;
    uint hw[4], lw[4];
#pragma unroll
    for (int j = 0; j < 4; ++j) hw[j] = pack2(st[c * 8 + 2 * j][n], st[c * 8 + 2 * j + 1][n], lw[j]);
    *(uint4*)(dh + obase + (size_t)n * 512 + c * 8) = make_uint4(hw[0], hw[1], hw[2], hw[3]);
    *(uint4*)(dl + obase + (size_t)n * 512 + c * 8) = make_uint4(lw[0], lw[1], lw[2], lw[3]);
  }
}

// square transpose, hi-only RNE: src [mat][64][64] -> dh [mat][64][64]^T
__global__ __launch_bounds__(256) void k_tsplitSq(const float* __restrict__ src,
                                                  ushort* __restrict__ dh) {
  __shared__ float st[64][65];
  int mat = blockIdx.x;
  int tid = threadIdx.x;
  size_t sbase = (size_t)mat * 4096;
#pragma unroll
  for (int i = 0; i < 4; ++i) {
    int idx = tid + i * 256;
    int r = idx >> 4, c4 = idx & 15;
    float4 v = *(const float4*)(src + sbase + r * 64 + c4 * 4);
    st[r][c4 * 4 + 0] = v.x; st[r][c4 * 4 + 1] = v.y;
    st[r][c4 * 4 + 2] = v.z; st[r][c4 * 4 + 3] = v.w;
  }
  __syncthreads();
#pragma unroll
  for (int i = 0; i < 2; ++i) {
    int idx = tid + i * 256;
    int d = idx >> 3, c = idx & 7;
    uint hw[4];
#pragma unroll
    for (int j = 0; j < 4; ++j)
      hw[j] = (uint)f2bfr(st[c * 8 + 2 * j][d]) | ((uint)f2bfr(st[c * 8 + 2 * j + 1][d]) << 16);
    *(uint4*)(dh + sbase + (size_t)d * 64 + c * 8) = make_uint4(hw[0], hw[1], hw[2], hw[3]);
  }
}

__global__ __launch_bounds__(64) void k_gconv(
    const float* __restrict__ x, const float* __restrict__ K3,
    const float* __restrict__ qwl, const float* __restrict__ qbl,
    const float* __restrict__ kwl, const float* __restrict__ kbl,
    const float* __restrict__ vwl, const float* __restrict__ vbl,
    ushort* __restrict__ xqh, ushort* __restrict__ xql,
    ushort* __restrict__ xkh, ushort* __restrict__ xkl, float* __restrict__ xv) {
  __shared__ float sx[64];
  int lane = threadIdx.x;
  size_t bt = blockIdx.x;
  size_t b = bt >> 10, t = bt & 1023;
  float xm = x[bt * 64 + lane];
  sx[lane] = xm;
  __syncthreads();
  float a0 = 0.f, a1 = 0.f, a2 = 0.f;
#pragma unroll 4
  for (int n = 0; n < 64; ++n) {
    float xn = sx[n];
    a0 = fmaf(xn, K3[n * 192 + lane], a0);
    a1 = fmaf(xn, K3[n * 192 + 64 + lane], a1);
    a2 = fmaf(xn, K3[n * 192 + 128 + lane], a2);
  }
#pragma unroll
  for (int hh = 0; hh < HH; ++hh) {
    size_t off = (((size_t)b * HH + hh) * TT + t) * 64 + lane;
    float q = fmaf(qwl[hh * 3 + 0], a0,
              fmaf(qwl[hh * 3 + 1], a1, fmaf(qwl[hh * 3 + 2], a2, qbl[hh] + xm)));
    q = fmaxf(q, 0.f) * (0.015625f * LOG2E);  // fold 1/N and log2(e) into Q
    ushort h_, l_;
    split1(q, h_, l_); xqh[off] = h_; xql[off] = l_;
    float k = fmaf(kwl[hh * 3 + 0], a0,
              fmaf(kwl[hh * 3 + 1], a1, fmaf(kwl[hh * 3 + 2], a2, kbl[hh] + xm)));
    k = fmaxf(k, 0.f);
    split1(k, h_, l_); xkh[off] = h_; xkl[off] = l_;
    float v = fmaf(vwl[hh * 3 + 0], a0,
              fmaf(vwl[hh * 3 + 1], a1, fmaf(vwl[hh * 3 + 2], a2, vbl[hh] + xm)));
    xv[off] = fmaxf(v, 0.f);
  }
}

// ---------- pass A: flash attention (log2 domain), V hi-only, 32KB LDS ----------
__global__ __launch_bounds__(256, 4) void k_attn(
    const ushort* __restrict__ xkh, const ushort* __restrict__ xkl,
    const ushort* __restrict__ xqh, const ushort* __restrict__ xql,
    const ushort* __restrict__ xvTh,
    float* __restrict__ auv, float* __restrict__ lse) {
  __shared__ ushort sQh[4096], sQl[4096];  // 2 bufs x 32x64
  __shared__ ushort sVh[4096];             // 2 bufs x 64x32
  __shared__ ushort sPh[2048], sPl[2048];  // 64x32
  int tid = threadIdx.x;
  int lane = tid & 63, w = tid >> 6;
  int l15 = lane & 15, g = lane >> 4;
  int nb = gridDim.x, chunk = nb >> 3, bid = blockIdx.x;
  int blk = (bid & 7) * chunk + (bid >> 3);  // XCD swizzle (nb % 8 == 0)
  int bh = blk >> 4, t0 = (blk & 15) << 6;
  size_t bhTT = (size_t)bh * TT;
  int trow = 16 * w + l15, psw = (trow >> 1) & 3;

  stage_async(sQh, xkh + (bhTT + t0) * NN, 64, tid);
  stage_async(sQl, xkl + (bhTT + t0) * NN, 64, tid);
  WAIT_VM0();
  BAR();
  short8 fKh[2], fKl[2];
#pragma unroll
  for (int ks = 0; ks < 2; ++ks) {
    fKh[ks] = frag(sQh, trow, g + 4 * ks);
    fKl[ks] = frag(sQl, trow, g + 4 * ks);
  }
  WAIT_LGKM0();
  BAR();
  stage_q32(sQh, xqh + bhTT * NN, tid);
  stage_q32(sQl, xql + bhTT * NN, tid);
  stage_v32(sVh, xvTh + bhTT * NN, tid);
  stage_q32(sQh + 2048, xqh + (bhTT + 32) * NN, tid);
  stage_q32(sQl + 2048, xql + (bhTT + 32) * NN, tid);
  stage_v32(sVh + 2048, xvTh + bhTT * NN + 32, tid);

  float m = -3.0e38f, lsum = 0.f;
  f32x4 O[4];
#pragma unroll
  for (int ct = 0; ct < 4; ++ct)
#pragma unroll
    for (int r = 0; r < 4; ++r) O[ct][r] = 0.f;

  for (int ut = 0; ut < 32; ++ut) {
    int cur = ut & 1;
    if (ut < 31) WAIT_VM3(); else WAIT_VM0();
    BAR();
    const ushort* cQh = sQh + cur * 2048;
    const ushort* cQl = sQl + cur * 2048;
    const ushort* cVh = sVh + cur * 2048;

    __builtin_amdgcn_s_setprio(1);
    f32x4 S[2];
#pragma unroll
    for (int rt = 0; rt < 2; ++rt) {
      f32x4 a = {0.f, 0.f, 0.f, 0.f};
#pragma unroll
      for (int ks = 0; ks < 2; ++ks) {
        short8 aQh = frag(cQh, 16 * rt + l15, g + 4 * ks);
        short8 aQl = frag(cQl, 16 * rt + l15, g + 4 * ks);
        a = MFMA16(aQh, fKh[ks], a);
        a = MFMA16(aQh, fKl[ks], a);
        a = MFMA16(aQl, fKh[ks], a);
      }
      S[rt] = a;
    }
    __builtin_amdgcn_s_setprio(0);

    float tmax = S[0][0];
#pragma unroll
    for (int rt = 0; rt < 2; ++rt)
#pragma unroll
      for (int r = 0; r < 4; ++r) tmax = fmaxf(tmax, S[rt][r]);
    tmax = fmaxf(tmax, __shfl_xor(tmax, 16, 64));
    tmax = fmaxf(tmax, __shfl_xor(tmax, 32, 64));
    if (__ballot(tmax > m + 5.77f)) {  // T13 deferred rescale (log2 domain)
      float mnew = fmaxf(m, tmax);
      float f = exp2_(m - mnew);
      float fr[4];
#pragma unroll
      for (int r = 0; r < 4; ++r) fr[r] = __shfl(f, (lane & 48) | (4 * g + r), 64);
#pragma unroll
      for (int ct = 0; ct < 4; ++ct)
#pragma unroll
        for (int r = 0; r < 4; ++r) O[ct][r] *= fr[r];
      lsum *= f;
      m = mnew;
    }
    float psum = 0.f;
    uint2 ph[2], plo[2];
#pragma unroll
    for (int rt = 0; rt < 2; ++rt) {
      float p0 = exp2_(S[rt][0] - m), p1 = exp2_(S[rt][1] - m);
      float p2 = exp2_(S[rt][2] - m), p3 = exp2_(S[rt][3] - m);
      psum += (p0 + p1) + (p2 + p3);
      uint lo0, lo1;
      ph[rt].x = pack2(p0, p1, lo0);
      ph[rt].y = pack2(p2, p3, lo1);
      plo[rt].x = lo0; plo[rt].y = lo1;
    }
    psum += __shfl_xor(psum, 16, 64);
    psum += __shfl_xor(psum, 32, 64);
    lsum += psum;
#pragma unroll
    for (int rt = 0; rt < 2; ++rt) {
      int ch = 2 * rt + (g >> 1);
      int off = trow * 32 + ((ch ^ psw) << 3) + ((g & 1) << 2);
      *(uint2*)(sPh + off) = ph[rt];
      *(uint2*)(sPl + off) = plo[rt];
    }
    WAIT_LGKM0();
    __builtin_amdgcn_sched_barrier(0);
    __builtin_amdgcn_s_setprio(1);
    {
      short8 aPh = frag32(sPh, trow, g);
      short8 aPl = frag32(sPl, trow, g);
#pragma unroll
      for (int ct = 0; ct < 4; ++ct) {
        short8 bVh = frag32(cVh, 16 * ct + l15, g);
        O[ct] = MFMA16(aPh, bVh, O[ct]);
        O[ct] = MFMA16(aPl, bVh, O[ct]);
      }
    }
    __builtin_amdgcn_s_setprio(0);
    WAIT_LGKM0();
    BAR();
    if (ut < 30) {
      int tn = ut + 2;
      stage_q32(sQh + cur * 2048, xqh + (bhTT + tn * 32) * NN, tid);
      stage_q32(sQl + cur * 2048, xql + (bhTT + tn * 32) * NN, tid);
      stage_v32(sVh + cur * 2048, xvTh + bhTT * NN + tn * 32, tid);
    }
  }
  float il = 1.0f / lsum;
  float ilr[4];
#pragma unroll
  for (int r = 0; r < 4; ++r) ilr[r] = __shfl(il, (lane & 48) | (4 * g + r), 64);
#pragma unroll
  for (int r = 0; r < 4; ++r) {
    size_t row = (bhTT + t0 + 16 * w + 4 * g + r) * NN;
#pragma unroll
    for (int ct = 0; ct < 4; ++ct) auv[row + 16 * ct + l15] = O[ct][r] * ilr[r];
  }
  if (g == 0) lse[bhTT + t0 + trow] = m + log2_(lsum);  // log2-domain lse
}

// ---------- pass B: h1 = relu(P^T @ W1 + b1), W1 hi-only, h1 out bf16 ----------
__global__ __launch_bounds__(256, 4) void k_h1(
    const ushort* __restrict__ xkh, const ushort* __restrict__ xkl,
    const ushort* __restrict__ xqh, const ushort* __restrict__ xql,
    const ushort* __restrict__ w1Th,
    const float* __restrict__ lse, const float* __restrict__ b1,
    ushort* __restrict__ h1h) {
  __shared__ ushort sKh[4096], sKl[4096];  // 2 bufs x 32x64 (prologue: Q tile)
  __shared__ ushort sWh[4096];             // 2 bufs x 64x32
  __shared__ ushort sPh[2048], sPl[2048];
  __shared__ float sL[1024];
  int tid = threadIdx.x;
  int lane = tid & 63, w = tid >> 6;
  int l15 = lane & 15, g = lane >> 4;
  int nb = gridDim.x, chunk = nb >> 3, bid = blockIdx.x;
  int blk = (bid & 7) * chunk + (bid >> 3);
  int bh = blk >> 4, h = bh & (HH - 1), a0 = (blk & 15) << 6;
  size_t bhTT = (size_t)bh * TT;
  size_t wbase = (size_t)h * NN * TT;
  int arow = 16 * w + l15, psw = (arow >> 1) & 3;

  stage_async(sKh, xqh + (bhTT + a0) * NN, 64, tid);
  stage_async(sKl, xql + (bhTT + a0) * NN, 64, tid);
  WAIT_VM0();
  BAR();
  short8 fQh[2], fQl[2];
#pragma unroll
  for (int ks = 0; ks < 2; ++ks) {
    fQh[ks] = frag(sKh, arow, g + 4 * ks);
    fQl[ks] = frag(sKl, arow, g + 4 * ks);
  }
#pragma unroll
  for (int i = 0; i < 4; ++i) sL[tid + i * 256] = lse[bhTT + tid + i * 256];
  WAIT_LGKM0();
  BAR();
  stage_q32(sKh, xkh + bhTT * NN, tid);
  stage_q32(sKl, xkl + bhTT * NN, tid);
  stage_v32(sWh, w1Th + wbase, tid);
  stage_q32(sKh + 2048, xkh + (bhTT + 32) * NN, tid);
  stage_q32(sKl + 2048, xkl + (bhTT + 32) * NN, tid);
  stage_v32(sWh + 2048, w1Th + wbase + 32, tid);

  f32x4 acc[4];
#pragma unroll
  for (int ct = 0; ct < 4; ++ct)
#pragma unroll
    for (int r = 0; r < 4; ++r) acc[ct][r] = 0.f;

  for (int tt = 0; tt < 32; ++tt) {
    int cur = tt & 1;
    if (tt < 31) WAIT_VM3(); else WAIT_VM0();
    BAR();
    const ushort* cKh = sKh + cur * 2048;
    const ushort* cKl = sKl + cur * 2048;
    const ushort* cWh = sWh + cur * 2048;

    __builtin_amdgcn_s_setprio(1);
    f32x4 S[2];
#pragma unroll
    for (int rt = 0; rt < 2; ++rt) {
      f32x4 a = {0.f, 0.f, 0.f, 0.f};
#pragma unroll
      for (int ks = 0; ks < 2; ++ks) {
        short8 aKh = frag(cKh, 16 * rt + l15, g + 4 * ks);
        short8 aKl = frag(cKl, 16 * rt + l15, g + 4 * ks);
        a = MFMA16(aKh, fQh[ks], a);
        a = MFMA16(aKh, fQl[ks], a);
        a = MFMA16(aKl, fQh[ks], a);
      }
      S[rt] = a;
    }
    __builtin_amdgcn_s_setprio(0);

    uint2 ph[2], plo[2];
#pragma unroll
    for (int rt = 0; rt < 2; ++rt) {
      f32x4 lv = *(const f32x4*)(sL + tt * 32 + 16 * rt + 4 * g);
      float p0 = exp2_(S[rt][0] - lv[0]);
      float p1 = exp2_(S[rt][1] - lv[1]);
      float p2 = exp2_(S[rt][2] - lv[2]);
      float p3 = exp2_(S[rt][3] - lv[3]);
      uint lo0, lo1;
      ph[rt].x = pack2(p0, p1, lo0);
      ph[rt].y = pack2(p2, p3, lo1);
      plo[rt].x = lo0; plo[rt].y = lo1;
    }
#pragma unroll
    for (int rt = 0; rt < 2; ++rt) {
      int ch = 2 * rt + (g >> 1);
      int off = arow * 32 + ((ch ^ psw) << 3) + ((g & 1) << 2);
      *(uint2*)(sPh + off) = ph[rt];
      *(uint2*)(sPl + off) = plo[rt];
    }
    WAIT_LGKM0();
    __builtin_amdgcn_sched_barrier(0);
    __builtin_amdgcn_s_setprio(1);
    {
      short8 aPh = frag32(sPh, arow, g);
      short8 aPl = frag32(sPl, arow, g);
#pragma unroll
      for (int ct = 0; ct < 4; ++ct) {
        short8 bWh = frag32(cWh, 16 * ct + l15, g);
        acc[ct] = MFMA16(aPh, bWh, acc[ct]);
        acc[ct] = MFMA16(aPl, bWh, acc[ct]);
      }
    }
    __builtin_amdgcn_s_setprio(0);
    WAIT_LGKM0();
    BAR();
    if (tt < 30) {
      int tn = tt + 2;
      stage_q32(sKh + cur * 2048, xkh + (bhTT + tn * 32) * NN, tid);
      stage_q32(sKl + cur * 2048, xkl + (bhTT + tn * 32) * NN, tid);
      stage_v32(sWh + cur * 2048, w1Th + wbase + tn * 32, tid);
    }
  }
#pragma unroll
  for (int ct = 0; ct < 4; ++ct) {
    float bb = b1[h * 64 + 16 * ct + l15];
#pragma unroll
    for (int r = 0; r < 4; ++r)
      h1h[(bhTT + a0 + 16 * w + 4 * g + r) * NN + 16 * ct + l15] =
          f2bfr(fmaxf(acc[ct][r] + bb, 0.f));
  }
}

// gate: h2=relu(h1@W2+b2); g=softmax(h2@W3+b3); ho=g0*auv+g1*xv -> bf16 hi/lo
__global__ __launch_bounds__(256) void k_gate(
    const ushort* __restrict__ h1h, const float* __restrict__ xv,
    const ushort* __restrict__ w2Th, const float* __restrict__ b2l,
    const float* __restrict__ W3l, const float* __restrict__ b3l,
    const float* __restrict__ auv, ushort* __restrict__ hoh,
    ushort* __restrict__ hol) {
  __shared__ ushort sA[4096], sB[4096];
  __shared__ float sred[2][64][4];
  __shared__ float sg[64][2];
  int tid = threadIdx.x;
  int lane = tid & 63, w = tid >> 6;
  int l15 = lane & 15, g = lane >> 4;
  int blk = blockIdx.x;
  int bh = blk >> 4, t0 = (blk & 15) << 6, h = bh & (HH - 1);
  size_t bhTT = (size_t)bh * TT;
  stage_async(sA, h1h + (bhTT + t0) * NN, 64, tid);
  stage_async(sB, w2Th + (size_t)h * 4096, 64, tid);
  WAIT_VM0();
  BAR();
  f32x4 acc[4];
#pragma unroll
  for (int rt = 0; rt < 4; ++rt)
#pragma unroll
    for (int r = 0; r < 4; ++r) acc[rt][r] = 0.f;
#pragma unroll
  for (int ks = 0; ks < 2; ++ks) {
    short8 bB = frag(sB, 16 * w + l15, g + 4 * ks);
#pragma unroll
    for (int rt = 0; rt < 4; ++rt)
      acc[rt] = MFMA16(frag(sA, 16 * rt + l15, g + 4 * ks), bB, acc[rt]);
  }
  int col = 16 * w + l15;
  float b2c = b2l[h * 64 + col];
  float w30 = W3l[h * 128 + col * 2 + 0];
  float w31 = W3l[h * 128 + col * 2 + 1];
#pragma unroll
  for (int rt = 0; rt < 4; ++rt)
#pragma unroll
    for (int r = 0; r < 4; ++r) {
      float v = fmaxf(acc[rt][r] + b2c, 0.f);
      float z0 = v * w30, z1 = v * w31;
#pragma unroll
      for (int mm = 1; mm < 16; mm <<= 1) {
        z0 += __shfl_xor(z0, mm, 64);
        z1 += __shfl_xor(z1, mm, 64);
      }
      if (l15 == 0) {
        int row = 16 * rt + 4 * g + r;
        sred[0][row][w] = z0;
        sred[1][row][w] = z1;
      }
    }
  __syncthreads();
  if (tid < 64) {
    float z0 = sred[0][tid][0] + sred[0][tid][1] + sred[0][tid][2] + sred[0][tid][3] +
               b3l[h * 2 + 0];
    float z1 = sred[1][tid][0] + sred[1][tid][1] + sred[1][tid][2] + sred[1][tid][3] +
               b3l[h * 2 + 1];
    float g0 = 1.0f / (1.0f + __expf(z1 - z0));
    sg[tid][0] = g0;
    sg[tid][1] = 1.0f - g0;
  }
  __syncthreads();
#pragma unroll
  for (int rr = 0; rr < 16; ++rr) {
    int row = 16 * w + rr;
    size_t off = (bhTT + t0 + row) * 64 + lane;
    float ho = sg[row][0] * auv[off] + sg[row][1] * xv[off];
    ushort hb, lb;
    split1(ho, hb, lb);
    hoh[off] = hb;
    hol[off] = lb;
  }
}

// out1 = LN(x + concat_h(ho) @ Wlt) -> bf16 hi/lo
__global__ __launch_bounds__(256, 2) void k_merge(
    const float* __restrict__ x, const ushort* __restrict__ hoh,
    const ushort* __restrict__ hol, const ushort* __restrict__ wth,
    const ushort* __restrict__ wtl, const float* __restrict__ g1l,
    const float* __restrict__ b1l, ushort* __restrict__ out1h,
    ushort* __restrict__ out1l) {
  __shared__ ushort sAh[2][4096], sAl[2][4096], sBh[2][4096], sBl[2][4096];
  __shared__ float sred[2][64][4];
  __shared__ float sfin[64][2];
  int tid = threadIdx.x;
  int lane = tid & 63, w = tid >> 6;
  int l15 = lane & 15, g = lane >> 4;
  int blk = blockIdx.x;
  int b = blk >> 4, t0 = (blk & 15) << 6;

  {
    size_t ab0 = (((size_t)b * HH + 0) * TT + t0) * NN;
    size_t ab1 = (((size_t)b * HH + 1) * TT + t0) * NN;
    stage_async(sAh[0], hoh + ab0, 64, tid);
    stage_async(sAl[0], hol + ab0, 64, tid);
    stage_async(sBh[0], wth, 512, tid);
    stage_async(sBl[0], wtl, 512, tid);
    stage_async(sAh[1], hoh + ab1, 64, tid);
    stage_async(sAl[1], hol + ab1, 64, tid);
    stage_async(sBh[1], wth + 64, 512, tid);
    stage_async(sBl[1], wtl + 64, 512, tid);
  }

  f32x4 acc[4];
#pragma unroll
  for (int rt = 0; rt < 4; ++rt)
#pragma unroll
    for (int r = 0; r < 4; ++r) acc[rt][r] = 0.f;

  for (int h = 0; h < 8; ++h) {
    int cur = h & 1;
    if (h < 7) WAIT_VM8(); else WAIT_VM0();
    BAR();
    __builtin_amdgcn_s_setprio(1);
#pragma unroll
    for (int ks = 0; ks < 2; ++ks) {
      short8 bBh = frag(sBh[cur], 16 * w + l15, g + 4 * ks);
      short8 bBl = frag(sBl[cur], 16 * w + l15, g + 4 * ks);
#pragma unroll
      for (int rt = 0; rt < 4; ++rt) {
        short8 aAh = frag(sAh[cur], 16 * rt + l15, g + 4 * ks);
        short8 aAl = frag(sAl[cur], 16 * rt + l15, g + 4 * ks);
        acc[rt] = MFMA16(aAh, bBh, acc[rt]);
        acc[rt] = MFMA16(aAh, bBl, acc[rt]);
        acc[rt] = MFMA16(aAl, bBh, acc[rt]);
      }
    }
    __builtin_amdgcn_s_setprio(0);
    WAIT_LGKM0();
    BAR();
    if (h < 6) {
      int hn = h + 2;
      size_t ab = (((size_t)b * HH + hn) * TT + t0) * NN;
      stage_async(sAh[cur], hoh + ab, 64, tid);
      stage_async(sAl[cur], hol + ab, 64, tid);
      stage_async(sBh[cur], wth + hn * 64, 512, tid);
      stage_async(sBl[cur], wtl + hn * 64, 512, tid);
    }
  }
  int mcol = 16 * w + l15;
  float vv[4][4];
#pragma unroll
  for (int rt = 0; rt < 4; ++rt)
#pragma unroll
    for (int r = 0; r < 4; ++r) {
      int row = 16 * rt + 4 * g + r;
      vv[rt][r] = acc[rt][r] + x[((size_t)b * TT + t0 + row) * 64 + mcol];
    }
#pragma unroll
  for (int rt = 0; rt < 4; ++rt)
#pragma unroll
    for (int r = 0; r < 4; ++r) {
      float s1 = vv[rt][r], s2 = vv[rt][r] * vv[rt][r];
#pragma unroll
      for (int mm = 1; mm < 16; mm <<= 1) {
        s1 += __shfl_xor(s1, mm, 64);
        s2 += __shfl_xor(s2, mm, 64);
      }
      if (l15 == 0) {
        int row = 16 * rt + 4 * g + r;
        sred[0][row][w] = s1;
        sred[1][row][w] = s2;
      }
    }
  __syncthreads();
  if (tid < 64) {
    float a1 = sred[0][tid][0] + sred[0][tid][1] + sred[0][tid][2] + sred[0][tid][3];
    float a2 = sred[1][tid][0] + sred[1][tid][1] + sred[1][tid][2] + sred[1][tid][3];
    float mean = a1 * (1.0f / 64.0f);
    float var = a2 * (1.0f / 64.0f) - mean * mean;
    sfin[tid][0] = mean;
    sfin[tid][1] = rsqrtf(var + EPSV);
  }
  __syncthreads();
  float gg = g1l[mcol], bb = b1l[mcol];
#pragma unroll
  for (int rt = 0; rt < 4; ++rt)
#pragma unroll
    for (int r = 0; r < 4; ++r) {
      int row = 16 * rt + 4 * g + r;
      float mean = sfin[row][0], rstd = sfin[row][1];
      float val = (vv[rt][r] - mean) * rstd * gg + bb;
      ushort hb, lb;
      split1(val, hb, lb);
      size_t idx = ((size_t)b * TT + t0 + row) * 64 + mcol;
      out1h[idx] = hb;
      out1l[idx] = lb;
    }
}

// ffn via MFMA: gc = out1@K3s + sclb; f1 = relu(gc + out1); f2 = f1@elW + elb;
// x = LN(out1 + f2).  block = (b, 32-t tile)
__global__ __launch_bounds__(256) void k_ffn(
    const ushort* __restrict__ o1h_, const ushort* __restrict__ o1l_,
    const float* __restrict__ sclb_l, const ushort* __restrict__ k3sTh,
    const ushort* __restrict__ elWTh, const float* __restrict__ elbl,
    const float* __restrict__ g2l, const float* __restrict__ b2l,
    float* __restrict__ xout) {
  __shared__ ushort sAh[2048], sAl[2048];  // 32x64
  __shared__ ushort sB1[4096], sB2[4096];  // K3sT, elWT
  __shared__ float sred[2][32][4];
  __shared__ float sfin[32][2];
  int tid = threadIdx.x;
  int lane = tid & 63, w = tid >> 6;
  int l15 = lane & 15, g = lane >> 4;
  int blk = blockIdx.x;
  int b = blk >> 5, t0 = (blk & 31) << 5;
  size_t rb = ((size_t)b * TT + t0) * 64;

  stage_q32(sAh, o1h_ + rb, tid);
  stage_q32(sAl, o1l_ + rb, tid);
  stage_async(sB1, k3sTh, 64, tid);
  stage_async(sB2, elWTh, 64, tid);
  WAIT_VM0();
  BAR();

  int col = 16 * w + l15;
  f32x4 acc[2];
#pragma unroll
  for (int rt = 0; rt < 2; ++rt)
#pragma unroll
    for (int r = 0; r < 4; ++r) acc[rt][r] = 0.f;
#pragma unroll
  for (int ks = 0; ks < 2; ++ks) {
    short8 bB = frag(sB1, col, g + 4 * ks);
#pragma unroll
    for (int rt = 0; rt < 2; ++rt) {
      acc[rt] = MFMA16(frag(sAh, 16 * rt + l15, g + 4 * ks), bB, acc[rt]);
      acc[rt] = MFMA16(frag(sAl, 16 * rt + l15, g + 4 * ks), bB, acc[rt]);
    }
  }
  float sclb = sclb_l[0];
  int cch = col >> 3, cin = col & 7;
  float o1v[2][4], f1v[2][4];
#pragma unroll
  for (int rt = 0; rt < 2; ++rt)
#pragma unroll
    for (int r = 0; r < 4; ++r) {
      int row = 16 * rt + 4 * g + r;
      int a = row * 64 + (((cch ^ (row & 7)) << 3)) + cin;
      float o1 = bf2f(sAh[a]) + bf2f(sAl[a]);
      o1v[rt][r] = o1;
      f1v[rt][r] = fmaxf(acc[rt][r] + sclb + o1, 0.f);
    }
  __syncthreads();
#pragma unroll
  for (int rt = 0; rt < 2; ++rt)
#pragma unroll
    for (int r = 0; r < 4; ++r) {
      int row = 16 * rt + 4 * g + r;
      int a = row * 64 + (((cch ^ (row & 7)) << 3)) + cin;
      ushort hb, lb;
      split1(f1v[rt][r], hb, lb);
      sAh[a] = hb;
      sAl[a] = lb;
    }
  __syncthreads();
  f32x4 acc2[2];
#pragma unroll
  for (int rt = 0; rt < 2; ++rt)
#pragma unroll
    for (int r = 0; r < 4; ++r) acc2[rt][r] = 0.f;
#pragma unroll
  for (int ks = 0; ks < 2; ++ks) {
    short8 bB = frag(sB2, col, g + 4 * ks);
#pragma unroll
    for (int rt = 0; rt < 2; ++rt) {
      acc2[rt] = MFMA16(frag(sAh, 16 * rt + l15, g + 4 * ks), bB, acc2[rt]);
      acc2[rt] = MFMA16(frag(sAl, 16 * rt + l15, g + 4 * ks), bB, acc2[rt]);
    }
  }
  float elb = elbl[col];
  float vv[2][4];
#pragma unroll
  for (int rt = 0; rt < 2; ++rt)
#pragma unroll
    for (int r = 0; r < 4; ++r) {
      vv[rt][r] = o1v[rt][r] + acc2[rt][r] + elb;
      float s1 = vv[rt][r], s2 = vv[rt][r] * vv[rt][r];
#pragma unroll
      for (int mm = 1; mm < 16; mm <<= 1) {
        s1 += __shfl_xor(s1, mm, 64);
        s2 += __shfl_xor(s2, mm, 64);
      }
      if (l15 == 0) {
        int row = 16 * rt + 4 * g + r;
        sred[0][row][w] = s1;
        sred[1][row][w] = s2;
      }
    }
  __syncthreads();
  if (tid < 32) {
    float a1 = sred[0][tid][0] + sred[0][tid][1] + sred[0][tid][2] + sred[0][tid][3];
    float a2 = sred[1][tid][0] + sred[1][tid][1] + sred[1][tid][2] + sred[1][tid][3];
    float mean = a1 * (1.0f / 64.0f);
    float var = a2 * (1.0f / 64.0f) - mean * mean;
    sfin[tid][0] = mean;
    sfin[tid][1] = rsqrtf(var + EPSV);
  }
  __syncthreads();
  float gg = g2l[col], bb = b2l[col];
#pragma unroll
  for (int rt = 0; rt < 2; ++rt)
#pragma unroll
    for (int r = 0; r < 4; ++r) {
      int row = 16 * rt + 4 * g + r;
      xout[rb + (size_t)row * 64 + col] =
          (vv[rt][r] - sfin[row][0]) * sfin[row][1] * gg + bb;
    }
}

__global__ __launch_bounds__(256) void k_final(
    const float* __restrict__ x, const float* __restrict__ fW1,
    const float* __restrict__ fb1, const float* __restrict__ fW2,
    const float* __restrict__ fb2, float* __restrict__ out) {
  __shared__ float pl[4][64];
  int tid = threadIdx.x;
  int lane = tid & 63, w = tid >> 6;
  size_t b = blockIdx.x;
  float s = 0.f;
  for (int t = 256 * w; t < 256 * w + 256; ++t) s += x[(b * TT + t) * 64 + lane];
  pl[w][lane] = s;
  __syncthreads();
  if (tid < 64) pl[0][tid] = (pl[0][tid] + pl[1][tid] + pl[2][tid] + pl[3][tid]) * (1.0f / TT);
  __syncthreads();
  if (tid < 64) {
    float hv = 0.f;
    if (lane < 32) {
      hv = fb1[lane];
#pragma unroll 8
      for (int n = 0; n < 64; ++n) hv = fmaf(pl[0][n], fW1[n * 32 + lane], hv);
      hv = fmaxf(hv, 0.f) * fW2[lane];
    }
#pragma unroll
    for (int m = 1; m < 64; m <<= 1) hv += __shfl_xor(hv, m, 64);
    if (lane == 0) out[b] = hv + fb2[0];
  }
}

extern "C" void kernel_launch(void* const* d_in, const int* in_sizes, int n_in,
                              void* d_out, int out_size, void* d_ws, size_t ws_size,
                              hipStream_t stream) {
  const float* inputs = (const float*)d_in[0];
  const float* pos_emb = (const float*)d_in[1];
  const float* K3 = (const float*)d_in[2];
  const float* qw = (const float*)d_in[3];
  const float* qb = (const float*)d_in[4];
  const float* kw = (const float*)d_in[5];
  const float* kb = (const float*)d_in[6];
  const float* vw = (const float*)d_in[7];
  const float* vb = (const float*)d_in[8];
  const float* tqW1 = (const float*)d_in[9];
  const float* tqb1 = (const float*)d_in[10];
  const float* tqW2 = (const float*)d_in[11];
  const float* tqb2 = (const float*)d_in[12];
  const float* tqW3 = (const float*)d_in[13];
  const float* tqb3 = (const float*)d_in[14];
  const float* Wlt = (const float*)d_in[15];
  const float* ln1g = (const float*)d_in[16];
  const float* ln1b = (const float*)d_in[17];
  const float* ln2g = (const float*)d_in[18];
  const float* ln2b = (const float*)d_in[19];
  const float* sclw = (const float*)d_in[20];
  const float* sclb = (const float*)d_in[21];
  const float* elW = (const float*)d_in[22];
  const float* elb = (const float*)d_in[23];
  const float* fW1 = (const float*)d_in[24];
  const float* fb1 = (const float*)d_in[25];
  const float* fW2 = (const float*)d_in[26];
  const float* fb2 = (const float*)d_in[27];
  float* out = (float*)d_out;
  float* ws_f = (float*)d_ws;

  const size_t TN = (size_t)TT * NN;
  const size_t HTN = (size_t)HH * TT * NN;
  const size_t W1T_ELEMS = (size_t)LL * HH * NN * TT;  // ushorts
  const size_t WLT_ELEMS = (size_t)LL * 64 * 512;      // ushorts

  ushort* k3sTh = (ushort*)ws_f;                      // LL*4096
  ushort* w1Th = k3sTh + (size_t)LL * 4096;           // W1T_ELEMS
  ushort* wth = w1Th + W1T_ELEMS;                     // WLT_ELEMS
  ushort* wtl = wth + WLT_ELEMS;                      // WLT_ELEMS
  ushort* w2Th = wtl + WLT_ELEMS;                     // LL*HH*4096
  ushort* elWTh = w2Th + (size_t)LL * HH * 4096;      // LL*4096
  size_t base_ush = (size_t)LL * 4096 + W1T_ELEMS + 2 * WLT_ELEMS +
                    (size_t)LL * HH * 4096 + (size_t)LL * 4096;
  const size_t base = (base_ush + 1) / 2;  // words

  for (int l = 0; l < LL; ++l)
    k_k3s<<<16, 256, 0, stream>>>(K3, sclw + l * KSS, k3sTh + (size_t)l * 4096);
  k_tsplit<<<LL * HH * 16, 256, 0, stream>>>(tqW1, w1Th);
  k_tsplitW<<<LL * 8, 256, 0, stream>>>(Wlt, wth, wtl);
  k_tsplitSq<<<LL * HH, 256, 0, stream>>>(tqW2, w2Th);
  k_tsplitSq<<<LL, 256, 0, stream>>>(elW, elWTh);

  const size_t per_b = TN + 2 * HTN + (size_t)HH * TT + TN + HTN / 2 + 2 * HTN +
                       HTN / 2 + HTN;
  size_t avail = ws_size / sizeof(float);
  avail = (avail > base) ? avail - base : 0;
  int Bc = (int)(avail / per_b);
  if (Bc > BB) Bc = BB;
  if (Bc < 1) Bc = 1;

  for (int b0 = 0; b0 < BB; b0 += Bc) {
    int bc = (BB - b0 < Bc) ? (BB - b0) : Bc;
    float* x = ws_f + base;
    float* xv = x + (size_t)bc * TN;
    float* auv = xv + (size_t)bc * HTN;
    float* lseb = auv + (size_t)bc * HTN;
    ushort* out1h = (ushort*)(lseb + (size_t)bc * HH * TT);
    ushort* out1l = out1h + (size_t)bc * TN;
    ushort* h1h = out1l + (size_t)bc * TN;
    ushort* xqh = h1h + (size_t)bc * HTN;
    ushort* xql = xqh + (size_t)bc * HTN;
    ushort* xkh = xql + (size_t)bc * HTN;
    ushort* xkl = xkh + (size_t)bc * HTN;
    ushort* xvTh = xkl + (size_t)bc * HTN;
    ushort* hoh = xvTh + (size_t)bc * HTN;
    ushort* hol = hoh + (size_t)bc * HTN;

    int total = bc * (int)TN;
    k_addpos<<<(total + 255) / 256, 256, 0, stream>>>(inputs + (size_t)b0 * TN, pos_emb, x,
                                                      total);
    for (int l = 0; l < LL; ++l) {
      k_gconv<<<bc * TT, 64, 0, stream>>>(x, K3, qw + l * HH * KSS, qb + l * HH,
                                          kw + l * HH * KSS, kb + l * HH,
                                          vw + l * HH * KSS, vb + l * HH,
                                          xqh, xql, xkh, xkl, xv);
      k_tsplit<<<bc * HH * 16, 256, 0, stream>>>(xv, xvTh);
      k_attn<<<bc * HH * 16, 256, 0, stream>>>(xkh, xkl, xqh, xql, xvTh, auv, lseb);
      k_h1<<<bc * HH * 16, 256, 0, stream>>>(
          xkh, xkl, xqh, xql, w1Th + (size_t)l * HH * NN * TT, lseb,
          tqb1 + l * HH * DD1, h1h);
      k_gate<<<bc * HH * 16, 256, 0, stream>>>(
          h1h, xv, w2Th + (size_t)l * HH * 4096, tqb2 + l * HH * DD1,
          tqW3 + (size_t)l * HH * DD1 * 2, tqb3 + l * HH * 2, auv, hoh, hol);
      k_merge<<<bc * 16, 256, 0, stream>>>(x, hoh, hol, wth + (size_t)l * 64 * 512,
                                           wtl + (size_t)l * 64 * 512, ln1g + l * NN,
                                           ln1b + l * NN, out1h, out1l);
      k_ffn<<<bc * 32, 256, 0, stream>>>(out1h, out1l, sclb + l,
                                         k3sTh + (size_t)l * 4096,
                                         elWTh + (size_t)l * 4096, elb + l * NN,
                                         ln2g + l * NN, ln2b + l * NN, x);
    }
    k_final<<<bc, 256, 0, stream>>>(x, fW1, fb1, fW2, fb2, out + b0);
  }
}

// Round 9
// 293.681 us; speedup vs baseline: 2.5457x; 1.1717x over previous
//
#include <hip/hip_runtime.h>

typedef __attribute__((ext_vector_type(8))) short short8;
typedef __attribute__((ext_vector_type(4))) float f32x4;

#define BB 8
#define TT 1024
#define NN 64
#define HH 8
#define LL 2
#define KSS 3
#define DD1 64
#define EPSV 1e-6f
#define LOG2E 1.4426950408889634f

#define MFMA16(a, b, c) __builtin_amdgcn_mfma_f32_16x16x32_bf16(a, b, c, 0, 0, 0)
#define BAR() __builtin_amdgcn_s_barrier()
#define WAIT_VM8() asm volatile("s_waitcnt vmcnt(8)" ::: "memory")
#define WAIT_VM3() asm volatile("s_waitcnt vmcnt(3)" ::: "memory")
#define WAIT_VM2() asm volatile("s_waitcnt vmcnt(2)" ::: "memory")
#define WAIT_VM0() asm volatile("s_waitcnt vmcnt(0)" ::: "memory")
#define WAIT_LGKM0() asm volatile("s_waitcnt lgkmcnt(0)" ::: "memory")

__device__ __forceinline__ float exp2_(float x) { return __builtin_amdgcn_exp2f(x); }
__device__ __forceinline__ float log2_(float x) { return __builtin_amdgcn_logf(x); }

// ---- truncation-based hi/lo bf16 split (hi error lands exactly in lo) ----
__device__ __forceinline__ void split1(float x, ushort& hi, ushort& lo) {
  uint u = __float_as_uint(x);
  hi = (ushort)(u >> 16);
  float hf = __uint_as_float(u & 0xffff0000u);
  lo = (ushort)(__float_as_uint(x - hf) >> 16);
}
__device__ __forceinline__ uint pack2(float a, float b, uint& lo) {
  uint ua = __float_as_uint(a), ub = __float_as_uint(b);
  float ra = __uint_as_float(ua & 0xffff0000u);
  float rb = __uint_as_float(ub & 0xffff0000u);
  lo = (__float_as_uint(a - ra) >> 16) | (__float_as_uint(b - rb) & 0xffff0000u);
  return (ua >> 16) | (ub & 0xffff0000u);
}
// round-half-up packed pair (unbiased enough; 5 ops)
__device__ __forceinline__ uint pack2rhu(float a, float b) {
  uint ua = __float_as_uint(a) + 0x8000u;
  uint ub = __float_as_uint(b) + 0x8000u;
  return (ua >> 16) | (ub & 0xffff0000u);
}
// round-to-nearest-even bf16
__device__ __forceinline__ ushort f2bfr(float x) {
  union { float f; uint u; } v; v.f = x;
  uint r = (v.u + 0x7fffu + ((v.u >> 16) & 1u)) >> 16;
  return (ushort)r;
}
__device__ __forceinline__ float bf2f(ushort b) {
  union { uint u; float f; } v; v.u = ((uint)b) << 16; return v.f;
}

// ---- async global->LDS staging ----
__device__ __forceinline__ void gl2lds16(const ushort* g, ushort* l) {
  __builtin_amdgcn_global_load_lds(
      (const __attribute__((address_space(1))) void*)g,
      (__attribute__((address_space(3))) void*)l, 16, 0, 0);
}
// 64x64 tile, chunk swizzle c ^ (r&7); 2 gl_lds/wave
__device__ __forceinline__ void stage_async(ushort* __restrict__ s,
                                            const ushort* __restrict__ g,
                                            int stride, int tid) {
  int w = tid >> 6;
  int sub = (tid & 63) >> 3, c = tid & 7;
#pragma unroll
  for (int i = 0; i < 2; ++i) {
    int rb = (i * 4 + w) * 8;
    gl2lds16(g + (size_t)(rb + sub) * stride + ((c ^ sub) << 3), s + rb * 64);
  }
}
__device__ __forceinline__ short8 frag(const ushort* __restrict__ s, int row, int ch) {
  return *(const short8*)(s + row * 64 + ((ch ^ (row & 7)) << 3));
}
// 32x64 tile; 1 gl_lds/wave
__device__ __forceinline__ void stage_q32(ushort* __restrict__ s,
                                          const ushort* __restrict__ g, int tid) {
  int w = tid >> 6;
  int sub = (tid & 63) >> 3, c = tid & 7;
  int rb = w * 8, r = rb + sub;
  gl2lds16(g + (size_t)r * 64 + ((c ^ (r & 7)) << 3), s + rb * 64);
}
// 64x32 tile (stride 1024), chunk swizzle c ^ ((n>>1)&3); 1 gl_lds/wave
__device__ __forceinline__ void stage_v32(ushort* __restrict__ s,
                                          const ushort* __restrict__ g, int tid) {
  int w = tid >> 6;
  int noff = (tid & 63) >> 2, c = tid & 3;
  int nb = w * 16, n = nb + noff;
  gl2lds16(g + (size_t)n * 1024 + ((c ^ ((n >> 1) & 3)) << 3), s + nb * 32);
}
__device__ __forceinline__ short8 frag32(const ushort* __restrict__ s, int row, int g) {
  return *(const short8*)(s + row * 32 + ((g ^ ((row >> 1) & 3)) << 3));
}

// ---------- small kernels ----------

__global__ void k_addpos(const float* __restrict__ in, const float* __restrict__ pe,
                         float* __restrict__ x, int total) {
  int idx = blockIdx.x * 256 + threadIdx.x;
  if (idx < total) {
    int tn = idx & (TT * NN - 1);
    x[idx] = in[idx] + pe[tn];
  }
}

// K3s^T (bf16 RNE): out[m*64+n] = sum_k K3[n,k,m]*sclw[k]
__global__ void k_k3s(const float* __restrict__ K3, const float* __restrict__ sclwl,
                      ushort* __restrict__ dh) {
  int idx = blockIdx.x * 256 + threadIdx.x;  // < 4096
  int n = idx >> 6, m = idx & 63;
  float v = K3[n * 192 + m] * sclwl[0] + K3[n * 192 + 64 + m] * sclwl[1] +
            K3[n * 192 + 128 + m] * sclwl[2];
  dh[m * 64 + n] = f2bfr(v);
}

// transpose, hi-only RNE: src [mat][1024][64] f32 -> dh [mat][64][1024] bf16
__global__ __launch_bounds__(256) void k_tsplit(const float* __restrict__ src,
                                                ushort* __restrict__ dh) {
  __shared__ float st[64][65];
  int blk = blockIdx.x;
  int mat = blk >> 4, rt = blk & 15;
  int tid = threadIdx.x;
  size_t sbase = ((size_t)mat * TT + rt * 64) * 64;
#pragma unroll
  for (int i = 0; i < 4; ++i) {
    int idx = tid + i * 256;
    int r = idx >> 4, c4 = idx & 15;
    float4 v = *(const float4*)(src + sbase + r * 64 + c4 * 4);
    st[r][c4 * 4 + 0] = v.x; st[r][c4 * 4 + 1] = v.y;
    st[r][c4 * 4 + 2] = v.z; st[r][c4 * 4 + 3] = v.w;
  }
  __syncthreads();
  size_t obase = (size_t)mat * (64 * (size_t)TT) + rt * 64;
#pragma unroll
  for (int i = 0; i < 2; ++i) {
    int idx = tid + i * 256;
    int n = idx >> 3, c = idx & 7;
    uint hw[4];
#pragma unroll
    for (int j = 0; j < 4; ++j)
      hw[j] = (uint)f2bfr(st[c * 8 + 2 * j][n]) | ((uint)f2bfr(st[c * 8 + 2 * j + 1][n]) << 16);
    *(uint4*)(dh + obase + (size_t)n * TT + c * 8) = make_uint4(hw[0], hw[1], hw[2], hw[3]);
  }
}

// transpose+split Wlt (hi/lo)
__global__ __launch_bounds__(256) void k_tsplitW(const float* __restrict__ Wlt,
                                                 ushort* __restrict__ dh,
                                                 ushort* __restrict__ dl) {
  __shared__ float st[64][65];
  int blk = blockIdx.x;
  int l = blk >> 3, rt = blk & 7;
  int tid = threadIdx.x;
  size_t sbase = ((size_t)l * 512 + rt * 64) * 64;
#pragma unroll
  for (int i = 0; i < 4; ++i) {
    int idx = tid + i * 256;
    int r = idx >> 4, c4 = idx & 15;
    float4 v = *(const float4*)(Wlt + sbase + r * 64 + c4 * 4);
    st[r][c4 * 4 + 0] = v.x; st[r][c4 * 4 + 1] = v.y;
    st[r][c4 * 4 + 2] = v.z; st[r][c4 * 4 + 3] = v.w;
  }
  __syncthreads();
  size_t obase = (size_t)l * 64 * 512 + rt * 64;
#pragma unroll
  for (int i = 0; i < 2; ++i) {
    int idx = tid + i * 256;
    int n = idx >> 3, c = idx & 7;
    uint hw[4], lw[4];
#pragma unroll
    for (int j = 0; j < 4; ++j) hw[j] = pack2(st[c * 8 + 2 * j][n], st[c * 8 + 2 * j + 1][n], lw[j]);
    *(uint4*)(dh + obase + (size_t)n * 512 + c * 8) = make_uint4(hw[0], hw[1], hw[2], hw[3]);
    *(uint4*)(dl + obase + (size_t)n * 512 + c * 8) = make_uint4(lw[0], lw[1], lw[2], lw[3]);
  }
}

// square transpose, hi-only RNE: src [mat][64][64] -> dh [mat][64][64]^T
__global__ __launch_bounds__(256) void k_tsplitSq(const float* __restrict__ src,
                                                  ushort* __restrict__ dh) {
  __shared__ float st[64][65];
  int mat = blockIdx.x;
  int tid = threadIdx.x;
  size_t sbase = (size_t)mat * 4096;
#pragma unroll
  for (int i = 0; i < 4; ++i) {
    int idx = tid + i * 256;
    int r = idx >> 4, c4 = idx & 15;
    float4 v = *(const float4*)(src + sbase + r * 64 + c4 * 4);
    st[r][c4 * 4 + 0] = v.x; st[r][c4 * 4 + 1] = v.y;
    st[r][c4 * 4 + 2] = v.z; st[r][c4 * 4 + 3] = v.w;
  }
  __syncthreads();
#pragma unroll
  for (int i = 0; i < 2; ++i) {
    int idx = tid + i * 256;
    int d = idx >> 3, c = idx & 7;
    uint hw[4];
#pragma unroll
    for (int j = 0; j < 4; ++j)
      hw[j] = (uint)f2bfr(st[c * 8 + 2 * j][d]) | ((uint)f2bfr(st[c * 8 + 2 * j + 1][d]) << 16);
    *(uint4*)(dh + sbase + (size_t)d * 64 + c * 8) = make_uint4(hw[0], hw[1], hw[2], hw[3]);
  }
}

// gconv: 256-thr blocks, K3 staged in LDS, 4 (b,t) rows per block
__global__ __launch_bounds__(256) void k_gconv(
    const float* __restrict__ x, const float* __restrict__ K3,
    const float* __restrict__ qwl, const float* __restrict__ qbl,
    const float* __restrict__ kwl, const float* __restrict__ kbl,
    const float* __restrict__ vwl, const float* __restrict__ vbl,
    ushort* __restrict__ xqh, ushort* __restrict__ xql,
    ushort* __restrict__ xkh, float* __restrict__ xv) {
  __shared__ float sK3[12288];
  __shared__ float sx[4][64];
  int tid = threadIdx.x;
  int w = tid >> 6, lane = tid & 63;
#pragma unroll
  for (int i = 0; i < 12; ++i)
    ((float4*)sK3)[tid + i * 256] = ((const float4*)K3)[tid + i * 256];
  size_t bt = (size_t)blockIdx.x * 4 + w;
  size_t b = bt >> 10, t = bt & 1023;
  float xm = x[bt * 64 + lane];
  sx[w][lane] = xm;
  __syncthreads();
  float a0 = 0.f, a1 = 0.f, a2 = 0.f;
#pragma unroll 8
  for (int n = 0; n < 64; ++n) {
    float xn = sx[w][n];
    a0 = fmaf(xn, sK3[n * 192 + lane], a0);
    a1 = fmaf(xn, sK3[n * 192 + 64 + lane], a1);
    a2 = fmaf(xn, sK3[n * 192 + 128 + lane], a2);
  }
#pragma unroll
  for (int hh = 0; hh < HH; ++hh) {
    size_t off = (((size_t)b * HH + hh) * TT + t) * 64 + lane;
    float q = fmaf(qwl[hh * 3 + 0], a0,
              fmaf(qwl[hh * 3 + 1], a1, fmaf(qwl[hh * 3 + 2], a2, qbl[hh] + xm)));
    q = fmaxf(q, 0.f) * (0.015625f * LOG2E);  // fold 1/N and log2(e) into Q
    ushort h_, l_;
    split1(q, h_, l_); xqh[off] = h_; xql[off] = l_;
    float k = fmaf(kwl[hh * 3 + 0], a0,
              fmaf(kwl[hh * 3 + 1], a1, fmaf(kwl[hh * 3 + 2], a2, kbl[hh] + xm)));
    xkh[off] = f2bfr(fmaxf(k, 0.f));  // K hi-only, RNE
    float v = fmaf(vwl[hh * 3 + 0], a0,
              fmaf(vwl[hh * 3 + 1], a1, fmaf(vwl[hh * 3 + 2], a2, vbl[hh] + xm)));
    xv[off] = fmaxf(v, 0.f);
  }
}

// ---------- pass A: flash attention; K bf16, 2-term QK, P hi-only PV ----------
__global__ __launch_bounds__(256, 4) void k_attn(
    const ushort* __restrict__ xkh,
    const ushort* __restrict__ xqh, const ushort* __restrict__ xql,
    const ushort* __restrict__ xvTh,
    float* __restrict__ auv, float* __restrict__ lse) {
  __shared__ ushort sQh[4096], sQl[4096];  // 2 bufs x 32x64
  __shared__ ushort sVh[4096];             // 2 bufs x 64x32
  __shared__ ushort sPh[2048];             // 64x32
  int tid = threadIdx.x;
  int lane = tid & 63, w = tid >> 6;
  int l15 = lane & 15, g = lane >> 4;
  int nb = gridDim.x, chunk = nb >> 3, bid = blockIdx.x;
  int blk = (bid & 7) * chunk + (bid >> 3);  // XCD swizzle (nb % 8 == 0)
  int bh = blk >> 4, t0 = (blk & 15) << 6;
  size_t bhTT = (size_t)bh * TT;
  int trow = 16 * w + l15, psw = (trow >> 1) & 3;

  // prologue: K tile (64x64, hi-only) into sQ region; persistent K B-frags
  stage_async(sQh, xkh + (bhTT + t0) * NN, 64, tid);
  WAIT_VM0();
  BAR();
  short8 fKh[2];
#pragma unroll
  for (int ks = 0; ks < 2; ++ks) fKh[ks] = frag(sQh, trow, g + 4 * ks);
  WAIT_LGKM0();
  BAR();
  stage_q32(sQh, xqh + bhTT * NN, tid);
  stage_q32(sQl, xql + bhTT * NN, tid);
  stage_v32(sVh, xvTh + bhTT * NN, tid);
  stage_q32(sQh + 2048, xqh + (bhTT + 32) * NN, tid);
  stage_q32(sQl + 2048, xql + (bhTT + 32) * NN, tid);
  stage_v32(sVh + 2048, xvTh + bhTT * NN + 32, tid);

  float m = -3.0e38f, lsum = 0.f;
  f32x4 O[4];
#pragma unroll
  for (int ct = 0; ct < 4; ++ct)
#pragma unroll
    for (int r = 0; r < 4; ++r) O[ct][r] = 0.f;

  for (int ut = 0; ut < 32; ++ut) {
    int cur = ut & 1;
    if (ut < 31) WAIT_VM3(); else WAIT_VM0();
    BAR();
    const ushort* cQh = sQh + cur * 2048;
    const ushort* cQl = sQl + cur * 2048;
    const ushort* cVh = sVh + cur * 2048;

    __builtin_amdgcn_s_setprio(1);
    f32x4 S[2];
#pragma unroll
    for (int rt = 0; rt < 2; ++rt) {
      f32x4 a = {0.f, 0.f, 0.f, 0.f};
#pragma unroll
      for (int ks = 0; ks < 2; ++ks) {
        a = MFMA16(frag(cQh, 16 * rt + l15, g + 4 * ks), fKh[ks], a);
        a = MFMA16(frag(cQl, 16 * rt + l15, g + 4 * ks), fKh[ks], a);
      }
      S[rt] = a;
    }
    __builtin_amdgcn_s_setprio(0);

    float tmax = S[0][0];
#pragma unroll
    for (int rt = 0; rt < 2; ++rt)
#pragma unroll
      for (int r = 0; r < 4; ++r) tmax = fmaxf(tmax, S[rt][r]);
    tmax = fmaxf(tmax, __shfl_xor(tmax, 16, 64));
    tmax = fmaxf(tmax, __shfl_xor(tmax, 32, 64));
    if (__ballot(tmax > m + 5.77f)) {  // T13 deferred rescale (log2 domain)
      float mnew = fmaxf(m, tmax);
      float f = exp2_(m - mnew);
      float fr[4];
#pragma unroll
      for (int r = 0; r < 4; ++r) fr[r] = __shfl(f, (lane & 48) | (4 * g + r), 64);
#pragma unroll
      for (int ct = 0; ct < 4; ++ct)
#pragma unroll
        for (int r = 0; r < 4; ++r) O[ct][r] *= fr[r];
      lsum *= f;
      m = mnew;
    }
    float psum = 0.f;
    uint2 ph[2];
#pragma unroll
    for (int rt = 0; rt < 2; ++rt) {
      float p0 = exp2_(S[rt][0] - m), p1 = exp2_(S[rt][1] - m);
      float p2 = exp2_(S[rt][2] - m), p3 = exp2_(S[rt][3] - m);
      psum += (p0 + p1) + (p2 + p3);
      ph[rt].x = pack2rhu(p0, p1);
      ph[rt].y = pack2rhu(p2, p3);
    }
    psum += __shfl_xor(psum, 16, 64);
    psum += __shfl_xor(psum, 32, 64);
    lsum += psum;
#pragma unroll
    for (int rt = 0; rt < 2; ++rt) {
      int ch = 2 * rt + (g >> 1);
      int off = trow * 32 + ((ch ^ psw) << 3) + ((g & 1) << 2);
      *(uint2*)(sPh + off) = ph[rt];
    }
    WAIT_LGKM0();
    __builtin_amdgcn_sched_barrier(0);
    __builtin_amdgcn_s_setprio(1);
    {
      short8 aPh = frag32(sPh, trow, g);
#pragma unroll
      for (int ct = 0; ct < 4; ++ct)
        O[ct] = MFMA16(aPh, frag32(cVh, 16 * ct + l15, g), O[ct]);
    }
    __builtin_amdgcn_s_setprio(0);
    WAIT_LGKM0();
    BAR();
    if (ut < 30) {
      int tn = ut + 2;
      stage_q32(sQh + cur * 2048, xqh + (bhTT + tn * 32) * NN, tid);
      stage_q32(sQl + cur * 2048, xql + (bhTT + tn * 32) * NN, tid);
      stage_v32(sVh + cur * 2048, xvTh + bhTT * NN + tn * 32, tid);
    }
  }
  float il = 1.0f / lsum;
  float ilr[4];
#pragma unroll
  for (int r = 0; r < 4; ++r) ilr[r] = __shfl(il, (lane & 48) | (4 * g + r), 64);
#pragma unroll
  for (int r = 0; r < 4; ++r) {
    size_t row = (bhTT + t0 + 16 * w + 4 * g + r) * NN;
#pragma unroll
    for (int ct = 0; ct < 4; ++ct) auv[row + 16 * ct + l15] = O[ct][r] * ilr[r];
  }
  if (g == 0) lse[bhTT + t0 + trow] = m + log2_(lsum);
}

// ---------- pass B: h1 = relu(P^T @ W1 + b1); K bf16 A, P hi-only ----------
__global__ __launch_bounds__(256, 4) void k_h1(
    const ushort* __restrict__ xkh,
    const ushort* __restrict__ xqh, const ushort* __restrict__ xql,
    const ushort* __restrict__ w1Th,
    const float* __restrict__ lse, const float* __restrict__ b1,
    ushort* __restrict__ h1h) {
  __shared__ ushort sKh[4096];  // 2 bufs x 32x64 (prologue: Q hi tile)
  __shared__ ushort sWh[4096];  // 2 bufs x 64x32 (prologue: Q lo tile)
  __shared__ ushort sPh[2048];
  __shared__ float sL[1024];
  int tid = threadIdx.x;
  int lane = tid & 63, w = tid >> 6;
  int l15 = lane & 15, g = lane >> 4;
  int nb = gridDim.x, chunk = nb >> 3, bid = blockIdx.x;
  int blk = (bid & 7) * chunk + (bid >> 3);
  int bh = blk >> 4, h = bh & (HH - 1), a0 = (blk & 15) << 6;
  size_t bhTT = (size_t)bh * TT;
  size_t wbase = (size_t)h * NN * TT;
  int arow = 16 * w + l15, psw = (arow >> 1) & 3;

  stage_async(sKh, xqh + (bhTT + a0) * NN, 64, tid);
  stage_async(sWh, xql + (bhTT + a0) * NN, 64, tid);
  WAIT_VM0();
  BAR();
  short8 fQh[2], fQl[2];
#pragma unroll
  for (int ks = 0; ks < 2; ++ks) {
    fQh[ks] = frag(sKh, arow, g + 4 * ks);
    fQl[ks] = frag(sWh, arow, g + 4 * ks);
  }
#pragma unroll
  for (int i = 0; i < 4; ++i) sL[tid + i * 256] = lse[bhTT + tid + i * 256];
  WAIT_LGKM0();
  BAR();
  stage_q32(sKh, xkh + bhTT * NN, tid);
  stage_v32(sWh, w1Th + wbase, tid);
  stage_q32(sKh + 2048, xkh + (bhTT + 32) * NN, tid);
  stage_v32(sWh + 2048, w1Th + wbase + 32, tid);

  f32x4 acc[4];
#pragma unroll
  for (int ct = 0; ct < 4; ++ct)
#pragma unroll
    for (int r = 0; r < 4; ++r) acc[ct][r] = 0.f;

  for (int tt = 0; tt < 32; ++tt) {
    int cur = tt & 1;
    if (tt < 31) WAIT_VM2(); else WAIT_VM0();
    BAR();
    const ushort* cKh = sKh + cur * 2048;
    const ushort* cWh = sWh + cur * 2048;

    __builtin_amdgcn_s_setprio(1);
    f32x4 S[2];
#pragma unroll
    for (int rt = 0; rt < 2; ++rt) {
      f32x4 a = {0.f, 0.f, 0.f, 0.f};
#pragma unroll
      for (int ks = 0; ks < 2; ++ks) {
        short8 aKh = frag(cKh, 16 * rt + l15, g + 4 * ks);
        a = MFMA16(aKh, fQh[ks], a);
        a = MFMA16(aKh, fQl[ks], a);
      }
      S[rt] = a;
    }
    __builtin_amdgcn_s_setprio(0);

    uint2 ph[2];
#pragma unroll
    for (int rt = 0; rt < 2; ++rt) {
      f32x4 lv = *(const f32x4*)(sL + tt * 32 + 16 * rt + 4 * g);
      float p0 = exp2_(S[rt][0] - lv[0]);
      float p1 = exp2_(S[rt][1] - lv[1]);
      float p2 = exp2_(S[rt][2] - lv[2]);
      float p3 = exp2_(S[rt][3] - lv[3]);
      ph[rt].x = pack2rhu(p0, p1);
      ph[rt].y = pack2rhu(p2, p3);
    }
#pragma unroll
    for (int rt = 0; rt < 2; ++rt) {
      int ch = 2 * rt + (g >> 1);
      int off = arow * 32 + ((ch ^ psw) << 3) + ((g & 1) << 2);
      *(uint2*)(sPh + off) = ph[rt];
    }
    WAIT_LGKM0();
    __builtin_amdgcn_sched_barrier(0);
    __builtin_amdgcn_s_setprio(1);
    {
      short8 aPh = frag32(sPh, arow, g);
#pragma unroll
      for (int ct = 0; ct < 4; ++ct)
        acc[ct] = MFMA16(aPh, frag32(cWh, 16 * ct + l15, g), acc[ct]);
    }
    __builtin_amdgcn_s_setprio(0);
    WAIT_LGKM0();
    BAR();
    if (tt < 30) {
      int tn = tt + 2;
      stage_q32(sKh + cur * 2048, xkh + (bhTT + tn * 32) * NN, tid);
      stage_v32(sWh + cur * 2048, w1Th + wbase + tn * 32, tid);
    }
  }
#pragma unroll
  for (int ct = 0; ct < 4; ++ct) {
    float bb = b1[h * 64 + 16 * ct + l15];
#pragma unroll
    for (int r = 0; r < 4; ++r)
      h1h[(bhTT + a0 + 16 * w + 4 * g + r) * NN + 16 * ct + l15] =
          f2bfr(fmaxf(acc[ct][r] + bb, 0.f));
  }
}

// gate: h2=relu(h1@W2+b2); g=softmax(h2@W3+b3); ho=g0*auv+g1*xv -> bf16 hi/lo
__global__ __launch_bounds__(256) void k_gate(
    const ushort* __restrict__ h1h, const float* __restrict__ xv,
    const ushort* __restrict__ w2Th, const float* __restrict__ b2l,
    const float* __restrict__ W3l, const float* __restrict__ b3l,
    const float* __restrict__ auv, ushort* __restrict__ hoh,
    ushort* __restrict__ hol) {
  __shared__ ushort sA[4096], sB[4096];
  __shared__ float sred[2][64][4];
  __shared__ float sg[64][2];
  int tid = threadIdx.x;
  int lane = tid & 63, w = tid >> 6;
  int l15 = lane & 15, g = lane >> 4;
  int blk = blockIdx.x;
  int bh = blk >> 4, t0 = (blk & 15) << 6, h = bh & (HH - 1);
  size_t bhTT = (size_t)bh * TT;
  stage_async(sA, h1h + (bhTT + t0) * NN, 64, tid);
  stage_async(sB, w2Th + (size_t)h * 4096, 64, tid);
  WAIT_VM0();
  BAR();
  f32x4 acc[4];
#pragma unroll
  for (int rt = 0; rt < 4; ++rt)
#pragma unroll
    for (int r = 0; r < 4; ++r) acc[rt][r] = 0.f;
#pragma unroll
  for (int ks = 0; ks < 2; ++ks) {
    short8 bB = frag(sB, 16 * w + l15, g + 4 * ks);
#pragma unroll
    for (int rt = 0; rt < 4; ++rt)
      acc[rt] = MFMA16(frag(sA, 16 * rt + l15, g + 4 * ks), bB, acc[rt]);
  }
  int col = 16 * w + l15;
  float b2c = b2l[h * 64 + col];
  float w30 = W3l[h * 128 + col * 2 + 0];
  float w31 = W3l[h * 128 + col * 2 + 1];
#pragma unroll
  for (int rt = 0; rt < 4; ++rt)
#pragma unroll
    for (int r = 0; r < 4; ++r) {
      float v = fmaxf(acc[rt][r] + b2c, 0.f);
      float z0 = v * w30, z1 = v * w31;
#pragma unroll
      for (int mm = 1; mm < 16; mm <<= 1) {
        z0 += __shfl_xor(z0, mm, 64);
        z1 += __shfl_xor(z1, mm, 64);
      }
      if (l15 == 0) {
        int row = 16 * rt + 4 * g + r;
        sred[0][row][w] = z0;
        sred[1][row][w] = z1;
      }
    }
  __syncthreads();
  if (tid < 64) {
    float z0 = sred[0][tid][0] + sred[0][tid][1] + sred[0][tid][2] + sred[0][tid][3] +
               b3l[h * 2 + 0];
    float z1 = sred[1][tid][0] + sred[1][tid][1] + sred[1][tid][2] + sred[1][tid][3] +
               b3l[h * 2 + 1];
    float g0 = 1.0f / (1.0f + __expf(z1 - z0));
    sg[tid][0] = g0;
    sg[tid][1] = 1.0f - g0;
  }
  __syncthreads();
#pragma unroll
  for (int rr = 0; rr < 16; ++rr) {
    int row = 16 * w + rr;
    size_t off = (bhTT + t0 + row) * 64 + lane;
    float ho = sg[row][0] * auv[off] + sg[row][1] * xv[off];
    ushort hb, lb;
    split1(ho, hb, lb);
    hoh[off] = hb;
    hol[off] = lb;
  }
}

// out1 = LN(x + concat_h(ho) @ Wlt) -> bf16 hi/lo
__global__ __launch_bounds__(256, 2) void k_merge(
    const float* __restrict__ x, const ushort* __restrict__ hoh,
    const ushort* __restrict__ hol, const ushort* __restrict__ wth,
    const ushort* __restrict__ wtl, const float* __restrict__ g1l,
    const float* __restrict__ b1l, ushort* __restrict__ out1h,
    ushort* __restrict__ out1l) {
  __shared__ ushort sAh[2][4096], sAl[2][4096], sBh[2][4096], sBl[2][4096];
  __shared__ float sred[2][64][4];
  __shared__ float sfin[64][2];
  int tid = threadIdx.x;
  int lane = tid & 63, w = tid >> 6;
  int l15 = lane & 15, g = lane >> 4;
  int blk = blockIdx.x;
  int b = blk >> 4, t0 = (blk & 15) << 6;

  {
    size_t ab0 = (((size_t)b * HH + 0) * TT + t0) * NN;
    size_t ab1 = (((size_t)b * HH + 1) * TT + t0) * NN;
    stage_async(sAh[0], hoh + ab0, 64, tid);
    stage_async(sAl[0], hol + ab0, 64, tid);
    stage_async(sBh[0], wth, 512, tid);
    stage_async(sBl[0], wtl, 512, tid);
    stage_async(sAh[1], hoh + ab1, 64, tid);
    stage_async(sAl[1], hol + ab1, 64, tid);
    stage_async(sBh[1], wth + 64, 512, tid);
    stage_async(sBl[1], wtl + 64, 512, tid);
  }

  f32x4 acc[4];
#pragma unroll
  for (int rt = 0; rt < 4; ++rt)
#pragma unroll
    for (int r = 0; r < 4; ++r) acc[rt][r] = 0.f;

  for (int h = 0; h < 8; ++h) {
    int cur = h & 1;
    if (h < 7) WAIT_VM8(); else WAIT_VM0();
    BAR();
    __builtin_amdgcn_s_setprio(1);
#pragma unroll
    for (int ks = 0; ks < 2; ++ks) {
      short8 bBh = frag(sBh[cur], 16 * w + l15, g + 4 * ks);
      short8 bBl = frag(sBl[cur], 16 * w + l15, g + 4 * ks);
#pragma unroll
      for (int rt = 0; rt < 4; ++rt) {
        short8 aAh = frag(sAh[cur], 16 * rt + l15, g + 4 * ks);
        short8 aAl = frag(sAl[cur], 16 * rt + l15, g + 4 * ks);
        acc[rt] = MFMA16(aAh, bBh, acc[rt]);
        acc[rt] = MFMA16(aAh, bBl, acc[rt]);
        acc[rt] = MFMA16(aAl, bBh, acc[rt]);
      }
    }
    __builtin_amdgcn_s_setprio(0);
    WAIT_LGKM0();
    BAR();
    if (h < 6) {
      int hn = h + 2;
      size_t ab = (((size_t)b * HH + hn) * TT + t0) * NN;
      stage_async(sAh[cur], hoh + ab, 64, tid);
      stage_async(sAl[cur], hol + ab, 64, tid);
      stage_async(sBh[cur], wth + hn * 64, 512, tid);
      stage_async(sBl[cur], wtl + hn * 64, 512, tid);
    }
  }
  int mcol = 16 * w + l15;
  float vv[4][4];
#pragma unroll
  for (int rt = 0; rt < 4; ++rt)
#pragma unroll
    for (int r = 0; r < 4; ++r) {
      int row = 16 * rt + 4 * g + r;
      vv[rt][r] = acc[rt][r] + x[((size_t)b * TT + t0 + row) * 64 + mcol];
    }
#pragma unroll
  for (int rt = 0; rt < 4; ++rt)
#pragma unroll
    for (int r = 0; r < 4; ++r) {
      float s1 = vv[rt][r], s2 = vv[rt][r] * vv[rt][r];
#pragma unroll
      for (int mm = 1; mm < 16; mm <<= 1) {
        s1 += __shfl_xor(s1, mm, 64);
        s2 += __shfl_xor(s2, mm, 64);
      }
      if (l15 == 0) {
        int row = 16 * rt + 4 * g + r;
        sred[0][row][w] = s1;
        sred[1][row][w] = s2;
      }
    }
  __syncthreads();
  if (tid < 64) {
    float a1 = sred[0][tid][0] + sred[0][tid][1] + sred[0][tid][2] + sred[0][tid][3];
    float a2 = sred[1][tid][0] + sred[1][tid][1] + sred[1][tid][2] + sred[1][tid][3];
    float mean = a1 * (1.0f / 64.0f);
    float var = a2 * (1.0f / 64.0f) - mean * mean;
    sfin[tid][0] = mean;
    sfin[tid][1] = rsqrtf(var + EPSV);
  }
  __syncthreads();
  float gg = g1l[mcol], bb = b1l[mcol];
#pragma unroll
  for (int rt = 0; rt < 4; ++rt)
#pragma unroll
    for (int r = 0; r < 4; ++r) {
      int row = 16 * rt + 4 * g + r;
      float mean = sfin[row][0], rstd = sfin[row][1];
      float val = (vv[rt][r] - mean) * rstd * gg + bb;
      ushort hb, lb;
      split1(val, hb, lb);
      size_t idx = ((size_t)b * TT + t0 + row) * 64 + mcol;
      out1h[idx] = hb;
      out1l[idx] = lb;
    }
}

// ffn via MFMA: gc = out1@K3s + sclb; f1 = relu(gc + out1); f2 = f1@elW + elb;
// x = LN(out1 + f2).  block = (b, 32-t tile)
__global__ __launch_bounds__(256) void k_ffn(
    const ushort* __restrict__ o1h_, const ushort* __restrict__ o1l_,
    const float* __restrict__ sclb_l, const ushort* __restrict__ k3sTh,
    const ushort* __restrict__ elWTh, const float* __restrict__ elbl,
    const float* __restrict__ g2l, const float* __restrict__ b2l,
    float* __restrict__ xout) {
  __shared__ ushort sAh[2048], sAl[2048];  // 32x64
  __shared__ ushort sB1[4096], sB2[4096];  // K3sT, elWT
  __shared__ float sred[2][32][4];
  __shared__ float sfin[32][2];
  int tid = threadIdx.x;
  int lane = tid & 63, w = tid >> 6;
  int l15 = lane & 15, g = lane >> 4;
  int blk = blockIdx.x;
  int b = blk >> 5, t0 = (blk & 31) << 5;
  size_t rb = ((size_t)b * TT + t0) * 64;

  stage_q32(sAh, o1h_ + rb, tid);
  stage_q32(sAl, o1l_ + rb, tid);
  stage_async(sB1, k3sTh, 64, tid);
  stage_async(sB2, elWTh, 64, tid);
  WAIT_VM0();
  BAR();

  int col = 16 * w + l15;
  f32x4 acc[2];
#pragma unroll
  for (int rt = 0; rt < 2; ++rt)
#pragma unroll
    for (int r = 0; r < 4; ++r) acc[rt][r] = 0.f;
#pragma unroll
  for (int ks = 0; ks < 2; ++ks) {
    short8 bB = frag(sB1, col, g + 4 * ks);
#pragma unroll
    for (int rt = 0; rt < 2; ++rt) {
      acc[rt] = MFMA16(frag(sAh, 16 * rt + l15, g + 4 * ks), bB, acc[rt]);
      acc[rt] = MFMA16(frag(sAl, 16 * rt + l15, g + 4 * ks), bB, acc[rt]);
    }
  }
  float sclb = sclb_l[0];
  int cch = col >> 3, cin = col & 7;
  float o1v[2][4], f1v[2][4];
#pragma unroll
  for (int rt = 0; rt < 2; ++rt)
#pragma unroll
    for (int r = 0; r < 4; ++r) {
      int row = 16 * rt + 4 * g + r;
      int a = row * 64 + (((cch ^ (row & 7)) << 3)) + cin;
      float o1 = bf2f(sAh[a]) + bf2f(sAl[a]);
      o1v[rt][r] = o1;
      f1v[rt][r] = fmaxf(acc[rt][r] + sclb + o1, 0.f);
    }
  __syncthreads();
#pragma unroll
  for (int rt = 0; rt < 2; ++rt)
#pragma unroll
    for (int r = 0; r < 4; ++r) {
      int row = 16 * rt + 4 * g + r;
      int a = row * 64 + (((cch ^ (row & 7)) << 3)) + cin;
      ushort hb, lb;
      split1(f1v[rt][r], hb, lb);
      sAh[a] = hb;
      sAl[a] = lb;
    }
  __syncthreads();
  f32x4 acc2[2];
#pragma unroll
  for (int rt = 0; rt < 2; ++rt)
#pragma unroll
    for (int r = 0; r < 4; ++r) acc2[rt][r] = 0.f;
#pragma unroll
  for (int ks = 0; ks < 2; ++ks) {
    short8 bB = frag(sB2, col, g + 4 * ks);
#pragma unroll
    for (int rt = 0; rt < 2; ++rt) {
      acc2[rt] = MFMA16(frag(sAh, 16 * rt + l15, g + 4 * ks), bB, acc2[rt]);
      acc2[rt] = MFMA16(frag(sAl, 16 * rt + l15, g + 4 * ks), bB, acc2[rt]);
    }
  }
  float elb = elbl[col];
  float vv[2][4];
#pragma unroll
  for (int rt = 0; rt < 2; ++rt)
#pragma unroll
    for (int r = 0; r < 4; ++r) {
      vv[rt][r] = o1v[rt][r] + acc2[rt][r] + elb;
      float s1 = vv[rt][r], s2 = vv[rt][r] * vv[rt][r];
#pragma unroll
      for (int mm = 1; mm < 16; mm <<= 1) {
        s1 += __shfl_xor(s1, mm, 64);
        s2 += __shfl_xor(s2, mm, 64);
      }
      if (l15 == 0) {
        int row = 16 * rt + 4 * g + r;
        sred[0][row][w] = s1;
        sred[1][row][w] = s2;
      }
    }
  __syncthreads();
  if (tid < 32) {
    float a1 = sred[0][tid][0] + sred[0][tid][1] + sred[0][tid][2] + sred[0][tid][3];
    float a2 = sred[1][tid][0] + sred[1][tid][1] + sred[1][tid][2] + sred[1][tid][3];
    float mean = a1 * (1.0f / 64.0f);
    float var = a2 * (1.0f / 64.0f) - mean * mean;
    sfin[tid][0] = mean;
    sfin[tid][1] = rsqrtf(var + EPSV);
  }
  __syncthreads();
  float gg = g2l[col], bb = b2l[col];
#pragma unroll
  for (int rt = 0; rt < 2; ++rt)
#pragma unroll
    for (int r = 0; r < 4; ++r) {
      int row = 16 * rt + 4 * g + r;
      xout[rb + (size_t)row * 64 + col] =
          (vv[rt][r] - sfin[row][0]) * sfin[row][1] * gg + bb;
    }
}

__global__ __launch_bounds__(256) void k_final(
    const float* __restrict__ x, const float* __restrict__ fW1,
    const float* __restrict__ fb1, const float* __restrict__ fW2,
    const float* __restrict__ fb2, float* __restrict__ out) {
  __shared__ float pl[4][64];
  int tid = threadIdx.x;
  int lane = tid & 63, w = tid >> 6;
  size_t b = blockIdx.x;
  float s = 0.f;
  for (int t = 256 * w; t < 256 * w + 256; ++t) s += x[(b * TT + t) * 64 + lane];
  pl[w][lane] = s;
  __syncthreads();
  if (tid < 64) pl[0][tid] = (pl[0][tid] + pl[1][tid] + pl[2][tid] + pl[3][tid]) * (1.0f / TT);
  __syncthreads();
  if (tid < 64) {
    float hv = 0.f;
    if (lane < 32) {
      hv = fb1[lane];
#pragma unroll 8
      for (int n = 0; n < 64; ++n) hv = fmaf(pl[0][n], fW1[n * 32 + lane], hv);
      hv = fmaxf(hv, 0.f) * fW2[lane];
    }
#pragma unroll
    for (int m = 1; m < 64; m <<= 1) hv += __shfl_xor(hv, m, 64);
    if (lane == 0) out[b] = hv + fb2[0];
  }
}

extern "C" void kernel_launch(void* const* d_in, const int* in_sizes, int n_in,
                              void* d_out, int out_size, void* d_ws, size_t ws_size,
                              hipStream_t stream) {
  const float* inputs = (const float*)d_in[0];
  const float* pos_emb = (const float*)d_in[1];
  const float* K3 = (const float*)d_in[2];
  const float* qw = (const float*)d_in[3];
  const float* qb = (const float*)d_in[4];
  const float* kw = (const float*)d_in[5];
  const float* kb = (const float*)d_in[6];
  const float* vw = (const float*)d_in[7];
  const float* vb = (const float*)d_in[8];
  const float* tqW1 = (const float*)d_in[9];
  const float* tqb1 = (const float*)d_in[10];
  const float* tqW2 = (const float*)d_in[11];
  const float* tqb2 = (const float*)d_in[12];
  const float* tqW3 = (const float*)d_in[13];
  const float* tqb3 = (const float*)d_in[14];
  const float* Wlt = (const float*)d_in[15];
  const float* ln1g = (const float*)d_in[16];
  const float* ln1b = (const float*)d_in[17];
  const float* ln2g = (const float*)d_in[18];
  const float* ln2b = (const float*)d_in[19];
  const float* sclw = (const float*)d_in[20];
  const float* sclb = (const float*)d_in[21];
  const float* elW = (const float*)d_in[22];
  const float* elb = (const float*)d_in[23];
  const float* fW1 = (const float*)d_in[24];
  const float* fb1 = (const float*)d_in[25];
  const float* fW2 = (const float*)d_in[26];
  const float* fb2 = (const float*)d_in[27];
  float* out = (float*)d_out;
  float* ws_f = (float*)d_ws;

  const size_t TN = (size_t)TT * NN;
  const size_t HTN = (size_t)HH * TT * NN;
  const size_t W1T_ELEMS = (size_t)LL * HH * NN * TT;  // ushorts
  const size_t WLT_ELEMS = (size_t)LL * 64 * 512;      // ushorts

  ushort* k3sTh = (ushort*)ws_f;                      // LL*4096
  ushort* w1Th = k3sTh + (size_t)LL * 4096;           // W1T_ELEMS
  ushort* wth = w1Th + W1T_ELEMS;                     // WLT_ELEMS
  ushort* wtl = wth + WLT_ELEMS;                      // WLT_ELEMS
  ushort* w2Th = wtl + WLT_ELEMS;                     // LL*HH*4096
  ushort* elWTh = w2Th + (size_t)LL * HH * 4096;      // LL*4096
  size_t base_ush = (size_t)LL * 4096 + W1T_ELEMS + 2 * WLT_ELEMS +
                    (size_t)LL * HH * 4096 + (size_t)LL * 4096;
  const size_t base = (base_ush + 1) / 2;  // words

  for (int l = 0; l < LL; ++l)
    k_k3s<<<16, 256, 0, stream>>>(K3, sclw + l * KSS, k3sTh + (size_t)l * 4096);
  k_tsplit<<<LL * HH * 16, 256, 0, stream>>>(tqW1, w1Th);
  k_tsplitW<<<LL * 8, 256, 0, stream>>>(Wlt, wth, wtl);
  k_tsplitSq<<<LL * HH, 256, 0, stream>>>(tqW2, w2Th);
  k_tsplitSq<<<LL, 256, 0, stream>>>(elW, elWTh);

  // per-batch f32 words: x TN + xv HTN + auv HTN + lse HH*TT + out1h/l TN
  //  + h1h HTN/2 + xqh+xql HTN + xkh HTN/2 + xvTh HTN/2 + hoh+hol HTN
  const size_t per_b = 2 * TN + (size_t)HH * TT + (11 * HTN) / 2;
  size_t avail = ws_size / sizeof(float);
  avail = (avail > base) ? avail - base : 0;
  int Bc = (int)(avail / per_b);
  if (Bc > BB) Bc = BB;
  if (Bc < 1) Bc = 1;

  for (int b0 = 0; b0 < BB; b0 += Bc) {
    int bc = (BB - b0 < Bc) ? (BB - b0) : Bc;
    float* x = ws_f + base;
    float* xv = x + (size_t)bc * TN;
    float* auv = xv + (size_t)bc * HTN;
    float* lseb = auv + (size_t)bc * HTN;
    ushort* out1h = (ushort*)(lseb + (size_t)bc * HH * TT);
    ushort* out1l = out1h + (size_t)bc * TN;
    ushort* h1h = out1l + (size_t)bc * TN;
    ushort* xqh = h1h + (size_t)bc * HTN;
    ushort* xql = xqh + (size_t)bc * HTN;
    ushort* xkh = xql + (size_t)bc * HTN;
    ushort* xvTh = xkh + (size_t)bc * HTN;
    ushort* hoh = xvTh + (size_t)bc * HTN;
    ushort* hol = hoh + (size_t)bc * HTN;

    int total = bc * (int)TN;
    k_addpos<<<(total + 255) / 256, 256, 0, stream>>>(inputs + (size_t)b0 * TN, pos_emb, x,
                                                      total);
    for (int l = 0; l < LL; ++l) {
      k_gconv<<<bc * TT / 4, 256, 0, stream>>>(x, K3, qw + l * HH * KSS, qb + l * HH,
                                               kw + l * HH * KSS, kb + l * HH,
                                               vw + l * HH * KSS, vb + l * HH,
                                               xqh, xql, xkh, xv);
      k_tsplit<<<bc * HH * 16, 256, 0, stream>>>(xv, xvTh);
      k_attn<<<bc * HH * 16, 256, 0, stream>>>(xkh, xqh, xql, xvTh, auv, lseb);
      k_h1<<<bc * HH * 16, 256, 0, stream>>>(
          xkh, xqh, xql, w1Th + (size_t)l * HH * NN * TT, lseb,
          tqb1 + l * HH * DD1, h1h);
      k_gate<<<bc * HH * 16, 256, 0, stream>>>(
          h1h, xv, w2Th + (size_t)l * HH * 4096, tqb2 + l * HH * DD1,
          tqW3 + (size_t)l * HH * DD1 * 2, tqb3 + l * HH * 2, auv, hoh, hol);
      k_merge<<<bc * 16, 256, 0, stream>>>(x, hoh, hol, wth + (size_t)l * 64 * 512,
                                           wtl + (size_t)l * 64 * 512, ln1g + l * NN,
                                           ln1b + l * NN, out1h, out1l);
      k_ffn<<<bc * 32, 256, 0, stream>>>(out1h, out1l, sclb + l,
                                         k3sTh + (size_t)l * 4096,
                                         elWTh + (size_t)l * 4096, elb + l * NN,
                                         ln2g + l * NN, ln2b + l * NN, x);
    }
    k_final<<<bc, 256, 0, stream>>>(x, fW1, fb1, fW2, fb2, out + b0);
  }
}

// Round 10
// 261.645 us; speedup vs baseline: 2.8574x; 1.1224x over previous
//
#include <hip/hip_runtime.h>

typedef __attribute__((ext_vector_type(8))) short short8;
typedef __attribute__((ext_vector_type(4))) float f32x4;

#define BB 8
#define TT 1024
#define NN 64
#define HH 8
#define LL 2
#define KSS 3
#define DD1 64
#define EPSV 1e-6f
#define LOG2E 1.4426950408889634f

#define MFMA16(a, b, c) __builtin_amdgcn_mfma_f32_16x16x32_bf16(a, b, c, 0, 0, 0)
#define BAR() __builtin_amdgcn_s_barrier()
#define WAIT_VM8() asm volatile("s_waitcnt vmcnt(8)" ::: "memory")
#define WAIT_VM2() asm volatile("s_waitcnt vmcnt(2)" ::: "memory")
#define WAIT_VM0() asm volatile("s_waitcnt vmcnt(0)" ::: "memory")
#define WAIT_LGKM0() asm volatile("s_waitcnt lgkmcnt(0)" ::: "memory")

__device__ __forceinline__ float exp2_(float x) { return __builtin_amdgcn_exp2f(x); }
__device__ __forceinline__ float log2_(float x) { return __builtin_amdgcn_logf(x); }

// ---- truncation-based hi/lo bf16 split (hi error lands exactly in lo) ----
__device__ __forceinline__ void split1(float x, ushort& hi, ushort& lo) {
  uint u = __float_as_uint(x);
  hi = (ushort)(u >> 16);
  float hf = __uint_as_float(u & 0xffff0000u);
  lo = (ushort)(__float_as_uint(x - hf) >> 16);
}
__device__ __forceinline__ uint pack2(float a, float b, uint& lo) {
  uint ua = __float_as_uint(a), ub = __float_as_uint(b);
  float ra = __uint_as_float(ua & 0xffff0000u);
  float rb = __uint_as_float(ub & 0xffff0000u);
  lo = (__float_as_uint(a - ra) >> 16) | (__float_as_uint(b - rb) & 0xffff0000u);
  return (ua >> 16) | (ub & 0xffff0000u);
}
// round-half-up packed pair (unbiased enough; 5 ops)
__device__ __forceinline__ uint pack2rhu(float a, float b) {
  uint ua = __float_as_uint(a) + 0x8000u;
  uint ub = __float_as_uint(b) + 0x8000u;
  return (ua >> 16) | (ub & 0xffff0000u);
}
// round-to-nearest-even bf16
__device__ __forceinline__ ushort f2bfr(float x) {
  union { float f; uint u; } v; v.f = x;
  uint r = (v.u + 0x7fffu + ((v.u >> 16) & 1u)) >> 16;
  return (ushort)r;
}
__device__ __forceinline__ float bf2f(ushort b) {
  union { uint u; float f; } v; v.u = ((uint)b) << 16; return v.f;
}

// ---- async global->LDS staging ----
__device__ __forceinline__ void gl2lds16(const ushort* g, ushort* l) {
  __builtin_amdgcn_global_load_lds(
      (const __attribute__((address_space(1))) void*)g,
      (__attribute__((address_space(3))) void*)l, 16, 0, 0);
}
// 64x64 tile, chunk swizzle c ^ (r&7); 2 gl_lds/wave
__device__ __forceinline__ void stage_async(ushort* __restrict__ s,
                                            const ushort* __restrict__ g,
                                            int stride, int tid) {
  int w = tid >> 6;
  int sub = (tid & 63) >> 3, c = tid & 7;
#pragma unroll
  for (int i = 0; i < 2; ++i) {
    int rb = (i * 4 + w) * 8;
    gl2lds16(g + (size_t)(rb + sub) * stride + ((c ^ sub) << 3), s + rb * 64);
  }
}
__device__ __forceinline__ short8 frag(const ushort* __restrict__ s, int row, int ch) {
  return *(const short8*)(s + row * 64 + ((ch ^ (row & 7)) << 3));
}
// 32x64 tile; 1 gl_lds/wave
__device__ __forceinline__ void stage_q32(ushort* __restrict__ s,
                                          const ushort* __restrict__ g, int tid) {
  int w = tid >> 6;
  int sub = (tid & 63) >> 3, c = tid & 7;
  int rb = w * 8, r = rb + sub;
  gl2lds16(g + (size_t)r * 64 + ((c ^ (r & 7)) << 3), s + rb * 64);
}
// 64x32 tile (stride 1024), chunk swizzle c ^ ((n>>1)&3); 1 gl_lds/wave
__device__ __forceinline__ void stage_v32(ushort* __restrict__ s,
                                          const ushort* __restrict__ g, int tid) {
  int w = tid >> 6;
  int noff = (tid & 63) >> 2, c = tid & 3;
  int nb = w * 16, n = nb + noff;
  gl2lds16(g + (size_t)n * 1024 + ((c ^ ((n >> 1) & 3)) << 3), s + nb * 32);
}
__device__ __forceinline__ short8 frag32(const ushort* __restrict__ s, int row, int g) {
  return *(const short8*)(s + row * 32 + ((g ^ ((row >> 1) & 3)) << 3));
}

// ---------- small kernels ----------

__global__ void k_addpos(const float* __restrict__ in, const float* __restrict__ pe,
                         float* __restrict__ x, int total) {
  int idx = blockIdx.x * 256 + threadIdx.x;
  if (idx < total) {
    int tn = idx & (TT * NN - 1);
    x[idx] = in[idx] + pe[tn];
  }
}

// K3s^T (bf16 RNE): out[m*64+n] = sum_k K3[n,k,m]*sclw[k]
__global__ void k_k3s(const float* __restrict__ K3, const float* __restrict__ sclwl,
                      ushort* __restrict__ dh) {
  int idx = blockIdx.x * 256 + threadIdx.x;  // < 4096
  int n = idx >> 6, m = idx & 63;
  float v = K3[n * 192 + m] * sclwl[0] + K3[n * 192 + 64 + m] * sclwl[1] +
            K3[n * 192 + 128 + m] * sclwl[2];
  dh[m * 64 + n] = f2bfr(v);
}

// transpose, hi-only RNE: src [mat][1024][64] f32 -> dh [mat][64][1024] bf16
__global__ __launch_bounds__(256) void k_tsplit(const float* __restrict__ src,
                                                ushort* __restrict__ dh) {
  __shared__ float st[64][65];
  int blk = blockIdx.x;
  int mat = blk >> 4, rt = blk & 15;
  int tid = threadIdx.x;
  size_t sbase = ((size_t)mat * TT + rt * 64) * 64;
#pragma unroll
  for (int i = 0; i < 4; ++i) {
    int idx = tid + i * 256;
    int r = idx >> 4, c4 = idx & 15;
    float4 v = *(const float4*)(src + sbase + r * 64 + c4 * 4);
    st[r][c4 * 4 + 0] = v.x; st[r][c4 * 4 + 1] = v.y;
    st[r][c4 * 4 + 2] = v.z; st[r][c4 * 4 + 3] = v.w;
  }
  __syncthreads();
  size_t obase = (size_t)mat * (64 * (size_t)TT) + rt * 64;
#pragma unroll
  for (int i = 0; i < 2; ++i) {
    int idx = tid + i * 256;
    int n = idx >> 3, c = idx & 7;
    uint hw[4];
#pragma unroll
    for (int j = 0; j < 4; ++j)
      hw[j] = (uint)f2bfr(st[c * 8 + 2 * j][n]) | ((uint)f2bfr(st[c * 8 + 2 * j + 1][n]) << 16);
    *(uint4*)(dh + obase + (size_t)n * TT + c * 8) = make_uint4(hw[0], hw[1], hw[2], hw[3]);
  }
}

// transpose+split Wlt (hi/lo)
__global__ __launch_bounds__(256) void k_tsplitW(const float* __restrict__ Wlt,
                                                 ushort* __restrict__ dh,
                                                 ushort* __restrict__ dl) {
  __shared__ float st[64][65];
  int blk = blockIdx.x;
  int l = blk >> 3, rt = blk & 7;
  int tid = threadIdx.x;
  size_t sbase = ((size_t)l * 512 + rt * 64) * 64;
#pragma unroll
  for (int i = 0; i < 4; ++i) {
    int idx = tid + i * 256;
    int r = idx >> 4, c4 = idx & 15;
    float4 v = *(const float4*)(Wlt + sbase + r * 64 + c4 * 4);
    st[r][c4 * 4 + 0] = v.x; st[r][c4 * 4 + 1] = v.y;
    st[r][c4 * 4 + 2] = v.z; st[r][c4 * 4 + 3] = v.w;
  }
  __syncthreads();
  size_t obase = (size_t)l * 64 * 512 + rt * 64;
#pragma unroll
  for (int i = 0; i < 2; ++i) {
    int idx = tid + i * 256;
    int n = idx >> 3, c = idx & 7;
    uint hw[4], lw[4];
#pragma unroll
    for (int j = 0; j < 4; ++j) hw[j] = pack2(st[c * 8 + 2 * j][n], st[c * 8 + 2 * j + 1][n], lw[j]);
    *(uint4*)(dh + obase + (size_t)n * 512 + c * 8) = make_uint4(hw[0], hw[1], hw[2], hw[3]);
    *(uint4*)(dl + obase + (size_t)n * 512 + c * 8) = make_uint4(lw[0], lw[1], lw[2], lw[3]);
  }
}

// square transpose, hi-only RNE: src [mat][64][64] -> dh [mat][64][64]^T
__global__ __launch_bounds__(256) void k_tsplitSq(const float* __restrict__ src,
                                                  ushort* __restrict__ dh) {
  __shared__ float st[64][65];
  int mat = blockIdx.x;
  int tid = threadIdx.x;
  size_t sbase = (size_t)mat * 4096;
#pragma unroll
  for (int i = 0; i < 4; ++i) {
    int idx = tid + i * 256;
    int r = idx >> 4, c4 = idx & 15;
    float4 v = *(const float4*)(src + sbase + r * 64 + c4 * 4);
    st[r][c4 * 4 + 0] = v.x; st[r][c4 * 4 + 1] = v.y;
    st[r][c4 * 4 + 2] = v.z; st[r][c4 * 4 + 3] = v.w;
  }
  __syncthreads();
#pragma unroll
  for (int i = 0; i < 2; ++i) {
    int idx = tid + i * 256;
    int d = idx >> 3, c = idx & 7;
    uint hw[4];
#pragma unroll
    for (int j = 0; j < 4; ++j)
      hw[j] = (uint)f2bfr(st[c * 8 + 2 * j][d]) | ((uint)f2bfr(st[c * 8 + 2 * j + 1][d]) << 16);
    *(uint4*)(dh + sbase + (size_t)d * 64 + c * 8) = make_uint4(hw[0], hw[1], hw[2], hw[3]);
  }
}

// gconv: 256-thr blocks, K3 staged in LDS, 4 (b,t) rows per block
__global__ __launch_bounds__(256) void k_gconv(
    const float* __restrict__ x, const float* __restrict__ K3,
    const float* __restrict__ qwl, const float* __restrict__ qbl,
    const float* __restrict__ kwl, const float* __restrict__ kbl,
    const float* __restrict__ vwl, const float* __restrict__ vbl,
    ushort* __restrict__ xqh, ushort* __restrict__ xkh, float* __restrict__ xv) {
  __shared__ float sK3[12288];
  __shared__ float sx[4][64];
  int tid = threadIdx.x;
  int w = tid >> 6, lane = tid & 63;
#pragma unroll
  for (int i = 0; i < 12; ++i)
    ((float4*)sK3)[tid + i * 256] = ((const float4*)K3)[tid + i * 256];
  size_t bt = (size_t)blockIdx.x * 4 + w;
  size_t b = bt >> 10, t = bt & 1023;
  float xm = x[bt * 64 + lane];
  sx[w][lane] = xm;
  __syncthreads();
  float a0 = 0.f, a1 = 0.f, a2 = 0.f;
#pragma unroll 8
  for (int n = 0; n < 64; ++n) {
    float xn = sx[w][n];
    a0 = fmaf(xn, sK3[n * 192 + lane], a0);
    a1 = fmaf(xn, sK3[n * 192 + 64 + lane], a1);
    a2 = fmaf(xn, sK3[n * 192 + 128 + lane], a2);
  }
#pragma unroll
  for (int hh = 0; hh < HH; ++hh) {
    size_t off = (((size_t)b * HH + hh) * TT + t) * 64 + lane;
    float q = fmaf(qwl[hh * 3 + 0], a0,
              fmaf(qwl[hh * 3 + 1], a1, fmaf(qwl[hh * 3 + 2], a2, qbl[hh] + xm)));
    q = fmaxf(q, 0.f) * (0.015625f * LOG2E);  // fold 1/N and log2(e) into Q
    xqh[off] = f2bfr(q);                      // Q hi-only, RNE
    float k = fmaf(kwl[hh * 3 + 0], a0,
              fmaf(kwl[hh * 3 + 1], a1, fmaf(kwl[hh * 3 + 2], a2, kbl[hh] + xm)));
    xkh[off] = f2bfr(fmaxf(k, 0.f));          // K hi-only, RNE
    float v = fmaf(vwl[hh * 3 + 0], a0,
              fmaf(vwl[hh * 3 + 1], a1, fmaf(vwl[hh * 3 + 2], a2, vbl[hh] + xm)));
    xv[off] = fmaxf(v, 0.f);
  }
}

// ---------- pass A: flash attention, NO-MAX softmax (S >= 0 bounded) ----------
__global__ __launch_bounds__(256, 4) void k_attn(
    const ushort* __restrict__ xkh, const ushort* __restrict__ xqh,
    const ushort* __restrict__ xvTh,
    float* __restrict__ auv, float* __restrict__ lse) {
  __shared__ ushort sQh[4096];  // 2 bufs x 32x64 (prologue: K 64x64 tile)
  __shared__ ushort sVh[4096];  // 2 bufs x 64x32
  __shared__ ushort sPh[2048];  // 64x32
  int tid = threadIdx.x;
  int lane = tid & 63, w = tid >> 6;
  int l15 = lane & 15, g = lane >> 4;
  int nb = gridDim.x, chunk = nb >> 3, bid = blockIdx.x;
  int blk = (bid & 7) * chunk + (bid >> 3);  // XCD swizzle (nb % 8 == 0)
  int bh = blk >> 4, t0 = (blk & 15) << 6;
  size_t bhTT = (size_t)bh * TT;
  int trow = 16 * w + l15, psw = (trow >> 1) & 3;

  stage_async(sQh, xkh + (bhTT + t0) * NN, 64, tid);
  WAIT_VM0();
  BAR();
  short8 fKh[2];
#pragma unroll
  for (int ks = 0; ks < 2; ++ks) fKh[ks] = frag(sQh, trow, g + 4 * ks);
  WAIT_LGKM0();
  BAR();
  stage_q32(sQh, xqh + bhTT * NN, tid);
  stage_v32(sVh, xvTh + bhTT * NN, tid);
  stage_q32(sQh + 2048, xqh + (bhTT + 32) * NN, tid);
  stage_v32(sVh + 2048, xvTh + bhTT * NN + 32, tid);

  float lsum = 0.f;  // per-lane partial (its t, 8 u's per iter)
  f32x4 O[4];
#pragma unroll
  for (int ct = 0; ct < 4; ++ct)
#pragma unroll
    for (int r = 0; r < 4; ++r) O[ct][r] = 0.f;

  for (int ut = 0; ut < 32; ++ut) {
    int cur = ut & 1;
    if (ut < 31) WAIT_VM2(); else WAIT_VM0();
    BAR();
    const ushort* cQh = sQh + cur * 2048;
    const ushort* cVh = sVh + cur * 2048;

    __builtin_amdgcn_s_setprio(1);
    f32x4 S[2];
#pragma unroll
    for (int rt = 0; rt < 2; ++rt) {
      f32x4 a = {0.f, 0.f, 0.f, 0.f};
#pragma unroll
      for (int ks = 0; ks < 2; ++ks)
        a = MFMA16(frag(cQh, 16 * rt + l15, g + 4 * ks), fKh[ks], a);
      S[rt] = a;
    }
    __builtin_amdgcn_s_setprio(0);

    uint2 ph[2];
#pragma unroll
    for (int rt = 0; rt < 2; ++rt) {
      float p0 = exp2_(S[rt][0]), p1 = exp2_(S[rt][1]);
      float p2 = exp2_(S[rt][2]), p3 = exp2_(S[rt][3]);
      lsum += (p0 + p1) + (p2 + p3);
      ph[rt].x = pack2rhu(p0, p1);
      ph[rt].y = pack2rhu(p2, p3);
    }
#pragma unroll
    for (int rt = 0; rt < 2; ++rt) {
      int ch = 2 * rt + (g >> 1);
      int off = trow * 32 + ((ch ^ psw) << 3) + ((g & 1) << 2);
      *(uint2*)(sPh + off) = ph[rt];
    }
    WAIT_LGKM0();
    __builtin_amdgcn_sched_barrier(0);
    __builtin_amdgcn_s_setprio(1);
    {
      short8 aPh = frag32(sPh, trow, g);
#pragma unroll
      for (int ct = 0; ct < 4; ++ct)
        O[ct] = MFMA16(aPh, frag32(cVh, 16 * ct + l15, g), O[ct]);
    }
    __builtin_amdgcn_s_setprio(0);
    WAIT_LGKM0();
    BAR();
    if (ut < 30) {
      int tn = ut + 2;
      stage_q32(sQh + cur * 2048, xqh + (bhTT + tn * 32) * NN, tid);
      stage_v32(sVh + cur * 2048, xvTh + bhTT * NN + tn * 32, tid);
    }
  }
  // lane partials -> full lsum for t = trow (reduce over g)
  lsum += __shfl_xor(lsum, 16, 64);
  lsum += __shfl_xor(lsum, 32, 64);
  float il = 1.0f / lsum;
  float ilr[4];
#pragma unroll
  for (int r = 0; r < 4; ++r) ilr[r] = __shfl(il, (lane & 48) | (4 * g + r), 64);
#pragma unroll
  for (int r = 0; r < 4; ++r) {
    size_t row = (bhTT + t0 + 16 * w + 4 * g + r) * NN;
#pragma unroll
    for (int ct = 0; ct < 4; ++ct) auv[row + 16 * ct + l15] = O[ct][r] * ilr[r];
  }
  if (g == 0) lse[bhTT + t0 + trow] = log2_(lsum);
}

// ---------- pass B: h1 = relu(P^T @ W1 + b1); Q hi-only, P hi-only ----------
__global__ __launch_bounds__(256, 4) void k_h1(
    const ushort* __restrict__ xkh, const ushort* __restrict__ xqh,
    const ushort* __restrict__ w1Th,
    const float* __restrict__ lse, const float* __restrict__ b1,
    ushort* __restrict__ h1h) {
  __shared__ ushort sKh[4096];  // 2 bufs x 32x64 (prologue: Q hi tile)
  __shared__ ushort sWh[4096];  // 2 bufs x 64x32
  __shared__ ushort sPh[2048];
  __shared__ float sL[1024];
  int tid = threadIdx.x;
  int lane = tid & 63, w = tid >> 6;
  int l15 = lane & 15, g = lane >> 4;
  int nb = gridDim.x, chunk = nb >> 3, bid = blockIdx.x;
  int blk = (bid & 7) * chunk + (bid >> 3);
  int bh = blk >> 4, h = bh & (HH - 1), a0 = (blk & 15) << 6;
  size_t bhTT = (size_t)bh * TT;
  size_t wbase = (size_t)h * NN * TT;
  int arow = 16 * w + l15, psw = (arow >> 1) & 3;

  stage_async(sKh, xqh + (bhTT + a0) * NN, 64, tid);
  WAIT_VM0();
  BAR();
  short8 fQh[2];
#pragma unroll
  for (int ks = 0; ks < 2; ++ks) fQh[ks] = frag(sKh, arow, g + 4 * ks);
#pragma unroll
  for (int i = 0; i < 4; ++i) sL[tid + i * 256] = lse[bhTT + tid + i * 256];
  WAIT_LGKM0();
  BAR();
  stage_q32(sKh, xkh + bhTT * NN, tid);
  stage_v32(sWh, w1Th + wbase, tid);
  stage_q32(sKh + 2048, xkh + (bhTT + 32) * NN, tid);
  stage_v32(sWh + 2048, w1Th + wbase + 32, tid);

  f32x4 acc[4];
#pragma unroll
  for (int ct = 0; ct < 4; ++ct)
#pragma unroll
    for (int r = 0; r < 4; ++r) acc[ct][r] = 0.f;

  for (int tt = 0; tt < 32; ++tt) {
    int cur = tt & 1;
    if (tt < 31) WAIT_VM2(); else WAIT_VM0();
    BAR();
    const ushort* cKh = sKh + cur * 2048;
    const ushort* cWh = sWh + cur * 2048;

    __builtin_amdgcn_s_setprio(1);
    f32x4 S[2];
#pragma unroll
    for (int rt = 0; rt < 2; ++rt) {
      f32x4 a = {0.f, 0.f, 0.f, 0.f};
#pragma unroll
      for (int ks = 0; ks < 2; ++ks)
        a = MFMA16(frag(cKh, 16 * rt + l15, g + 4 * ks), fQh[ks], a);
      S[rt] = a;
    }
    __builtin_amdgcn_s_setprio(0);

    uint2 ph[2];
#pragma unroll
    for (int rt = 0; rt < 2; ++rt) {
      f32x4 lv = *(const f32x4*)(sL + tt * 32 + 16 * rt + 4 * g);
      float p0 = exp2_(S[rt][0] - lv[0]);
      float p1 = exp2_(S[rt][1] - lv[1]);
      float p2 = exp2_(S[rt][2] - lv[2]);
      float p3 = exp2_(S[rt][3] - lv[3]);
      ph[rt].x = pack2rhu(p0, p1);
      ph[rt].y = pack2rhu(p2, p3);
    }
#pragma unroll
    for (int rt = 0; rt < 2; ++rt) {
      int ch = 2 * rt + (g >> 1);
      int off = arow * 32 + ((ch ^ psw) << 3) + ((g & 1) << 2);
      *(uint2*)(sPh + off) = ph[rt];
    }
    WAIT_LGKM0();
    __builtin_amdgcn_sched_barrier(0);
    __builtin_amdgcn_s_setprio(1);
    {
      short8 aPh = frag32(sPh, arow, g);
#pragma unroll
      for (int ct = 0; ct < 4; ++ct)
        acc[ct] = MFMA16(aPh, frag32(cWh, 16 * ct + l15, g), acc[ct]);
    }
    __builtin_amdgcn_s_setprio(0);
    WAIT_LGKM0();
    BAR();
    if (tt < 30) {
      int tn = tt + 2;
      stage_q32(sKh + cur * 2048, xkh + (bhTT + tn * 32) * NN, tid);
      stage_v32(sWh + cur * 2048, w1Th + wbase + tn * 32, tid);
    }
  }
#pragma unroll
  for (int ct = 0; ct < 4; ++ct) {
    float bb = b1[h * 64 + 16 * ct + l15];
#pragma unroll
    for (int r = 0; r < 4; ++r)
      h1h[(bhTT + a0 + 16 * w + 4 * g + r) * NN + 16 * ct + l15] =
          f2bfr(fmaxf(acc[ct][r] + bb, 0.f));
  }
}

// gate: h2=relu(h1@W2+b2); g=softmax(h2@W3+b3); ho=g0*auv+g1*xv -> bf16 hi/lo
__global__ __launch_bounds__(256) void k_gate(
    const ushort* __restrict__ h1h, const float* __restrict__ xv,
    const ushort* __restrict__ w2Th, const float* __restrict__ b2l,
    const float* __restrict__ W3l, const float* __restrict__ b3l,
    const float* __restrict__ auv, ushort* __restrict__ hoh,
    ushort* __restrict__ hol) {
  __shared__ ushort sA[4096], sB[4096];
  __shared__ float sred[2][64][4];
  __shared__ float sg[64][2];
  int tid = threadIdx.x;
  int lane = tid & 63, w = tid >> 6;
  int l15 = lane & 15, g = lane >> 4;
  int blk = blockIdx.x;
  int bh = blk >> 4, t0 = (blk & 15) << 6, h = bh & (HH - 1);
  size_t bhTT = (size_t)bh * TT;
  stage_async(sA, h1h + (bhTT + t0) * NN, 64, tid);
  stage_async(sB, w2Th + (size_t)h * 4096, 64, tid);
  WAIT_VM0();
  BAR();
  f32x4 acc[4];
#pragma unroll
  for (int rt = 0; rt < 4; ++rt)
#pragma unroll
    for (int r = 0; r < 4; ++r) acc[rt][r] = 0.f;
#pragma unroll
  for (int ks = 0; ks < 2; ++ks) {
    short8 bB = frag(sB, 16 * w + l15, g + 4 * ks);
#pragma unroll
    for (int rt = 0; rt < 4; ++rt)
      acc[rt] = MFMA16(frag(sA, 16 * rt + l15, g + 4 * ks), bB, acc[rt]);
  }
  int col = 16 * w + l15;
  float b2c = b2l[h * 64 + col];
  float w30 = W3l[h * 128 + col * 2 + 0];
  float w31 = W3l[h * 128 + col * 2 + 1];
#pragma unroll
  for (int rt = 0; rt < 4; ++rt)
#pragma unroll
    for (int r = 0; r < 4; ++r) {
      float v = fmaxf(acc[rt][r] + b2c, 0.f);
      float z0 = v * w30, z1 = v * w31;
#pragma unroll
      for (int mm = 1; mm < 16; mm <<= 1) {
        z0 += __shfl_xor(z0, mm, 64);
        z1 += __shfl_xor(z1, mm, 64);
      }
      if (l15 == 0) {
        int row = 16 * rt + 4 * g + r;
        sred[0][row][w] = z0;
        sred[1][row][w] = z1;
      }
    }
  __syncthreads();
  if (tid < 64) {
    float z0 = sred[0][tid][0] + sred[0][tid][1] + sred[0][tid][2] + sred[0][tid][3] +
               b3l[h * 2 + 0];
    float z1 = sred[1][tid][0] + sred[1][tid][1] + sred[1][tid][2] + sred[1][tid][3] +
               b3l[h * 2 + 1];
    float g0 = 1.0f / (1.0f + __expf(z1 - z0));
    sg[tid][0] = g0;
    sg[tid][1] = 1.0f - g0;
  }
  __syncthreads();
#pragma unroll
  for (int rr = 0; rr < 16; ++rr) {
    int row = 16 * w + rr;
    size_t off = (bhTT + t0 + row) * 64 + lane;
    float ho = sg[row][0] * auv[off] + sg[row][1] * xv[off];
    ushort hb, lb;
    split1(ho, hb, lb);
    hoh[off] = hb;
    hol[off] = lb;
  }
}

// out1 = LN(x + concat_h(ho) @ Wlt) -> bf16 hi/lo
__global__ __launch_bounds__(256, 2) void k_merge(
    const float* __restrict__ x, const ushort* __restrict__ hoh,
    const ushort* __restrict__ hol, const ushort* __restrict__ wth,
    const ushort* __restrict__ wtl, const float* __restrict__ g1l,
    const float* __restrict__ b1l, ushort* __restrict__ out1h,
    ushort* __restrict__ out1l) {
  __shared__ ushort sAh[2][4096], sAl[2][4096], sBh[2][4096], sBl[2][4096];
  __shared__ float sred[2][64][4];
  __shared__ float sfin[64][2];
  int tid = threadIdx.x;
  int lane = tid & 63, w = tid >> 6;
  int l15 = lane & 15, g = lane >> 4;
  int blk = blockIdx.x;
  int b = blk >> 4, t0 = (blk & 15) << 6;

  {
    size_t ab0 = (((size_t)b * HH + 0) * TT + t0) * NN;
    size_t ab1 = (((size_t)b * HH + 1) * TT + t0) * NN;
    stage_async(sAh[0], hoh + ab0, 64, tid);
    stage_async(sAl[0], hol + ab0, 64, tid);
    stage_async(sBh[0], wth, 512, tid);
    stage_async(sBl[0], wtl, 512, tid);
    stage_async(sAh[1], hoh + ab1, 64, tid);
    stage_async(sAl[1], hol + ab1, 64, tid);
    stage_async(sBh[1], wth + 64, 512, tid);
    stage_async(sBl[1], wtl + 64, 512, tid);
  }

  f32x4 acc[4];
#pragma unroll
  for (int rt = 0; rt < 4; ++rt)
#pragma unroll
    for (int r = 0; r < 4; ++r) acc[rt][r] = 0.f;

  for (int h = 0; h < 8; ++h) {
    int cur = h & 1;
    if (h < 7) WAIT_VM8(); else WAIT_VM0();
    BAR();
    __builtin_amdgcn_s_setprio(1);
#pragma unroll
    for (int ks = 0; ks < 2; ++ks) {
      short8 bBh = frag(sBh[cur], 16 * w + l15, g + 4 * ks);
      short8 bBl = frag(sBl[cur], 16 * w + l15, g + 4 * ks);
#pragma unroll
      for (int rt = 0; rt < 4; ++rt) {
        short8 aAh = frag(sAh[cur], 16 * rt + l15, g + 4 * ks);
        short8 aAl = frag(sAl[cur], 16 * rt + l15, g + 4 * ks);
        acc[rt] = MFMA16(aAh, bBh, acc[rt]);
        acc[rt] = MFMA16(aAh, bBl, acc[rt]);
        acc[rt] = MFMA16(aAl, bBh, acc[rt]);
      }
    }
    __builtin_amdgcn_s_setprio(0);
    WAIT_LGKM0();
    BAR();
    if (h < 6) {
      int hn = h + 2;
      size_t ab = (((size_t)b * HH + hn) * TT + t0) * NN;
      stage_async(sAh[cur], hoh + ab, 64, tid);
      stage_async(sAl[cur], hol + ab, 64, tid);
      stage_async(sBh[cur], wth + hn * 64, 512, tid);
      stage_async(sBl[cur], wtl + hn * 64, 512, tid);
    }
  }
  int mcol = 16 * w + l15;
  float vv[4][4];
#pragma unroll
  for (int rt = 0; rt < 4; ++rt)
#pragma unroll
    for (int r = 0; r < 4; ++r) {
      int row = 16 * rt + 4 * g + r;
      vv[rt][r] = acc[rt][r] + x[((size_t)b * TT + t0 + row) * 64 + mcol];
    }
#pragma unroll
  for (int rt = 0; rt < 4; ++rt)
#pragma unroll
    for (int r = 0; r < 4; ++r) {
      float s1 = vv[rt][r], s2 = vv[rt][r] * vv[rt][r];
#pragma unroll
      for (int mm = 1; mm < 16; mm <<= 1) {
        s1 += __shfl_xor(s1, mm, 64);
        s2 += __shfl_xor(s2, mm, 64);
      }
      if (l15 == 0) {
        int row = 16 * rt + 4 * g + r;
        sred[0][row][w] = s1;
        sred[1][row][w] = s2;
      }
    }
  __syncthreads();
  if (tid < 64) {
    float a1 = sred[0][tid][0] + sred[0][tid][1] + sred[0][tid][2] + sred[0][tid][3];
    float a2 = sred[1][tid][0] + sred[1][tid][1] + sred[1][tid][2] + sred[1][tid][3];
    float mean = a1 * (1.0f / 64.0f);
    float var = a2 * (1.0f / 64.0f) - mean * mean;
    sfin[tid][0] = mean;
    sfin[tid][1] = rsqrtf(var + EPSV);
  }
  __syncthreads();
  float gg = g1l[mcol], bb = b1l[mcol];
#pragma unroll
  for (int rt = 0; rt < 4; ++rt)
#pragma unroll
    for (int r = 0; r < 4; ++r) {
      int row = 16 * rt + 4 * g + r;
      float mean = sfin[row][0], rstd = sfin[row][1];
      float val = (vv[rt][r] - mean) * rstd * gg + bb;
      ushort hb, lb;
      split1(val, hb, lb);
      size_t idx = ((size_t)b * TT + t0 + row) * 64 + mcol;
      out1h[idx] = hb;
      out1l[idx] = lb;
    }
}

// ffn via MFMA: gc = out1@K3s + sclb; f1 = relu(gc + out1); f2 = f1@elW + elb;
// x = LN(out1 + f2).  block = (b, 32-t tile)
__global__ __launch_bounds__(256) void k_ffn(
    const ushort* __restrict__ o1h_, const ushort* __restrict__ o1l_,
    const float* __restrict__ sclb_l, const ushort* __restrict__ k3sTh,
    const ushort* __restrict__ elWTh, const float* __restrict__ elbl,
    const float* __restrict__ g2l, const float* __restrict__ b2l,
    float* __restrict__ xout) {
  __shared__ ushort sAh[2048], sAl[2048];  // 32x64
  __shared__ ushort sB1[4096], sB2[4096];  // K3sT, elWT
  __shared__ float sred[2][32][4];
  __shared__ float sfin[32][2];
  int tid = threadIdx.x;
  int lane = tid & 63, w = tid >> 6;
  int l15 = lane & 15, g = lane >> 4;
  int blk = blockIdx.x;
  int b = blk >> 5, t0 = (blk & 31) << 5;
  size_t rb = ((size_t)b * TT + t0) * 64;

  stage_q32(sAh, o1h_ + rb, tid);
  stage_q32(sAl, o1l_ + rb, tid);
  stage_async(sB1, k3sTh, 64, tid);
  stage_async(sB2, elWTh, 64, tid);
  WAIT_VM0();
  BAR();

  int col = 16 * w + l15;
  f32x4 acc[2];
#pragma unroll
  for (int rt = 0; rt < 2; ++rt)
#pragma unroll
    for (int r = 0; r < 4; ++r) acc[rt][r] = 0.f;
#pragma unroll
  for (int ks = 0; ks < 2; ++ks) {
    short8 bB = frag(sB1, col, g + 4 * ks);
#pragma unroll
    for (int rt = 0; rt < 2; ++rt) {
      acc[rt] = MFMA16(frag(sAh, 16 * rt + l15, g + 4 * ks), bB, acc[rt]);
      acc[rt] = MFMA16(frag(sAl, 16 * rt + l15, g + 4 * ks), bB, acc[rt]);
    }
  }
  float sclb = sclb_l[0];
  int cch = col >> 3, cin = col & 7;
  float o1v[2][4], f1v[2][4];
#pragma unroll
  for (int rt = 0; rt < 2; ++rt)
#pragma unroll
    for (int r = 0; r < 4; ++r) {
      int row = 16 * rt + 4 * g + r;
      int a = row * 64 + (((cch ^ (row & 7)) << 3)) + cin;
      float o1 = bf2f(sAh[a]) + bf2f(sAl[a]);
      o1v[rt][r] = o1;
      f1v[rt][r] = fmaxf(acc[rt][r] + sclb + o1, 0.f);
    }
  __syncthreads();
#pragma unroll
  for (int rt = 0; rt < 2; ++rt)
#pragma unroll
    for (int r = 0; r < 4; ++r) {
      int row = 16 * rt + 4 * g + r;
      int a = row * 64 + (((cch ^ (row & 7)) << 3)) + cin;
      ushort hb, lb;
      split1(f1v[rt][r], hb, lb);
      sAh[a] = hb;
      sAl[a] = lb;
    }
  __syncthreads();
  f32x4 acc2[2];
#pragma unroll
  for (int rt = 0; rt < 2; ++rt)
#pragma unroll
    for (int r = 0; r < 4; ++r) acc2[rt][r] = 0.f;
#pragma unroll
  for (int ks = 0; ks < 2; ++ks) {
    short8 bB = frag(sB2, col, g + 4 * ks);
#pragma unroll
    for (int rt = 0; rt < 2; ++rt) {
      acc2[rt] = MFMA16(frag(sAh, 16 * rt + l15, g + 4 * ks), bB, acc2[rt]);
      acc2[rt] = MFMA16(frag(sAl, 16 * rt + l15, g + 4 * ks), bB, acc2[rt]);
    }
  }
  float elb = elbl[col];
  float vv[2][4];
#pragma unroll
  for (int rt = 0; rt < 2; ++rt)
#pragma unroll
    for (int r = 0; r < 4; ++r) {
      vv[rt][r] = o1v[rt][r] + acc2[rt][r] + elb;
      float s1 = vv[rt][r], s2 = vv[rt][r] * vv[rt][r];
#pragma unroll
      for (int mm = 1; mm < 16; mm <<= 1) {
        s1 += __shfl_xor(s1, mm, 64);
        s2 += __shfl_xor(s2, mm, 64);
      }
      if (l15 == 0) {
        int row = 16 * rt + 4 * g + r;
        sred[0][row][w] = s1;
        sred[1][row][w] = s2;
      }
    }
  __syncthreads();
  if (tid < 32) {
    float a1 = sred[0][tid][0] + sred[0][tid][1] + sred[0][tid][2] + sred[0][tid][3];
    float a2 = sred[1][tid][0] + sred[1][tid][1] + sred[1][tid][2] + sred[1][tid][3];
    float mean = a1 * (1.0f / 64.0f);
    float var = a2 * (1.0f / 64.0f) - mean * mean;
    sfin[tid][0] = mean;
    sfin[tid][1] = rsqrtf(var + EPSV);
  }
  __syncthreads();
  float gg = g2l[col], bb = b2l[col];
#pragma unroll
  for (int rt = 0; rt < 2; ++rt)
#pragma unroll
    for (int r = 0; r < 4; ++r) {
      int row = 16 * rt + 4 * g + r;
      xout[rb + (size_t)row * 64 + col] =
          (vv[rt][r] - sfin[row][0]) * sfin[row][1] * gg + bb;
    }
}

__global__ __launch_bounds__(256) void k_final(
    const float* __restrict__ x, const float* __restrict__ fW1,
    const float* __restrict__ fb1, const float* __restrict__ fW2,
    const float* __restrict__ fb2, float* __restrict__ out) {
  __shared__ float pl[4][64];
  int tid = threadIdx.x;
  int lane = tid & 63, w = tid >> 6;
  size_t b = blockIdx.x;
  float s = 0.f;
  for (int t = 256 * w; t < 256 * w + 256; ++t) s += x[(b * TT + t) * 64 + lane];
  pl[w][lane] = s;
  __syncthreads();
  if (tid < 64) pl[0][tid] = (pl[0][tid] + pl[1][tid] + pl[2][tid] + pl[3][tid]) * (1.0f / TT);
  __syncthreads();
  if (tid < 64) {
    float hv = 0.f;
    if (lane < 32) {
      hv = fb1[lane];
#pragma unroll 8
      for (int n = 0; n < 64; ++n) hv = fmaf(pl[0][n], fW1[n * 32 + lane], hv);
      hv = fmaxf(hv, 0.f) * fW2[lane];
    }
#pragma unroll
    for (int m = 1; m < 64; m <<= 1) hv += __shfl_xor(hv, m, 64);
    if (lane == 0) out[b] = hv + fb2[0];
  }
}

extern "C" void kernel_launch(void* const* d_in, const int* in_sizes, int n_in,
                              void* d_out, int out_size, void* d_ws, size_t ws_size,
                              hipStream_t stream) {
  const float* inputs = (const float*)d_in[0];
  const float* pos_emb = (const float*)d_in[1];
  const float* K3 = (const float*)d_in[2];
  const float* qw = (const float*)d_in[3];
  const float* qb = (const float*)d_in[4];
  const float* kw = (const float*)d_in[5];
  const float* kb = (const float*)d_in[6];
  const float* vw = (const float*)d_in[7];
  const float* vb = (const float*)d_in[8];
  const float* tqW1 = (const float*)d_in[9];
  const float* tqb1 = (const float*)d_in[10];
  const float* tqW2 = (const float*)d_in[11];
  const float* tqb2 = (const float*)d_in[12];
  const float* tqW3 = (const float*)d_in[13];
  const float* tqb3 = (const float*)d_in[14];
  const float* Wlt = (const float*)d_in[15];
  const float* ln1g = (const float*)d_in[16];
  const float* ln1b = (const float*)d_in[17];
  const float* ln2g = (const float*)d_in[18];
  const float* ln2b = (const float*)d_in[19];
  const float* sclw = (const float*)d_in[20];
  const float* sclb = (const float*)d_in[21];
  const float* elW = (const float*)d_in[22];
  const float* elb = (const float*)d_in[23];
  const float* fW1 = (const float*)d_in[24];
  const float* fb1 = (const float*)d_in[25];
  const float* fW2 = (const float*)d_in[26];
  const float* fb2 = (const float*)d_in[27];
  float* out = (float*)d_out;
  float* ws_f = (float*)d_ws;

  const size_t TN = (size_t)TT * NN;
  const size_t HTN = (size_t)HH * TT * NN;
  const size_t W1T_ELEMS = (size_t)LL * HH * NN * TT;  // ushorts
  const size_t WLT_ELEMS = (size_t)LL * 64 * 512;      // ushorts

  ushort* k3sTh = (ushort*)ws_f;                      // LL*4096
  ushort* w1Th = k3sTh + (size_t)LL * 4096;           // W1T_ELEMS
  ushort* wth = w1Th + W1T_ELEMS;                     // WLT_ELEMS
  ushort* wtl = wth + WLT_ELEMS;                      // WLT_ELEMS
  ushort* w2Th = wtl + WLT_ELEMS;                     // LL*HH*4096
  ushort* elWTh = w2Th + (size_t)LL * HH * 4096;      // LL*4096
  size_t base_ush = (size_t)LL * 4096 + W1T_ELEMS + 2 * WLT_ELEMS +
                    (size_t)LL * HH * 4096 + (size_t)LL * 4096;
  const size_t base = (base_ush + 1) / 2;  // words

  for (int l = 0; l < LL; ++l)
    k_k3s<<<16, 256, 0, stream>>>(K3, sclw + l * KSS, k3sTh + (size_t)l * 4096);
  k_tsplit<<<LL * HH * 16, 256, 0, stream>>>(tqW1, w1Th);
  k_tsplitW<<<LL * 8, 256, 0, stream>>>(Wlt, wth, wtl);
  k_tsplitSq<<<LL * HH, 256, 0, stream>>>(tqW2, w2Th);
  k_tsplitSq<<<LL, 256, 0, stream>>>(elW, elWTh);

  // per-batch f32 words: x TN + xv HTN + auv HTN + lse HH*TT + out1h/l TN
  //  + h1h HTN/2 + xqh HTN/2 + xkh HTN/2 + xvTh HTN/2 + hoh+hol HTN
  const size_t per_b = 2 * TN + (size_t)HH * TT + 5 * HTN;
  size_t avail = ws_size / sizeof(float);
  avail = (avail > base) ? avail - base : 0;
  int Bc = (int)(avail / per_b);
  if (Bc > BB) Bc = BB;
  if (Bc < 1) Bc = 1;

  for (int b0 = 0; b0 < BB; b0 += Bc) {
    int bc = (BB - b0 < Bc) ? (BB - b0) : Bc;
    float* x = ws_f + base;
    float* xv = x + (size_t)bc * TN;
    float* auv = xv + (size_t)bc * HTN;
    float* lseb = auv + (size_t)bc * HTN;
    ushort* out1h = (ushort*)(lseb + (size_t)bc * HH * TT);
    ushort* out1l = out1h + (size_t)bc * TN;
    ushort* h1h = out1l + (size_t)bc * TN;
    ushort* xqh = h1h + (size_t)bc * HTN;
    ushort* xkh = xqh + (size_t)bc * HTN;
    ushort* xvTh = xkh + (size_t)bc * HTN;
    ushort* hoh = xvTh + (size_t)bc * HTN;
    ushort* hol = hoh + (size_t)bc * HTN;

    int total = bc * (int)TN;
    k_addpos<<<(total + 255) / 256, 256, 0, stream>>>(inputs + (size_t)b0 * TN, pos_emb, x,
                                                      total);
    for (int l = 0; l < LL; ++l) {
      k_gconv<<<bc * TT / 4, 256, 0, stream>>>(x, K3, qw + l * HH * KSS, qb + l * HH,
                                               kw + l * HH * KSS, kb + l * HH,
                                               vw + l * HH * KSS, vb + l * HH,
                                               xqh, xkh, xv);
      k_tsplit<<<bc * HH * 16, 256, 0, stream>>>(xv, xvTh);
      k_attn<<<bc * HH * 16, 256, 0, stream>>>(xkh, xqh, xvTh, auv, lseb);
      k_h1<<<bc * HH * 16, 256, 0, stream>>>(
          xkh, xqh, w1Th + (size_t)l * HH * NN * TT, lseb,
          tqb1 + l * HH * DD1, h1h);
      k_gate<<<bc * HH * 16, 256, 0, stream>>>(
          h1h, xv, w2Th + (size_t)l * HH * 4096, tqb2 + l * HH * DD1,
          tqW3 + (size_t)l * HH * DD1 * 2, tqb3 + l * HH * 2, auv, hoh, hol);
      k_merge<<<bc * 16, 256, 0, stream>>>(x, hoh, hol, wth + (size_t)l * 64 * 512,
                                           wtl + (size_t)l * 64 * 512, ln1g + l * NN,
                                           ln1b + l * NN, out1h, out1l);
      k_ffn<<<bc * 32, 256, 0, stream>>>(out1h, out1l, sclb + l,
                                         k3sTh + (size_t)l * 4096,
                                         elWTh + (size_t)l * 4096, elb + l * NN,
                                         ln2g + l * NN, ln2b + l * NN, x);
    }
    k_final<<<bc, 256, 0, stream>>>(x, fW1, fb1, fW2, fb2, out + b0);
  }
}

// Round 11
// 245.731 us; speedup vs baseline: 3.0425x; 1.0648x over previous
//
#include <hip/hip_runtime.h>

typedef __attribute__((ext_vector_type(8))) short short8;
typedef __attribute__((ext_vector_type(4))) float f32x4;

#define BB 8
#define TT 1024
#define NN 64
#define HH 8
#define LL 2
#define KSS 3
#define DD1 64
#define EPSV 1e-6f
#define LOG2E 1.4426950408889634f

#define MFMA16(a, b, c) __builtin_amdgcn_mfma_f32_16x16x32_bf16(a, b, c, 0, 0, 0)
#define BAR() __builtin_amdgcn_s_barrier()
#define WAIT_VM8() asm volatile("s_waitcnt vmcnt(8)" ::: "memory")
#define WAIT_VM2() asm volatile("s_waitcnt vmcnt(2)" ::: "memory")
#define WAIT_VM0() asm volatile("s_waitcnt vmcnt(0)" ::: "memory")
#define WAIT_LGKM0() asm volatile("s_waitcnt lgkmcnt(0)" ::: "memory")

__device__ __forceinline__ float exp2_(float x) { return __builtin_amdgcn_exp2f(x); }
__device__ __forceinline__ float log2_(float x) { return __builtin_amdgcn_logf(x); }

// ---- truncation-based hi/lo bf16 split (hi error lands exactly in lo) ----
__device__ __forceinline__ void split1(float x, ushort& hi, ushort& lo) {
  uint u = __float_as_uint(x);
  hi = (ushort)(u >> 16);
  float hf = __uint_as_float(u & 0xffff0000u);
  lo = (ushort)(__float_as_uint(x - hf) >> 16);
}
__device__ __forceinline__ uint pack2(float a, float b, uint& lo) {
  uint ua = __float_as_uint(a), ub = __float_as_uint(b);
  float ra = __uint_as_float(ua & 0xffff0000u);
  float rb = __uint_as_float(ub & 0xffff0000u);
  lo = (__float_as_uint(a - ra) >> 16) | (__float_as_uint(b - rb) & 0xffff0000u);
  return (ua >> 16) | (ub & 0xffff0000u);
}
// round-half-up packed pair
__device__ __forceinline__ uint pack2rhu(float a, float b) {
  uint ua = __float_as_uint(a) + 0x8000u;
  uint ub = __float_as_uint(b) + 0x8000u;
  return (ua >> 16) | (ub & 0xffff0000u);
}
// round-to-nearest-even bf16
__device__ __forceinline__ ushort f2bfr(float x) {
  union { float f; uint u; } v; v.f = x;
  uint r = (v.u + 0x7fffu + ((v.u >> 16) & 1u)) >> 16;
  return (ushort)r;
}
__device__ __forceinline__ float bf2f(ushort b) {
  union { uint u; float f; } v; v.u = ((uint)b) << 16; return v.f;
}

// ---- async global->LDS staging ----
__device__ __forceinline__ void gl2lds16(const ushort* g, ushort* l) {
  __builtin_amdgcn_global_load_lds(
      (const __attribute__((address_space(1))) void*)g,
      (__attribute__((address_space(3))) void*)l, 16, 0, 0);
}
// 64x64 tile, chunk swizzle c ^ (r&7); 2 gl_lds/wave
__device__ __forceinline__ void stage_async(ushort* __restrict__ s,
                                            const ushort* __restrict__ g,
                                            int stride, int tid) {
  int w = tid >> 6;
  int sub = (tid & 63) >> 3, c = tid & 7;
#pragma unroll
  for (int i = 0; i < 2; ++i) {
    int rb = (i * 4 + w) * 8;
    gl2lds16(g + (size_t)(rb + sub) * stride + ((c ^ sub) << 3), s + rb * 64);
  }
}
__device__ __forceinline__ short8 frag(const ushort* __restrict__ s, int row, int ch) {
  return *(const short8*)(s + row * 64 + ((ch ^ (row & 7)) << 3));
}
// 32x64 tile; 1 gl_lds/wave
__device__ __forceinline__ void stage_q32(ushort* __restrict__ s,
                                          const ushort* __restrict__ g, int tid) {
  int w = tid >> 6;
  int sub = (tid & 63) >> 3, c = tid & 7;
  int rb = w * 8, r = rb + sub;
  gl2lds16(g + (size_t)r * 64 + ((c ^ (r & 7)) << 3), s + rb * 64);
}
// 64x32 tile (stride 1024), chunk swizzle c ^ ((n>>1)&3); 1 gl_lds/wave
__device__ __forceinline__ void stage_v32(ushort* __restrict__ s,
                                          const ushort* __restrict__ g, int tid) {
  int w = tid >> 6;
  int noff = (tid & 63) >> 2, c = tid & 3;
  int nb = w * 16, n = nb + noff;
  gl2lds16(g + (size_t)n * 1024 + ((c ^ ((n >> 1) & 3)) << 3), s + nb * 32);
}
__device__ __forceinline__ short8 frag32(const ushort* __restrict__ s, int row, int g) {
  return *(const short8*)(s + row * 32 + ((g ^ ((row >> 1) & 3)) << 3));
}

// ---------- small kernels ----------

__global__ void k_addpos(const float* __restrict__ in, const float* __restrict__ pe,
                         float* __restrict__ x, int total) {
  int idx = blockIdx.x * 256 + threadIdx.x;
  if (idx < total) {
    int tn = idx & (TT * NN - 1);
    x[idx] = in[idx] + pe[tn];
  }
}

// K3s^T (bf16 RNE)
__global__ void k_k3s(const float* __restrict__ K3, const float* __restrict__ sclwl,
                      ushort* __restrict__ dh) {
  int idx = blockIdx.x * 256 + threadIdx.x;
  int n = idx >> 6, m = idx & 63;
  float v = K3[n * 192 + m] * sclwl[0] + K3[n * 192 + 64 + m] * sclwl[1] +
            K3[n * 192 + 128 + m] * sclwl[2];
  dh[m * 64 + n] = f2bfr(v);
}

// transpose, hi-only RNE: src [mat][1024][64] f32 -> dh [mat][64][1024] bf16
__global__ __launch_bounds__(256) void k_tsplit(const float* __restrict__ src,
                                                ushort* __restrict__ dh) {
  __shared__ float st[64][65];
  int blk = blockIdx.x;
  int mat = blk >> 4, rt = blk & 15;
  int tid = threadIdx.x;
  size_t sbase = ((size_t)mat * TT + rt * 64) * 64;
#pragma unroll
  for (int i = 0; i < 4; ++i) {
    int idx = tid + i * 256;
    int r = idx >> 4, c4 = idx & 15;
    float4 v = *(const float4*)(src + sbase + r * 64 + c4 * 4);
    st[r][c4 * 4 + 0] = v.x; st[r][c4 * 4 + 1] = v.y;
    st[r][c4 * 4 + 2] = v.z; st[r][c4 * 4 + 3] = v.w;
  }
  __syncthreads();
  size_t obase = (size_t)mat * (64 * (size_t)TT) + rt * 64;
#pragma unroll
  for (int i = 0; i < 2; ++i) {
    int idx = tid + i * 256;
    int n = idx >> 3, c = idx & 7;
    uint hw[4];
#pragma unroll
    for (int j = 0; j < 4; ++j)
      hw[j] = (uint)f2bfr(st[c * 8 + 2 * j][n]) | ((uint)f2bfr(st[c * 8 + 2 * j + 1][n]) << 16);
    *(uint4*)(dh + obase + (size_t)n * TT + c * 8) = make_uint4(hw[0], hw[1], hw[2], hw[3]);
  }
}

// transpose+split Wlt (hi/lo)
__global__ __launch_bounds__(256) void k_tsplitW(const float* __restrict__ Wlt,
                                                 ushort* __restrict__ dh,
                                                 ushort* __restrict__ dl) {
  __shared__ float st[64][65];
  int blk = blockIdx.x;
  int l = blk >> 3, rt = blk & 7;
  int tid = threadIdx.x;
  size_t sbase = ((size_t)l * 512 + rt * 64) * 64;
#pragma unroll
  for (int i = 0; i < 4; ++i) {
    int idx = tid + i * 256;
    int r = idx >> 4, c4 = idx & 15;
    float4 v = *(const float4*)(Wlt + sbase + r * 64 + c4 * 4);
    st[r][c4 * 4 + 0] = v.x; st[r][c4 * 4 + 1] = v.y;
    st[r][c4 * 4 + 2] = v.z; st[r][c4 * 4 + 3] = v.w;
  }
  __syncthreads();
  size_t obase = (size_t)l * 64 * 512 + rt * 64;
#pragma unroll
  for (int i = 0; i < 2; ++i) {
    int idx = tid + i * 256;
    int n = idx >> 3, c = idx & 7;
    uint hw[4], lw[4];
#pragma unroll
    for (int j = 0; j < 4; ++j) hw[j] = pack2(st[c * 8 + 2 * j][n], st[c * 8 + 2 * j + 1][n], lw[j]);
    *(uint4*)(dh + obase + (size_t)n * 512 + c * 8) = make_uint4(hw[0], hw[1], hw[2], hw[3]);
    *(uint4*)(dl + obase + (size_t)n * 512 + c * 8) = make_uint4(lw[0], lw[1], lw[2], lw[3]);
  }
}

// square transpose, hi-only RNE
__global__ __launch_bounds__(256) void k_tsplitSq(const float* __restrict__ src,
                                                  ushort* __restrict__ dh) {
  __shared__ float st[64][65];
  int mat = blockIdx.x;
  int tid = threadIdx.x;
  size_t sbase = (size_t)mat * 4096;
#pragma unroll
  for (int i = 0; i < 4; ++i) {
    int idx = tid + i * 256;
    int r = idx >> 4, c4 = idx & 15;
    float4 v = *(const float4*)(src + sbase + r * 64 + c4 * 4);
    st[r][c4 * 4 + 0] = v.x; st[r][c4 * 4 + 1] = v.y;
    st[r][c4 * 4 + 2] = v.z; st[r][c4 * 4 + 3] = v.w;
  }
  __syncthreads();
#pragma unroll
  for (int i = 0; i < 2; ++i) {
    int idx = tid + i * 256;
    int d = idx >> 3, c = idx & 7;
    uint hw[4];
#pragma unroll
    for (int j = 0; j < 4; ++j)
      hw[j] = (uint)f2bfr(st[c * 8 + 2 * j][d]) | ((uint)f2bfr(st[c * 8 + 2 * j + 1][d]) << 16);
    *(uint4*)(dh + sbase + (size_t)d * 64 + c * 8) = make_uint4(hw[0], hw[1], hw[2], hw[3]);
  }
}

// gconv: 256-thr blocks, K3 staged in LDS, 4 (b,t) rows per block
__global__ __launch_bounds__(256) void k_gconv(
    const float* __restrict__ x, const float* __restrict__ K3,
    const float* __restrict__ qwl, const float* __restrict__ qbl,
    const float* __restrict__ kwl, const float* __restrict__ kbl,
    const float* __restrict__ vwl, const float* __restrict__ vbl,
    ushort* __restrict__ xqh, ushort* __restrict__ xkh, float* __restrict__ xv) {
  __shared__ float sK3[12288];
  __shared__ float sx[4][64];
  int tid = threadIdx.x;
  int w = tid >> 6, lane = tid & 63;
#pragma unroll
  for (int i = 0; i < 12; ++i)
    ((float4*)sK3)[tid + i * 256] = ((const float4*)K3)[tid + i * 256];
  size_t bt = (size_t)blockIdx.x * 4 + w;
  size_t b = bt >> 10, t = bt & 1023;
  float xm = x[bt * 64 + lane];
  sx[w][lane] = xm;
  __syncthreads();
  float a0 = 0.f, a1 = 0.f, a2 = 0.f;
#pragma unroll 8
  for (int n = 0; n < 64; ++n) {
    float xn = sx[w][n];
    a0 = fmaf(xn, sK3[n * 192 + lane], a0);
    a1 = fmaf(xn, sK3[n * 192 + 64 + lane], a1);
    a2 = fmaf(xn, sK3[n * 192 + 128 + lane], a2);
  }
#pragma unroll
  for (int hh = 0; hh < HH; ++hh) {
    size_t off = (((size_t)b * HH + hh) * TT + t) * 64 + lane;
    float q = fmaf(qwl[hh * 3 + 0], a0,
              fmaf(qwl[hh * 3 + 1], a1, fmaf(qwl[hh * 3 + 2], a2, qbl[hh] + xm)));
    q = fmaxf(q, 0.f) * (0.015625f * LOG2E);
    xqh[off] = f2bfr(q);
    float k = fmaf(kwl[hh * 3 + 0], a0,
              fmaf(kwl[hh * 3 + 1], a1, fmaf(kwl[hh * 3 + 2], a2, kbl[hh] + xm)));
    xkh[off] = f2bfr(fmaxf(k, 0.f));
    float v = fmaf(vwl[hh * 3 + 0], a0,
              fmaf(vwl[hh * 3 + 1], a1, fmaf(vwl[hh * 3 + 2], a2, vbl[hh] + xm)));
    xv[off] = fmaxf(v, 0.f);
  }
}

// ---------- pass A: flash attention, NO-MAX softmax (S >= 0 bounded) ----------
__global__ __launch_bounds__(256, 4) void k_attn(
    const ushort* __restrict__ xkh, const ushort* __restrict__ xqh,
    const ushort* __restrict__ xvTh,
    float* __restrict__ auv, float* __restrict__ lse) {
  __shared__ ushort sQh[4096];  // 2 bufs x 32x64 (prologue: K 64x64 tile)
  __shared__ ushort sVh[4096];  // 2 bufs x 64x32
  __shared__ ushort sPh[2048];  // 64x32
  int tid = threadIdx.x;
  int lane = tid & 63, w = tid >> 6;
  int l15 = lane & 15, g = lane >> 4;
  int nb = gridDim.x, chunk = nb >> 3, bid = blockIdx.x;
  int blk = (bid & 7) * chunk + (bid >> 3);  // XCD swizzle (nb % 8 == 0)
  int bh = blk >> 4, t0 = (blk & 15) << 6;
  size_t bhTT = (size_t)bh * TT;
  int trow = 16 * w + l15, psw = (trow >> 1) & 3;

  stage_async(sQh, xkh + (bhTT + t0) * NN, 64, tid);
  WAIT_VM0();
  BAR();
  short8 fKh[2];
#pragma unroll
  for (int ks = 0; ks < 2; ++ks) fKh[ks] = frag(sQh, trow, g + 4 * ks);
  WAIT_LGKM0();
  BAR();
  stage_q32(sQh, xqh + bhTT * NN, tid);
  stage_v32(sVh, xvTh + bhTT * NN, tid);
  stage_q32(sQh + 2048, xqh + (bhTT + 32) * NN, tid);
  stage_v32(sVh + 2048, xvTh + bhTT * NN + 32, tid);

  float lsum = 0.f;
  f32x4 O[4];
#pragma unroll
  for (int ct = 0; ct < 4; ++ct)
#pragma unroll
    for (int r = 0; r < 4; ++r) O[ct][r] = 0.f;

  for (int ut = 0; ut < 32; ++ut) {
    int cur = ut & 1;
    if (ut < 31) WAIT_VM2(); else WAIT_VM0();
    BAR();
    const ushort* cQh = sQh + cur * 2048;
    const ushort* cVh = sVh + cur * 2048;

    __builtin_amdgcn_s_setprio(1);
    f32x4 S[2];
#pragma unroll
    for (int rt = 0; rt < 2; ++rt) {
      f32x4 a = {0.f, 0.f, 0.f, 0.f};
#pragma unroll
      for (int ks = 0; ks < 2; ++ks)
        a = MFMA16(frag(cQh, 16 * rt + l15, g + 4 * ks), fKh[ks], a);
      S[rt] = a;
    }
    __builtin_amdgcn_s_setprio(0);

    uint2 ph[2];
#pragma unroll
    for (int rt = 0; rt < 2; ++rt) {
      float p0 = exp2_(S[rt][0]), p1 = exp2_(S[rt][1]);
      float p2 = exp2_(S[rt][2]), p3 = exp2_(S[rt][3]);
      lsum += (p0 + p1) + (p2 + p3);
      ph[rt].x = pack2rhu(p0, p1);
      ph[rt].y = pack2rhu(p2, p3);
    }
#pragma unroll
    for (int rt = 0; rt < 2; ++rt) {
      int ch = 2 * rt + (g >> 1);
      int off = trow * 32 + ((ch ^ psw) << 3) + ((g & 1) << 2);
      *(uint2*)(sPh + off) = ph[rt];
    }
    WAIT_LGKM0();
    __builtin_amdgcn_sched_barrier(0);
    __builtin_amdgcn_s_setprio(1);
    {
      short8 aPh = frag32(sPh, trow, g);
#pragma unroll
      for (int ct = 0; ct < 4; ++ct)
        O[ct] = MFMA16(aPh, frag32(cVh, 16 * ct + l15, g), O[ct]);
    }
    __builtin_amdgcn_s_setprio(0);
    WAIT_LGKM0();
    BAR();
    if (ut < 30) {
      int tn = ut + 2;
      stage_q32(sQh + cur * 2048, xqh + (bhTT + tn * 32) * NN, tid);
      stage_v32(sVh + cur * 2048, xvTh + bhTT * NN + tn * 32, tid);
    }
  }
  lsum += __shfl_xor(lsum, 16, 64);
  lsum += __shfl_xor(lsum, 32, 64);
  float il = 1.0f / lsum;
  float ilr[4];
#pragma unroll
  for (int r = 0; r < 4; ++r) ilr[r] = __shfl(il, (lane & 48) | (4 * g + r), 64);
#pragma unroll
  for (int r = 0; r < 4; ++r) {
    size_t row = (bhTT + t0 + 16 * w + 4 * g + r) * NN;
#pragma unroll
    for (int ct = 0; ct < 4; ++ct) auv[row + 16 * ct + l15] = O[ct][r] * ilr[r];
  }
  if (g == 0) lse[bhTT + t0 + trow] = log2_(lsum);
}

// ---------- pass B fused with gate: h1 -> h2 -> g -> ho ----------
__global__ __launch_bounds__(256, 4) void k_h1g(
    const ushort* __restrict__ xkh, const ushort* __restrict__ xqh,
    const ushort* __restrict__ w1Th, const float* __restrict__ lse,
    const float* __restrict__ b1, const ushort* __restrict__ w2Th,
    const float* __restrict__ b2l, const float* __restrict__ W3l,
    const float* __restrict__ b3l, const float* __restrict__ auv,
    const float* __restrict__ xv, ushort* __restrict__ hoh,
    ushort* __restrict__ hol) {
  __shared__ ushort sKh[4096];  // 2 bufs x 32x64 (prologue: Q hi tile)
  __shared__ ushort sWh[4096];  // 2 bufs x 64x32 -> epilogue: h1 64x64
  __shared__ ushort sPh[2048];
  __shared__ ushort sW2[4096];  // W2^T 64x64, persistent
  __shared__ float sL[1024];    // lse table -> epilogue scratch
  int tid = threadIdx.x;
  int lane = tid & 63, w = tid >> 6;
  int l15 = lane & 15, g = lane >> 4;
  int nb = gridDim.x, chunk = nb >> 3, bid = blockIdx.x;
  int blk = (bid & 7) * chunk + (bid >> 3);
  int bh = blk >> 4, h = bh & (HH - 1), a0 = (blk & 15) << 6;
  size_t bhTT = (size_t)bh * TT;
  size_t wbase = (size_t)h * NN * TT;
  int arow = 16 * w + l15, psw = (arow >> 1) & 3;

  stage_async(sKh, xqh + (bhTT + a0) * NN, 64, tid);
  stage_async(sW2, w2Th + (size_t)h * 4096, 64, tid);
  WAIT_VM0();
  BAR();
  short8 fQh[2];
#pragma unroll
  for (int ks = 0; ks < 2; ++ks) fQh[ks] = frag(sKh, arow, g + 4 * ks);
#pragma unroll
  for (int i = 0; i < 4; ++i) sL[tid + i * 256] = lse[bhTT + tid + i * 256];
  WAIT_LGKM0();
  BAR();
  stage_q32(sKh, xkh + bhTT * NN, tid);
  stage_v32(sWh, w1Th + wbase, tid);
  stage_q32(sKh + 2048, xkh + (bhTT + 32) * NN, tid);
  stage_v32(sWh + 2048, w1Th + wbase + 32, tid);

  f32x4 acc[4];
#pragma unroll
  for (int ct = 0; ct < 4; ++ct)
#pragma unroll
    for (int r = 0; r < 4; ++r) acc[ct][r] = 0.f;

  for (int tt = 0; tt < 32; ++tt) {
    int cur = tt & 1;
    if (tt < 31) WAIT_VM2(); else WAIT_VM0();
    BAR();
    const ushort* cKh = sKh + cur * 2048;
    const ushort* cWh = sWh + cur * 2048;

    __builtin_amdgcn_s_setprio(1);
    f32x4 S[2];
#pragma unroll
    for (int rt = 0; rt < 2; ++rt) {
      f32x4 a = {0.f, 0.f, 0.f, 0.f};
#pragma unroll
      for (int ks = 0; ks < 2; ++ks)
        a = MFMA16(frag(cKh, 16 * rt + l15, g + 4 * ks), fQh[ks], a);
      S[rt] = a;
    }
    __builtin_amdgcn_s_setprio(0);

    uint2 ph[2];
#pragma unroll
    for (int rt = 0; rt < 2; ++rt) {
      f32x4 lv = *(const f32x4*)(sL + tt * 32 + 16 * rt + 4 * g);
      float p0 = exp2_(S[rt][0] - lv[0]);
      float p1 = exp2_(S[rt][1] - lv[1]);
      float p2 = exp2_(S[rt][2] - lv[2]);
      float p3 = exp2_(S[rt][3] - lv[3]);
      ph[rt].x = pack2rhu(p0, p1);
      ph[rt].y = pack2rhu(p2, p3);
    }
#pragma unroll
    for (int rt = 0; rt < 2; ++rt) {
      int ch = 2 * rt + (g >> 1);
      int off = arow * 32 + ((ch ^ psw) << 3) + ((g & 1) << 2);
      *(uint2*)(sPh + off) = ph[rt];
    }
    WAIT_LGKM0();
    __builtin_amdgcn_sched_barrier(0);
    __builtin_amdgcn_s_setprio(1);
    {
      short8 aPh = frag32(sPh, arow, g);
#pragma unroll
      for (int ct = 0; ct < 4; ++ct)
        acc[ct] = MFMA16(aPh, frag32(cWh, 16 * ct + l15, g), acc[ct]);
    }
    __builtin_amdgcn_s_setprio(0);
    WAIT_LGKM0();
    BAR();
    if (tt < 30) {
      int tn = tt + 2;
      stage_q32(sKh + cur * 2048, xkh + (bhTT + tn * 32) * NN, tid);
      stage_v32(sWh + cur * 2048, w1Th + wbase + tn * 32, tid);
    }
  }
  // ---- epilogue: gate fused ----
  // h1 = relu(acc + b1), write bf16 RNE into sWh (64x64 A-layout swizzled)
#pragma unroll
  for (int ct = 0; ct < 4; ++ct) {
    float bb = b1[h * 64 + 16 * ct + l15];
    int cch = 2 * ct + (l15 >> 3), cin = l15 & 7;
#pragma unroll
    for (int r = 0; r < 4; ++r) {
      int row = 16 * w + 4 * g + r;
      float hv = fmaxf(acc[ct][r] + bb, 0.f);
      sWh[row * 64 + ((cch ^ (row & 7)) << 3) + cin] = f2bfr(hv);
    }
  }
  WAIT_LGKM0();
  BAR();
  // h2 = h1 @ W2
  f32x4 acc2[4];
#pragma unroll
  for (int rt = 0; rt < 4; ++rt)
#pragma unroll
    for (int r = 0; r < 4; ++r) acc2[rt][r] = 0.f;
#pragma unroll
  for (int ks = 0; ks < 2; ++ks) {
    short8 bB = frag(sW2, 16 * w + l15, g + 4 * ks);
#pragma unroll
    for (int rt = 0; rt < 4; ++rt)
      acc2[rt] = MFMA16(frag(sWh, 16 * rt + l15, g + 4 * ks), bB, acc2[rt]);
  }
  int col = 16 * w + l15;
  float b2c = b2l[h * 64 + col];
  float w30 = W3l[h * 128 + col * 2 + 0];
  float w31 = W3l[h * 128 + col * 2 + 1];
  float* sredf = sL;        // [2][64][4] = 512 floats
  float* sgf = sL + 512;    // [64][2]
#pragma unroll
  for (int rt = 0; rt < 4; ++rt)
#pragma unroll
    for (int r = 0; r < 4; ++r) {
      float v = fmaxf(acc2[rt][r] + b2c, 0.f);
      float z0 = v * w30, z1 = v * w31;
#pragma unroll
      for (int mm = 1; mm < 16; mm <<= 1) {
        z0 += __shfl_xor(z0, mm, 64);
        z1 += __shfl_xor(z1, mm, 64);
      }
      if (l15 == 0) {
        int row = 16 * rt + 4 * g + r;
        sredf[row * 4 + w] = z0;
        sredf[256 + row * 4 + w] = z1;
      }
    }
  __syncthreads();
  if (tid < 64) {
    float z0 = sredf[tid * 4] + sredf[tid * 4 + 1] + sredf[tid * 4 + 2] +
               sredf[tid * 4 + 3] + b3l[h * 2 + 0];
    float z1 = sredf[256 + tid * 4] + sredf[256 + tid * 4 + 1] +
               sredf[256 + tid * 4 + 2] + sredf[256 + tid * 4 + 3] + b3l[h * 2 + 1];
    float g0 = 1.0f / (1.0f + __expf(z1 - z0));
    sgf[tid * 2] = g0;
    sgf[tid * 2 + 1] = 1.0f - g0;
  }
  __syncthreads();
#pragma unroll
  for (int rr = 0; rr < 16; ++rr) {
    int row = 16 * w + rr;
    size_t off = (bhTT + a0 + row) * 64 + lane;
    float ho = sgf[row * 2] * auv[off] + sgf[row * 2 + 1] * xv[off];
    ushort hb, lb;
    split1(ho, hb, lb);
    hoh[off] = hb;
    hol[off] = lb;
  }
}

// ---------- merge fused with ffn: out1 = LN(x + ho@Wlt); x = LN(out1 + ffn) ----------
__global__ __launch_bounds__(256, 2) void k_mrgf(
    float* __restrict__ x, const ushort* __restrict__ hoh,
    const ushort* __restrict__ hol, const ushort* __restrict__ wth,
    const ushort* __restrict__ wtl, const float* __restrict__ g1l,
    const float* __restrict__ b1l, const float* __restrict__ sclb_l,
    const ushort* __restrict__ k3sTh, const ushort* __restrict__ elWTh,
    const float* __restrict__ elbl, const float* __restrict__ g2l,
    const float* __restrict__ b2l) {
  __shared__ ushort sAh[2][4096], sAl[2][4096], sBh[2][4096], sBl[2][4096];
  __shared__ float sred[2][64][4];
  __shared__ float sfin[64][2];
  int tid = threadIdx.x;
  int lane = tid & 63, w = tid >> 6;
  int l15 = lane & 15, g = lane >> 4;
  int blk = blockIdx.x;
  int b = blk >> 4, t0 = (blk & 15) << 6;

  {
    size_t ab0 = (((size_t)b * HH + 0) * TT + t0) * NN;
    size_t ab1 = (((size_t)b * HH + 1) * TT + t0) * NN;
    stage_async(sAh[0], hoh + ab0, 64, tid);
    stage_async(sAl[0], hol + ab0, 64, tid);
    stage_async(sBh[0], wth, 512, tid);
    stage_async(sBl[0], wtl, 512, tid);
    stage_async(sAh[1], hoh + ab1, 64, tid);
    stage_async(sAl[1], hol + ab1, 64, tid);
    stage_async(sBh[1], wth + 64, 512, tid);
    stage_async(sBl[1], wtl + 64, 512, tid);
  }

  f32x4 acc[4];
#pragma unroll
  for (int rt = 0; rt < 4; ++rt)
#pragma unroll
    for (int r = 0; r < 4; ++r) acc[rt][r] = 0.f;

  for (int h = 0; h < 8; ++h) {
    int cur = h & 1;
    if (h < 7) WAIT_VM8(); else WAIT_VM0();
    BAR();
    __builtin_amdgcn_s_setprio(1);
#pragma unroll
    for (int ks = 0; ks < 2; ++ks) {
      short8 bBh = frag(sBh[cur], 16 * w + l15, g + 4 * ks);
      short8 bBl = frag(sBl[cur], 16 * w + l15, g + 4 * ks);
#pragma unroll
      for (int rt = 0; rt < 4; ++rt) {
        short8 aAh = frag(sAh[cur], 16 * rt + l15, g + 4 * ks);
        short8 aAl = frag(sAl[cur], 16 * rt + l15, g + 4 * ks);
        acc[rt] = MFMA16(aAh, bBh, acc[rt]);
        acc[rt] = MFMA16(aAh, bBl, acc[rt]);
        acc[rt] = MFMA16(aAl, bBh, acc[rt]);
      }
    }
    __builtin_amdgcn_s_setprio(0);
    WAIT_LGKM0();
    BAR();
    if (h < 6) {
      int hn = h + 2;
      size_t ab = (((size_t)b * HH + hn) * TT + t0) * NN;
      stage_async(sAh[cur], hoh + ab, 64, tid);
      stage_async(sAl[cur], hol + ab, 64, tid);
      stage_async(sBh[cur], wth + hn * 64, 512, tid);
      stage_async(sBl[cur], wtl + hn * 64, 512, tid);
    }
  }
  // ---- epilogue: out1 = LN1(x + acc), then ffn, then x = LN2 ----
  // issue ffn weight stages early (land under LN1 math)
  stage_async(sBh[0], k3sTh, 64, tid);   // K3s^T 64x64
  stage_async(sBl[0], elWTh, 64, tid);   // elW^T 64x64
  int mcol = 16 * w + l15;
  float vv[4][4];
#pragma unroll
  for (int rt = 0; rt < 4; ++rt)
#pragma unroll
    for (int r = 0; r < 4; ++r) {
      int row = 16 * rt + 4 * g + r;
      vv[rt][r] = acc[rt][r] + x[((size_t)b * TT + t0 + row) * 64 + mcol];
    }
#pragma unroll
  for (int rt = 0; rt < 4; ++rt)
#pragma unroll
    for (int r = 0; r < 4; ++r) {
      float s1 = vv[rt][r], s2 = vv[rt][r] * vv[rt][r];
#pragma unroll
      for (int mm = 1; mm < 16; mm <<= 1) {
        s1 += __shfl_xor(s1, mm, 64);
        s2 += __shfl_xor(s2, mm, 64);
      }
      if (l15 == 0) {
        int row = 16 * rt + 4 * g + r;
        sred[0][row][w] = s1;
        sred[1][row][w] = s2;
      }
    }
  __syncthreads();
  if (tid < 64) {
    float a1 = sred[0][tid][0] + sred[0][tid][1] + sred[0][tid][2] + sred[0][tid][3];
    float a2 = sred[1][tid][0] + sred[1][tid][1] + sred[1][tid][2] + sred[1][tid][3];
    float mean = a1 * (1.0f / 64.0f);
    float var = a2 * (1.0f / 64.0f) - mean * mean;
    sfin[tid][0] = mean;
    sfin[tid][1] = rsqrtf(var + EPSV);
  }
  __syncthreads();
  float gg = g1l[mcol], bb1 = b1l[mcol];
  float val[4][4];  // out1 (f32, exact)
  ushort* sH = sAh[0];
  ushort* sHl = sAl[0];
  int cch = mcol >> 3, cin = mcol & 7;
#pragma unroll
  for (int rt = 0; rt < 4; ++rt)
#pragma unroll
    for (int r = 0; r < 4; ++r) {
      int row = 16 * rt + 4 * g + r;
      float v = (vv[rt][r] - sfin[row][0]) * sfin[row][1] * gg + bb1;
      val[rt][r] = v;
      ushort hb, lb;
      split1(v, hb, lb);
      int a = row * 64 + ((cch ^ (row & 7)) << 3) + cin;
      sH[a] = hb;
      sHl[a] = lb;
    }
  WAIT_VM0();    // ffn weights landed
  WAIT_LGKM0();  // out1 LDS writes retired
  BAR();
  // gc = out1 @ K3s
  f32x4 acc3[4];
#pragma unroll
  for (int rt = 0; rt < 4; ++rt)
#pragma unroll
    for (int r = 0; r < 4; ++r) acc3[rt][r] = 0.f;
#pragma unroll
  for (int ks = 0; ks < 2; ++ks) {
    short8 bB = frag(sBh[0], mcol, g + 4 * ks);
#pragma unroll
    for (int rt = 0; rt < 4; ++rt) {
      acc3[rt] = MFMA16(frag(sH, 16 * rt + l15, g + 4 * ks), bB, acc3[rt]);
      acc3[rt] = MFMA16(frag(sHl, 16 * rt + l15, g + 4 * ks), bB, acc3[rt]);
    }
  }
  WAIT_LGKM0();
  BAR();  // all gc A-reads done before overwrite
  float sclb = sclb_l[0];
#pragma unroll
  for (int rt = 0; rt < 4; ++rt)
#pragma unroll
    for (int r = 0; r < 4; ++r) {
      int row = 16 * rt + 4 * g + r;
      float f1 = fmaxf(acc3[rt][r] + sclb + val[rt][r], 0.f);
      ushort hb, lb;
      split1(f1, hb, lb);
      int a = row * 64 + ((cch ^ (row & 7)) << 3) + cin;
      sH[a] = hb;
      sHl[a] = lb;
    }
  WAIT_LGKM0();
  BAR();
  // f2 = f1 @ elW
  f32x4 acc4[4];
#pragma unroll
  for (int rt = 0; rt < 4; ++rt)
#pragma unroll
    for (int r = 0; r < 4; ++r) acc4[rt][r] = 0.f;
#pragma unroll
  for (int ks = 0; ks < 2; ++ks) {
    short8 bB = frag(sBl[0], mcol, g + 4 * ks);
#pragma unroll
    for (int rt = 0; rt < 4; ++rt) {
      acc4[rt] = MFMA16(frag(sH, 16 * rt + l15, g + 4 * ks), bB, acc4[rt]);
      acc4[rt] = MFMA16(frag(sHl, 16 * rt + l15, g + 4 * ks), bB, acc4[rt]);
    }
  }
  float elb = elbl[mcol];
#pragma unroll
  for (int rt = 0; rt < 4; ++rt)
#pragma unroll
    for (int r = 0; r < 4; ++r) {
      float v = val[rt][r] + acc4[rt][r] + elb;
      vv[rt][r] = v;
      float s1 = v, s2 = v * v;
#pragma unroll
      for (int mm = 1; mm < 16; mm <<= 1) {
        s1 += __shfl_xor(s1, mm, 64);
        s2 += __shfl_xor(s2, mm, 64);
      }
      if (l15 == 0) {
        int row = 16 * rt + 4 * g + r;
        sred[0][row][w] = s1;
        sred[1][row][w] = s2;
      }
    }
  __syncthreads();
  if (tid < 64) {
    float a1 = sred[0][tid][0] + sred[0][tid][1] + sred[0][tid][2] + sred[0][tid][3];
    float a2 = sred[1][tid][0] + sred[1][tid][1] + sred[1][tid][2] + sred[1][tid][3];
    float mean = a1 * (1.0f / 64.0f);
    float var = a2 * (1.0f / 64.0f) - mean * mean;
    sfin[tid][0] = mean;
    sfin[tid][1] = rsqrtf(var + EPSV);
  }
  __syncthreads();
  float g2 = g2l[mcol], bb2 = b2l[mcol];
#pragma unroll
  for (int rt = 0; rt < 4; ++rt)
#pragma unroll
    for (int r = 0; r < 4; ++r) {
      int row = 16 * rt + 4 * g + r;
      x[((size_t)b * TT + t0 + row) * 64 + mcol] =
          (vv[rt][r] - sfin[row][0]) * sfin[row][1] * g2 + bb2;
    }
}

__global__ __launch_bounds__(256) void k_final(
    const float* __restrict__ x, const float* __restrict__ fW1,
    const float* __restrict__ fb1, const float* __restrict__ fW2,
    const float* __restrict__ fb2, float* __restrict__ out) {
  __shared__ float pl[4][64];
  int tid = threadIdx.x;
  int lane = tid & 63, w = tid >> 6;
  size_t b = blockIdx.x;
  float s = 0.f;
  for (int t = 256 * w; t < 256 * w + 256; ++t) s += x[(b * TT + t) * 64 + lane];
  pl[w][lane] = s;
  __syncthreads();
  if (tid < 64) pl[0][tid] = (pl[0][tid] + pl[1][tid] + pl[2][tid] + pl[3][tid]) * (1.0f / TT);
  __syncthreads();
  if (tid < 64) {
    float hv = 0.f;
    if (lane < 32) {
      hv = fb1[lane];
#pragma unroll 8
      for (int n = 0; n < 64; ++n) hv = fmaf(pl[0][n], fW1[n * 32 + lane], hv);
      hv = fmaxf(hv, 0.f) * fW2[lane];
    }
#pragma unroll
    for (int m = 1; m < 64; m <<= 1) hv += __shfl_xor(hv, m, 64);
    if (lane == 0) out[b] = hv + fb2[0];
  }
}

extern "C" void kernel_launch(void* const* d_in, const int* in_sizes, int n_in,
                              void* d_out, int out_size, void* d_ws, size_t ws_size,
                              hipStream_t stream) {
  const float* inputs = (const float*)d_in[0];
  const float* pos_emb = (const float*)d_in[1];
  const float* K3 = (const float*)d_in[2];
  const float* qw = (const float*)d_in[3];
  const float* qb = (const float*)d_in[4];
  const float* kw = (const float*)d_in[5];
  const float* kb = (const float*)d_in[6];
  const float* vw = (const float*)d_in[7];
  const float* vb = (const float*)d_in[8];
  const float* tqW1 = (const float*)d_in[9];
  const float* tqb1 = (const float*)d_in[10];
  const float* tqW2 = (const float*)d_in[11];
  const float* tqb2 = (const float*)d_in[12];
  const float* tqW3 = (const float*)d_in[13];
  const float* tqb3 = (const float*)d_in[14];
  const float* Wlt = (const float*)d_in[15];
  const float* ln1g = (const float*)d_in[16];
  const float* ln1b = (const float*)d_in[17];
  const float* ln2g = (const float*)d_in[18];
  const float* ln2b = (const float*)d_in[19];
  const float* sclw = (const float*)d_in[20];
  const float* sclb = (const float*)d_in[21];
  const float* elW = (const float*)d_in[22];
  const float* elb = (const float*)d_in[23];
  const float* fW1 = (const float*)d_in[24];
  const float* fb1 = (const float*)d_in[25];
  const float* fW2 = (const float*)d_in[26];
  const float* fb2 = (const float*)d_in[27];
  float* out = (float*)d_out;
  float* ws_f = (float*)d_ws;

  const size_t TN = (size_t)TT * NN;
  const size_t HTN = (size_t)HH * TT * NN;
  const size_t W1T_ELEMS = (size_t)LL * HH * NN * TT;  // ushorts
  const size_t WLT_ELEMS = (size_t)LL * 64 * 512;      // ushorts

  ushort* k3sTh = (ushort*)ws_f;                      // LL*4096
  ushort* w1Th = k3sTh + (size_t)LL * 4096;           // W1T_ELEMS
  ushort* wth = w1Th + W1T_ELEMS;                     // WLT_ELEMS
  ushort* wtl = wth + WLT_ELEMS;                      // WLT_ELEMS
  ushort* w2Th = wtl + WLT_ELEMS;                     // LL*HH*4096
  ushort* elWTh = w2Th + (size_t)LL * HH * 4096;      // LL*4096
  size_t base_ush = (size_t)LL * 4096 + W1T_ELEMS + 2 * WLT_ELEMS +
                    (size_t)LL * HH * 4096 + (size_t)LL * 4096;
  const size_t base = (base_ush + 1) / 2;  // words

  for (int l = 0; l < LL; ++l)
    k_k3s<<<16, 256, 0, stream>>>(K3, sclw + l * KSS, k3sTh + (size_t)l * 4096);
  k_tsplit<<<LL * HH * 16, 256, 0, stream>>>(tqW1, w1Th);
  k_tsplitW<<<LL * 8, 256, 0, stream>>>(Wlt, wth, wtl);
  k_tsplitSq<<<LL * HH, 256, 0, stream>>>(tqW2, w2Th);
  k_tsplitSq<<<LL, 256, 0, stream>>>(elW, elWTh);

  // per-batch f32 words: x TN + xv HTN + auv HTN + lse HH*TT
  //  + ush: xqh/xkh/xvTh/hoh/hol = 5*HTN/2
  const size_t per_b = TN + 2 * HTN + (size_t)HH * TT + (5 * HTN) / 2;
  size_t avail = ws_size / sizeof(float);
  avail = (avail > base) ? avail - base : 0;
  int Bc = (int)(avail / per_b);
  if (Bc > BB) Bc = BB;
  if (Bc < 1) Bc = 1;

  for (int b0 = 0; b0 < BB; b0 += Bc) {
    int bc = (BB - b0 < Bc) ? (BB - b0) : Bc;
    float* x = ws_f + base;
    float* xv = x + (size_t)bc * TN;
    float* auv = xv + (size_t)bc * HTN;
    float* lseb = auv + (size_t)bc * HTN;
    ushort* xqh = (ushort*)(lseb + (size_t)bc * HH * TT);
    ushort* xkh = xqh + (size_t)bc * HTN;
    ushort* xvTh = xkh + (size_t)bc * HTN;
    ushort* hoh = xvTh + (size_t)bc * HTN;
    ushort* hol = hoh + (size_t)bc * HTN;

    int total = bc * (int)TN;
    k_addpos<<<(total + 255) / 256, 256, 0, stream>>>(inputs + (size_t)b0 * TN, pos_emb, x,
                                                      total);
    for (int l = 0; l < LL; ++l) {
      k_gconv<<<bc * TT / 4, 256, 0, stream>>>(x, K3, qw + l * HH * KSS, qb + l * HH,
                                               kw + l * HH * KSS, kb + l * HH,
                                               vw + l * HH * KSS, vb + l * HH,
                                               xqh, xkh, xv);
      k_tsplit<<<bc * HH * 16, 256, 0, stream>>>(xv, xvTh);
      k_attn<<<bc * HH * 16, 256, 0, stream>>>(xkh, xqh, xvTh, auv, lseb);
      k_h1g<<<bc * HH * 16, 256, 0, stream>>>(
          xkh, xqh, w1Th + (size_t)l * HH * NN * TT, lseb, tqb1 + l * HH * DD1,
          w2Th + (size_t)l * HH * 4096, tqb2 + l * HH * DD1,
          tqW3 + (size_t)l * HH * DD1 * 2, tqb3 + l * HH * 2, auv, xv, hoh, hol);
      k_mrgf<<<bc * 16, 256, 0, stream>>>(
          x, hoh, hol, wth + (size_t)l * 64 * 512, wtl + (size_t)l * 64 * 512,
          ln1g + l * NN, ln1b + l * NN, sclb + l, k3sTh + (size_t)l * 4096,
          elWTh + (size_t)l * 4096, elb + l * NN, ln2g + l * NN, ln2b + l * NN);
    }
    k_final<<<bc, 256, 0, stream>>>(x, fW1, fb1, fW2, fb2, out + b0);
  }
}

// Round 12
// 243.821 us; speedup vs baseline: 3.0663x; 1.0078x over previous
//
#include <hip/hip_runtime.h>

typedef __attribute__((ext_vector_type(8))) short short8;
typedef __attribute__((ext_vector_type(4))) float f32x4;

#define BB 8
#define TT 1024
#define NN 64
#define HH 8
#define LL 2
#define KSS 3
#define DD1 64
#define EPSV 1e-6f
#define LOG2E 1.4426950408889634f

#define MFMA16(a, b, c) __builtin_amdgcn_mfma_f32_16x16x32_bf16(a, b, c, 0, 0, 0)
#define BAR() __builtin_amdgcn_s_barrier()
#define WAIT_VM6() asm volatile("s_waitcnt vmcnt(6)" ::: "memory")
#define WAIT_VM2() asm volatile("s_waitcnt vmcnt(2)" ::: "memory")
#define WAIT_VM0() asm volatile("s_waitcnt vmcnt(0)" ::: "memory")
#define WAIT_LGKM0() asm volatile("s_waitcnt lgkmcnt(0)" ::: "memory")

__device__ __forceinline__ float exp2_(float x) { return __builtin_amdgcn_exp2f(x); }
__device__ __forceinline__ float log2_(float x) { return __builtin_amdgcn_logf(x); }

// ---- truncation-based hi/lo bf16 split ----
__device__ __forceinline__ void split1(float x, ushort& hi, ushort& lo) {
  uint u = __float_as_uint(x);
  hi = (ushort)(u >> 16);
  float hf = __uint_as_float(u & 0xffff0000u);
  lo = (ushort)(__float_as_uint(x - hf) >> 16);
}
__device__ __forceinline__ uint pack2(float a, float b, uint& lo) {
  uint ua = __float_as_uint(a), ub = __float_as_uint(b);
  float ra = __uint_as_float(ua & 0xffff0000u);
  float rb = __uint_as_float(ub & 0xffff0000u);
  lo = (__float_as_uint(a - ra) >> 16) | (__float_as_uint(b - rb) & 0xffff0000u);
  return (ua >> 16) | (ub & 0xffff0000u);
}
__device__ __forceinline__ uint pack2rhu(float a, float b) {
  uint ua = __float_as_uint(a) + 0x8000u;
  uint ub = __float_as_uint(b) + 0x8000u;
  return (ua >> 16) | (ub & 0xffff0000u);
}
__device__ __forceinline__ ushort f2bfr(float x) {
  union { float f; uint u; } v; v.f = x;
  uint r = (v.u + 0x7fffu + ((v.u >> 16) & 1u)) >> 16;
  return (ushort)r;
}
__device__ __forceinline__ float bf2f(ushort b) {
  union { uint u; float f; } v; v.u = ((uint)b) << 16; return v.f;
}

// ---- async global->LDS staging ----
__device__ __forceinline__ void gl2lds16(const ushort* g, ushort* l) {
  __builtin_amdgcn_global_load_lds(
      (const __attribute__((address_space(1))) void*)g,
      (__attribute__((address_space(3))) void*)l, 16, 0, 0);
}
// 64x64 tile, chunk swizzle c ^ (r&7); 2 gl_lds/wave
__device__ __forceinline__ void stage_async(ushort* __restrict__ s,
                                            const ushort* __restrict__ g,
                                            int stride, int tid) {
  int w = tid >> 6;
  int sub = (tid & 63) >> 3, c = tid & 7;
#pragma unroll
  for (int i = 0; i < 2; ++i) {
    int rb = (i * 4 + w) * 8;
    gl2lds16(g + (size_t)(rb + sub) * stride + ((c ^ sub) << 3), s + rb * 64);
  }
}
__device__ __forceinline__ short8 frag(const ushort* __restrict__ s, int row, int ch) {
  return *(const short8*)(s + row * 64 + ((ch ^ (row & 7)) << 3));
}
// 32x64 tile; 1 gl_lds/wave
__device__ __forceinline__ void stage_q32(ushort* __restrict__ s,
                                          const ushort* __restrict__ g, int tid) {
  int w = tid >> 6;
  int sub = (tid & 63) >> 3, c = tid & 7;
  int rb = w * 8, r = rb + sub;
  gl2lds16(g + (size_t)r * 64 + ((c ^ (r & 7)) << 3), s + rb * 64);
}
// 64x32 tile (stride 1024), chunk swizzle c ^ ((n>>1)&3); 1 gl_lds/wave
__device__ __forceinline__ void stage_v32(ushort* __restrict__ s,
                                          const ushort* __restrict__ g, int tid) {
  int w = tid >> 6;
  int noff = (tid & 63) >> 2, c = tid & 3;
  int nb = w * 16, n = nb + noff;
  gl2lds16(g + (size_t)n * 1024 + ((c ^ ((n >> 1) & 3)) << 3), s + nb * 32);
}
__device__ __forceinline__ short8 frag32(const ushort* __restrict__ s, int row, int g) {
  return *(const short8*)(s + row * 32 + ((g ^ ((row >> 1) & 3)) << 3));
}

// ---------- small kernels ----------

__global__ void k_addpos(const float* __restrict__ in, const float* __restrict__ pe,
                         float* __restrict__ x, int total) {
  int idx = blockIdx.x * 256 + threadIdx.x;
  if (idx < total) {
    int tn = idx & (TT * NN - 1);
    x[idx] = in[idx] + pe[tn];
  }
}

__global__ void k_k3s(const float* __restrict__ K3, const float* __restrict__ sclwl,
                      ushort* __restrict__ dh) {
  int idx = blockIdx.x * 256 + threadIdx.x;
  int n = idx >> 6, m = idx & 63;
  float v = K3[n * 192 + m] * sclwl[0] + K3[n * 192 + 64 + m] * sclwl[1] +
            K3[n * 192 + 128 + m] * sclwl[2];
  dh[m * 64 + n] = f2bfr(v);
}

__global__ __launch_bounds__(256) void k_tsplit(const float* __restrict__ src,
                                                ushort* __restrict__ dh) {
  __shared__ float st[64][65];
  int blk = blockIdx.x;
  int mat = blk >> 4, rt = blk & 15;
  int tid = threadIdx.x;
  size_t sbase = ((size_t)mat * TT + rt * 64) * 64;
#pragma unroll
  for (int i = 0; i < 4; ++i) {
    int idx = tid + i * 256;
    int r = idx >> 4, c4 = idx & 15;
    float4 v = *(const float4*)(src + sbase + r * 64 + c4 * 4);
    st[r][c4 * 4 + 0] = v.x; st[r][c4 * 4 + 1] = v.y;
    st[r][c4 * 4 + 2] = v.z; st[r][c4 * 4 + 3] = v.w;
  }
  __syncthreads();
  size_t obase = (size_t)mat * (64 * (size_t)TT) + rt * 64;
#pragma unroll
  for (int i = 0; i < 2; ++i) {
    int idx = tid + i * 256;
    int n = idx >> 3, c = idx & 7;
    uint hw[4];
#pragma unroll
    for (int j = 0; j < 4; ++j)
      hw[j] = (uint)f2bfr(st[c * 8 + 2 * j][n]) | ((uint)f2bfr(st[c * 8 + 2 * j + 1][n]) << 16);
    *(uint4*)(dh + obase + (size_t)n * TT + c * 8) = make_uint4(hw[0], hw[1], hw[2], hw[3]);
  }
}

__global__ __launch_bounds__(256) void k_tsplitW(const float* __restrict__ Wlt,
                                                 ushort* __restrict__ dh,
                                                 ushort* __restrict__ dl) {
  __shared__ float st[64][65];
  int blk = blockIdx.x;
  int l = blk >> 3, rt = blk & 7;
  int tid = threadIdx.x;
  size_t sbase = ((size_t)l * 512 + rt * 64) * 64;
#pragma unroll
  for (int i = 0; i < 4; ++i) {
    int idx = tid + i * 256;
    int r = idx >> 4, c4 = idx & 15;
    float4 v = *(const float4*)(Wlt + sbase + r * 64 + c4 * 4);
    st[r][c4 * 4 + 0] = v.x; st[r][c4 * 4 + 1] = v.y;
    st[r][c4 * 4 + 2] = v.z; st[r][c4 * 4 + 3] = v.w;
  }
  __syncthreads();
  size_t obase = (size_t)l * 64 * 512 + rt * 64;
#pragma unroll
  for (int i = 0; i < 2; ++i) {
    int idx = tid + i * 256;
    int n = idx >> 3, c = idx & 7;
    uint hw[4], lw[4];
#pragma unroll
    for (int j = 0; j < 4; ++j) hw[j] = pack2(st[c * 8 + 2 * j][n], st[c * 8 + 2 * j + 1][n], lw[j]);
    *(uint4*)(dh + obase + (size_t)n * 512 + c * 8) = make_uint4(hw[0], hw[1], hw[2], hw[3]);
    *(uint4*)(dl + obase + (size_t)n * 512 + c * 8) = make_uint4(lw[0], lw[1], lw[2], lw[3]);
  }
}

__global__ __launch_bounds__(256) void k_tsplitSq(const float* __restrict__ src,
                                                  ushort* __restrict__ dh) {
  __shared__ float st[64][65];
  int mat = blockIdx.x;
  int tid = threadIdx.x;
  size_t sbase = (size_t)mat * 4096;
#pragma unroll
  for (int i = 0; i < 4; ++i) {
    int idx = tid + i * 256;
    int r = idx >> 4, c4 = idx & 15;
    float4 v = *(const float4*)(src + sbase + r * 64 + c4 * 4);
    st[r][c4 * 4 + 0] = v.x; st[r][c4 * 4 + 1] = v.y;
    st[r][c4 * 4 + 2] = v.z; st[r][c4 * 4 + 3] = v.w;
  }
  __syncthreads();
#pragma unroll
  for (int i = 0; i < 2; ++i) {
    int idx = tid + i * 256;
    int d = idx >> 3, c = idx & 7;
    uint hw[4];
#pragma unroll
    for (int j = 0; j < 4; ++j)
      hw[j] = (uint)f2bfr(st[c * 8 + 2 * j][d]) | ((uint)f2bfr(st[c * 8 + 2 * j + 1][d]) << 16);
    *(uint4*)(dh + sbase + (size_t)d * 64 + c * 8) = make_uint4(hw[0], hw[1], hw[2], hw[3]);
  }
}

// gconv: 256-thr blocks, K3 staged in LDS, 4 (b,t) rows per block
__global__ __launch_bounds__(256) void k_gconv(
    const float* __restrict__ x, const float* __restrict__ K3,
    const float* __restrict__ qwl, const float* __restrict__ qbl,
    const float* __restrict__ kwl, const float* __restrict__ kbl,
    const float* __restrict__ vwl, const float* __restrict__ vbl,
    ushort* __restrict__ xqh, ushort* __restrict__ xkh, float* __restrict__ xv) {
  __shared__ float sK3[12288];
  __shared__ float sx[4][64];
  int tid = threadIdx.x;
  int w = tid >> 6, lane = tid & 63;
#pragma unroll
  for (int i = 0; i < 12; ++i)
    ((float4*)sK3)[tid + i * 256] = ((const float4*)K3)[tid + i * 256];
  size_t bt = (size_t)blockIdx.x * 4 + w;
  size_t b = bt >> 10, t = bt & 1023;
  float xm = x[bt * 64 + lane];
  sx[w][lane] = xm;
  __syncthreads();
  float a0 = 0.f, a1 = 0.f, a2 = 0.f;
#pragma unroll 8
  for (int n = 0; n < 64; ++n) {
    float xn = sx[w][n];
    a0 = fmaf(xn, sK3[n * 192 + lane], a0);
    a1 = fmaf(xn, sK3[n * 192 + 64 + lane], a1);
    a2 = fmaf(xn, sK3[n * 192 + 128 + lane], a2);
  }
#pragma unroll
  for (int hh = 0; hh < HH; ++hh) {
    size_t off = (((size_t)b * HH + hh) * TT + t) * 64 + lane;
    float q = fmaf(qwl[hh * 3 + 0], a0,
              fmaf(qwl[hh * 3 + 1], a1, fmaf(qwl[hh * 3 + 2], a2, qbl[hh] + xm)));
    q = fmaxf(q, 0.f) * (0.015625f * LOG2E);
    xqh[off] = f2bfr(q);
    float k = fmaf(kwl[hh * 3 + 0], a0,
              fmaf(kwl[hh * 3 + 1], a1, fmaf(kwl[hh * 3 + 2], a2, kbl[hh] + xm)));
    xkh[off] = f2bfr(fmaxf(k, 0.f));
    float v = fmaf(vwl[hh * 3 + 0], a0,
              fmaf(vwl[hh * 3 + 1], a1, fmaf(vwl[hh * 3 + 2], a2, vbl[hh] + xm)));
    xv[off] = fmaxf(v, 0.f);
  }
}

// ---------- pass A: flash attention, u-range split across 2 half-blocks ----------
// block -> (bh, t0-tile, half); writes RAW O partial + lsum partial
__global__ __launch_bounds__(256) void k_attn(
    const ushort* __restrict__ xkh, const ushort* __restrict__ xqh,
    const ushort* __restrict__ xvTh,
    float* __restrict__ auv0, float* __restrict__ auv1,
    float* __restrict__ ls0, float* __restrict__ ls1) {
  __shared__ ushort sQh[4096];  // 2 bufs x 32x64 (prologue: K 64x64 tile)
  __shared__ ushort sVh[4096];  // 2 bufs x 64x32
  __shared__ ushort sPh[2048];  // 64x32
  int tid = threadIdx.x;
  int lane = tid & 63, w = tid >> 6;
  int l15 = lane & 15, g = lane >> 4;
  int nb = gridDim.x, chunk = nb >> 3, bid = blockIdx.x;
  int blk = (bid & 7) * chunk + (bid >> 3);  // XCD swizzle (nb % 8 == 0)
  int bh = blk >> 5, t0 = ((blk >> 1) & 15) << 6, half = blk & 1;
  size_t bhTT = (size_t)bh * TT;
  size_t ubase = (size_t)(half << 9);
  int trow = 16 * w + l15, psw = (trow >> 1) & 3;

  stage_async(sQh, xkh + (bhTT + t0) * NN, 64, tid);
  WAIT_VM0();
  BAR();
  short8 fKh[2];
#pragma unroll
  for (int ks = 0; ks < 2; ++ks) fKh[ks] = frag(sQh, trow, g + 4 * ks);
  WAIT_LGKM0();
  BAR();
  stage_q32(sQh, xqh + (bhTT + ubase) * NN, tid);
  stage_v32(sVh, xvTh + bhTT * NN + ubase, tid);
  stage_q32(sQh + 2048, xqh + (bhTT + ubase + 32) * NN, tid);
  stage_v32(sVh + 2048, xvTh + bhTT * NN + ubase + 32, tid);

  float lsum = 0.f;
  f32x4 O[4];
#pragma unroll
  for (int ct = 0; ct < 4; ++ct)
#pragma unroll
    for (int r = 0; r < 4; ++r) O[ct][r] = 0.f;

  for (int ut = 0; ut < 16; ++ut) {
    int cur = ut & 1;
    if (ut < 15) WAIT_VM2(); else WAIT_VM0();
    BAR();
    const ushort* cQh = sQh + cur * 2048;
    const ushort* cVh = sVh + cur * 2048;

    __builtin_amdgcn_s_setprio(1);
    f32x4 S[2];
#pragma unroll
    for (int rt = 0; rt < 2; ++rt) {
      f32x4 a = {0.f, 0.f, 0.f, 0.f};
#pragma unroll
      for (int ks = 0; ks < 2; ++ks)
        a = MFMA16(frag(cQh, 16 * rt + l15, g + 4 * ks), fKh[ks], a);
      S[rt] = a;
    }
    __builtin_amdgcn_s_setprio(0);

    uint2 ph[2];
#pragma unroll
    for (int rt = 0; rt < 2; ++rt) {
      float p0 = exp2_(S[rt][0]), p1 = exp2_(S[rt][1]);
      float p2 = exp2_(S[rt][2]), p3 = exp2_(S[rt][3]);
      lsum += (p0 + p1) + (p2 + p3);
      ph[rt].x = pack2rhu(p0, p1);
      ph[rt].y = pack2rhu(p2, p3);
    }
#pragma unroll
    for (int rt = 0; rt < 2; ++rt) {
      int ch = 2 * rt + (g >> 1);
      int off = trow * 32 + ((ch ^ psw) << 3) + ((g & 1) << 2);
      *(uint2*)(sPh + off) = ph[rt];
    }
    WAIT_LGKM0();
    __builtin_amdgcn_sched_barrier(0);
    __builtin_amdgcn_s_setprio(1);
    {
      short8 aPh = frag32(sPh, trow, g);
#pragma unroll
      for (int ct = 0; ct < 4; ++ct)
        O[ct] = MFMA16(aPh, frag32(cVh, 16 * ct + l15, g), O[ct]);
    }
    __builtin_amdgcn_s_setprio(0);
    WAIT_LGKM0();
    BAR();
    if (ut < 14) {
      int tn = ut + 2;
      stage_q32(sQh + cur * 2048, xqh + (bhTT + ubase + tn * 32) * NN, tid);
      stage_v32(sVh + cur * 2048, xvTh + bhTT * NN + ubase + tn * 32, tid);
    }
  }
  lsum += __shfl_xor(lsum, 16, 64);
  lsum += __shfl_xor(lsum, 32, 64);
  float* A = half ? auv1 : auv0;
  float* L = half ? ls1 : ls0;
#pragma unroll
  for (int r = 0; r < 4; ++r) {
    size_t row = (bhTT + t0 + 16 * w + 4 * g + r) * NN;
#pragma unroll
    for (int ct = 0; ct < 4; ++ct) A[row + 16 * ct + l15] = O[ct][r];
  }
  if (g == 0) L[bhTT + t0 + trow] = lsum;
}

// ---------- pass B fused with gate; normalization folded in ----------
__global__ __launch_bounds__(256, 4) void k_h1g(
    const ushort* __restrict__ xkh, const ushort* __restrict__ xqh,
    const ushort* __restrict__ w1Th,
    const float* __restrict__ ls0, const float* __restrict__ ls1,
    const float* __restrict__ b1, const ushort* __restrict__ w2Th,
    const float* __restrict__ b2l, const float* __restrict__ W3l,
    const float* __restrict__ b3l,
    const float* __restrict__ auv0, const float* __restrict__ auv1,
    const float* __restrict__ xv, ushort* __restrict__ hoh,
    ushort* __restrict__ hol) {
  __shared__ ushort sKh[4096];  // 2 bufs x 32x64 (prologue: Q hi tile)
  __shared__ ushort sWh[4096];  // 2 bufs x 64x32 -> epilogue: h1 64x64
  __shared__ ushort sPh[2048];
  __shared__ ushort sW2[4096];  // W2^T 64x64, persistent
  __shared__ float sL[1024];    // lse table -> epilogue scratch
  __shared__ float sIl[1024];   // 1/lsum table
  int tid = threadIdx.x;
  int lane = tid & 63, w = tid >> 6;
  int l15 = lane & 15, g = lane >> 4;
  int nb = gridDim.x, chunk = nb >> 3, bid = blockIdx.x;
  int blk = (bid & 7) * chunk + (bid >> 3);
  int bh = blk >> 4, h = bh & (HH - 1), a0 = (blk & 15) << 6;
  size_t bhTT = (size_t)bh * TT;
  size_t wbase = (size_t)h * NN * TT;
  int arow = 16 * w + l15, psw = (arow >> 1) & 3;

  stage_async(sKh, xqh + (bhTT + a0) * NN, 64, tid);
  stage_async(sW2, w2Th + (size_t)h * 4096, 64, tid);
  WAIT_VM0();
  BAR();
  short8 fQh[2];
#pragma unroll
  for (int ks = 0; ks < 2; ++ks) fQh[ks] = frag(sKh, arow, g + 4 * ks);
#pragma unroll
  for (int i = 0; i < 4; ++i) {
    int idx = tid + i * 256;
    float l = ls0[bhTT + idx] + ls1[bhTT + idx];
    sL[idx] = log2_(l);
    sIl[idx] = 1.0f / l;
  }
  WAIT_LGKM0();
  BAR();
  stage_q32(sKh, xkh + bhTT * NN, tid);
  stage_v32(sWh, w1Th + wbase, tid);
  stage_q32(sKh + 2048, xkh + (bhTT + 32) * NN, tid);
  stage_v32(sWh + 2048, w1Th + wbase + 32, tid);

  f32x4 acc[4];
#pragma unroll
  for (int ct = 0; ct < 4; ++ct)
#pragma unroll
    for (int r = 0; r < 4; ++r) acc[ct][r] = 0.f;

  for (int tt = 0; tt < 32; ++tt) {
    int cur = tt & 1;
    if (tt < 31) WAIT_VM2(); else WAIT_VM0();
    BAR();
    const ushort* cKh = sKh + cur * 2048;
    const ushort* cWh = sWh + cur * 2048;

    __builtin_amdgcn_s_setprio(1);
    f32x4 S[2];
#pragma unroll
    for (int rt = 0; rt < 2; ++rt) {
      f32x4 a = {0.f, 0.f, 0.f, 0.f};
#pragma unroll
      for (int ks = 0; ks < 2; ++ks)
        a = MFMA16(frag(cKh, 16 * rt + l15, g + 4 * ks), fQh[ks], a);
      S[rt] = a;
    }
    __builtin_amdgcn_s_setprio(0);

    uint2 ph[2];
#pragma unroll
    for (int rt = 0; rt < 2; ++rt) {
      f32x4 lv = *(const f32x4*)(sL + tt * 32 + 16 * rt + 4 * g);
      float p0 = exp2_(S[rt][0] - lv[0]);
      float p1 = exp2_(S[rt][1] - lv[1]);
      float p2 = exp2_(S[rt][2] - lv[2]);
      float p3 = exp2_(S[rt][3] - lv[3]);
      ph[rt].x = pack2rhu(p0, p1);
      ph[rt].y = pack2rhu(p2, p3);
    }
#pragma unroll
    for (int rt = 0; rt < 2; ++rt) {
      int ch = 2 * rt + (g >> 1);
      int off = arow * 32 + ((ch ^ psw) << 3) + ((g & 1) << 2);
      *(uint2*)(sPh + off) = ph[rt];
    }
    WAIT_LGKM0();
    __builtin_amdgcn_sched_barrier(0);
    __builtin_amdgcn_s_setprio(1);
    {
      short8 aPh = frag32(sPh, arow, g);
#pragma unroll
      for (int ct = 0; ct < 4; ++ct)
        acc[ct] = MFMA16(aPh, frag32(cWh, 16 * ct + l15, g), acc[ct]);
    }
    __builtin_amdgcn_s_setprio(0);
    WAIT_LGKM0();
    BAR();
    if (tt < 30) {
      int tn = tt + 2;
      stage_q32(sKh + cur * 2048, xkh + (bhTT + tn * 32) * NN, tid);
      stage_v32(sWh + cur * 2048, w1Th + wbase + tn * 32, tid);
    }
  }
  // ---- epilogue: gate fused ----
#pragma unroll
  for (int ct = 0; ct < 4; ++ct) {
    float bb = b1[h * 64 + 16 * ct + l15];
    int cch = 2 * ct + (l15 >> 3), cin = l15 & 7;
#pragma unroll
    for (int r = 0; r < 4; ++r) {
      int row = 16 * w + 4 * g + r;
      float hv = fmaxf(acc[ct][r] + bb, 0.f);
      sWh[row * 64 + ((cch ^ (row & 7)) << 3) + cin] = f2bfr(hv);
    }
  }
  WAIT_LGKM0();
  BAR();
  f32x4 acc2[4];
#pragma unroll
  for (int rt = 0; rt < 4; ++rt)
#pragma unroll
    for (int r = 0; r < 4; ++r) acc2[rt][r] = 0.f;
#pragma unroll
  for (int ks = 0; ks < 2; ++ks) {
    short8 bB = frag(sW2, 16 * w + l15, g + 4 * ks);
#pragma unroll
    for (int rt = 0; rt < 4; ++rt)
      acc2[rt] = MFMA16(frag(sWh, 16 * rt + l15, g + 4 * ks), bB, acc2[rt]);
  }
  int col = 16 * w + l15;
  float b2c = b2l[h * 64 + col];
  float w30 = W3l[h * 128 + col * 2 + 0];
  float w31 = W3l[h * 128 + col * 2 + 1];
  float* sredf = sL;        // reuse (P loop done)
  float* sgf = sL + 512;
#pragma unroll
  for (int rt = 0; rt < 4; ++rt)
#pragma unroll
    for (int r = 0; r < 4; ++r) {
      float v = fmaxf(acc2[rt][r] + b2c, 0.f);
      float z0 = v * w30, z1 = v * w31;
#pragma unroll
      for (int mm = 1; mm < 16; mm <<= 1) {
        z0 += __shfl_xor(z0, mm, 64);
        z1 += __shfl_xor(z1, mm, 64);
      }
      if (l15 == 0) {
        int row = 16 * rt + 4 * g + r;
        sredf[row * 4 + w] = z0;
        sredf[256 + row * 4 + w] = z1;
      }
    }
  __syncthreads();
  if (tid < 64) {
    float z0 = sredf[tid * 4] + sredf[tid * 4 + 1] + sredf[tid * 4 + 2] +
               sredf[tid * 4 + 3] + b3l[h * 2 + 0];
    float z1 = sredf[256 + tid * 4] + sredf[256 + tid * 4 + 1] +
               sredf[256 + tid * 4 + 2] + sredf[256 + tid * 4 + 3] + b3l[h * 2 + 1];
    float g0 = 1.0f / (1.0f + __expf(z1 - z0));
    sgf[tid * 2] = g0 * sIl[a0 + tid];  // fold 1/lsum into g0
    sgf[tid * 2 + 1] = 1.0f - g0;
  }
  __syncthreads();
#pragma unroll
  for (int rr = 0; rr < 16; ++rr) {
    int row = 16 * w + rr;
    size_t off = (bhTT + a0 + row) * 64 + lane;
    float o = auv0[off] + auv1[off];
    float ho = sgf[row * 2] * o + sgf[row * 2 + 1] * xv[off];
    ushort hb, lb;
    split1(ho, hb, lb);
    hoh[off] = hb;
    hol[off] = lb;
  }
}

// ---------- merge fused with ffn; 32-row t-tiles (grid = bc*32) ----------
__global__ __launch_bounds__(256, 2) void k_mrgf(
    float* __restrict__ x, const ushort* __restrict__ hoh,
    const ushort* __restrict__ hol, const ushort* __restrict__ wth,
    const ushort* __restrict__ wtl, const float* __restrict__ g1l,
    const float* __restrict__ b1l, const float* __restrict__ sclb_l,
    const ushort* __restrict__ k3sTh, const ushort* __restrict__ elWTh,
    const float* __restrict__ elbl, const float* __restrict__ g2l,
    const float* __restrict__ b2l) {
  __shared__ ushort sAh[2][2048], sAl[2][2048], sBh[2][4096], sBl[2][4096];
  __shared__ float sred[2][32][4];
  __shared__ float sfin[32][2];
  int tid = threadIdx.x;
  int lane = tid & 63, w = tid >> 6;
  int l15 = lane & 15, g = lane >> 4;
  int blk = blockIdx.x;
  int b = blk >> 5, t0 = (blk & 31) << 5;

  {
    size_t ab0 = (((size_t)b * HH + 0) * TT + t0) * NN;
    size_t ab1 = (((size_t)b * HH + 1) * TT + t0) * NN;
    stage_q32(sAh[0], hoh + ab0, tid);
    stage_q32(sAl[0], hol + ab0, tid);
    stage_async(sBh[0], wth, 512, tid);
    stage_async(sBl[0], wtl, 512, tid);
    stage_q32(sAh[1], hoh + ab1, tid);
    stage_q32(sAl[1], hol + ab1, tid);
    stage_async(sBh[1], wth + 64, 512, tid);
    stage_async(sBl[1], wtl + 64, 512, tid);
  }

  f32x4 acc[2];
#pragma unroll
  for (int rt = 0; rt < 2; ++rt)
#pragma unroll
    for (int r = 0; r < 4; ++r) acc[rt][r] = 0.f;

  for (int h = 0; h < 8; ++h) {
    int cur = h & 1;
    if (h < 7) WAIT_VM6(); else WAIT_VM0();
    BAR();
    __builtin_amdgcn_s_setprio(1);
#pragma unroll
    for (int ks = 0; ks < 2; ++ks) {
      short8 bBh = frag(sBh[cur], 16 * w + l15, g + 4 * ks);
      short8 bBl = frag(sBl[cur], 16 * w + l15, g + 4 * ks);
#pragma unroll
      for (int rt = 0; rt < 2; ++rt) {
        short8 aAh = frag(sAh[cur], 16 * rt + l15, g + 4 * ks);
        short8 aAl = frag(sAl[cur], 16 * rt + l15, g + 4 * ks);
        acc[rt] = MFMA16(aAh, bBh, acc[rt]);
        acc[rt] = MFMA16(aAh, bBl, acc[rt]);
        acc[rt] = MFMA16(aAl, bBh, acc[rt]);
      }
    }
    __builtin_amdgcn_s_setprio(0);
    WAIT_LGKM0();
    BAR();
    if (h < 6) {
      int hn = h + 2;
      size_t ab = (((size_t)b * HH + hn) * TT + t0) * NN;
      stage_q32(sAh[cur], hoh + ab, tid);
      stage_q32(sAl[cur], hol + ab, tid);
      stage_async(sBh[cur], wth + hn * 64, 512, tid);
      stage_async(sBl[cur], wtl + hn * 64, 512, tid);
    }
  }
  // ---- epilogue: out1 = LN1(x + acc), ffn, x = LN2 ----
  stage_async(sBh[0], k3sTh, 64, tid);
  stage_async(sBl[0], elWTh, 64, tid);
  int mcol = 16 * w + l15;
  float vv[2][4];
#pragma unroll
  for (int rt = 0; rt < 2; ++rt)
#pragma unroll
    for (int r = 0; r < 4; ++r) {
      int row = 16 * rt + 4 * g + r;
      vv[rt][r] = acc[rt][r] + x[((size_t)b * TT + t0 + row) * 64 + mcol];
    }
#pragma unroll
  for (int rt = 0; rt < 2; ++rt)
#pragma unroll
    for (int r = 0; r < 4; ++r) {
      float s1 = vv[rt][r], s2 = vv[rt][r] * vv[rt][r];
#pragma unroll
      for (int mm = 1; mm < 16; mm <<= 1) {
        s1 += __shfl_xor(s1, mm, 64);
        s2 += __shfl_xor(s2, mm, 64);
      }
      if (l15 == 0) {
        int row = 16 * rt + 4 * g + r;
        sred[0][row][w] = s1;
        sred[1][row][w] = s2;
      }
    }
  __syncthreads();
  if (tid < 32) {
    float a1 = sred[0][tid][0] + sred[0][tid][1] + sred[0][tid][2] + sred[0][tid][3];
    float a2 = sred[1][tid][0] + sred[1][tid][1] + sred[1][tid][2] + sred[1][tid][3];
    float mean = a1 * (1.0f / 64.0f);
    float var = a2 * (1.0f / 64.0f) - mean * mean;
    sfin[tid][0] = mean;
    sfin[tid][1] = rsqrtf(var + EPSV);
  }
  __syncthreads();
  float gg = g1l[mcol], bb1 = b1l[mcol];
  float val[2][4];
  ushort* sH = sAh[0];
  ushort* sHl = sAl[0];
  int cch = mcol >> 3, cin = mcol & 7;
#pragma unroll
  for (int rt = 0; rt < 2; ++rt)
#pragma unroll
    for (int r = 0; r < 4; ++r) {
      int row = 16 * rt + 4 * g + r;
      float v = (vv[rt][r] - sfin[row][0]) * sfin[row][1] * gg + bb1;
      val[rt][r] = v;
      ushort hb, lb;
      split1(v, hb, lb);
      int a = row * 64 + ((cch ^ (row & 7)) << 3) + cin;
      sH[a] = hb;
      sHl[a] = lb;
    }
  WAIT_VM0();
  WAIT_LGKM0();
  BAR();
  f32x4 acc3[2];
#pragma unroll
  for (int rt = 0; rt < 2; ++rt)
#pragma unroll
    for (int r = 0; r < 4; ++r) acc3[rt][r] = 0.f;
#pragma unroll
  for (int ks = 0; ks < 2; ++ks) {
    short8 bB = frag(sBh[0], mcol, g + 4 * ks);
#pragma unroll
    for (int rt = 0; rt < 2; ++rt) {
      acc3[rt] = MFMA16(frag(sH, 16 * rt + l15, g + 4 * ks), bB, acc3[rt]);
      acc3[rt] = MFMA16(frag(sHl, 16 * rt + l15, g + 4 * ks), bB, acc3[rt]);
    }
  }
  WAIT_LGKM0();
  BAR();
  float sclb = sclb_l[0];
#pragma unroll
  for (int rt = 0; rt < 2; ++rt)
#pragma unroll
    for (int r = 0; r < 4; ++r) {
      int row = 16 * rt + 4 * g + r;
      float f1 = fmaxf(acc3[rt][r] + sclb + val[rt][r], 0.f);
      ushort hb, lb;
      split1(f1, hb, lb);
      int a = row * 64 + ((cch ^ (row & 7)) << 3) + cin;
      sH[a] = hb;
      sHl[a] = lb;
    }
  WAIT_LGKM0();
  BAR();
  f32x4 acc4[2];
#pragma unroll
  for (int rt = 0; rt < 2; ++rt)
#pragma unroll
    for (int r = 0; r < 4; ++r) acc4[rt][r] = 0.f;
#pragma unroll
  for (int ks = 0; ks < 2; ++ks) {
    short8 bB = frag(sBl[0], mcol, g + 4 * ks);
#pragma unroll
    for (int rt = 0; rt < 2; ++rt) {
      acc4[rt] = MFMA16(frag(sH, 16 * rt + l15, g + 4 * ks), bB, acc4[rt]);
      acc4[rt] = MFMA16(frag(sHl, 16 * rt + l15, g + 4 * ks), bB, acc4[rt]);
    }
  }
  float elb = elbl[mcol];
#pragma unroll
  for (int rt = 0; rt < 2; ++rt)
#pragma unroll
    for (int r = 0; r < 4; ++r) {
      float v = val[rt][r] + acc4[rt][r] + elb;
      vv[rt][r] = v;
      float s1 = v, s2 = v * v;
#pragma unroll
      for (int mm = 1; mm < 16; mm <<= 1) {
        s1 += __shfl_xor(s1, mm, 64);
        s2 += __shfl_xor(s2, mm, 64);
      }
      if (l15 == 0) {
        int row = 16 * rt + 4 * g + r;
        sred[0][row][w] = s1;
        sred[1][row][w] = s2;
      }
    }
  __syncthreads();
  if (tid < 32) {
    float a1 = sred[0][tid][0] + sred[0][tid][1] + sred[0][tid][2] + sred[0][tid][3];
    float a2 = sred[1][tid][0] + sred[1][tid][1] + sred[1][tid][2] + sred[1][tid][3];
    float mean = a1 * (1.0f / 64.0f);
    float var = a2 * (1.0f / 64.0f) - mean * mean;
    sfin[tid][0] = mean;
    sfin[tid][1] = rsqrtf(var + EPSV);
  }
  __syncthreads();
  float g2 = g2l[mcol], bb2 = b2l[mcol];
#pragma unroll
  for (int rt = 0; rt < 2; ++rt)
#pragma unroll
    for (int r = 0; r < 4; ++r) {
      int row = 16 * rt + 4 * g + r;
      x[((size_t)b * TT + t0 + row) * 64 + mcol] =
          (vv[rt][r] - sfin[row][0]) * sfin[row][1] * g2 + bb2;
    }
}

__global__ __launch_bounds__(256) void k_final(
    const float* __restrict__ x, const float* __restrict__ fW1,
    const float* __restrict__ fb1, const float* __restrict__ fW2,
    const float* __restrict__ fb2, float* __restrict__ out) {
  __shared__ float pl[4][64];
  int tid = threadIdx.x;
  int lane = tid & 63, w = tid >> 6;
  size_t b = blockIdx.x;
  float s = 0.f;
  for (int t = 256 * w; t < 256 * w + 256; ++t) s += x[(b * TT + t) * 64 + lane];
  pl[w][lane] = s;
  __syncthreads();
  if (tid < 64) pl[0][tid] = (pl[0][tid] + pl[1][tid] + pl[2][tid] + pl[3][tid]) * (1.0f / TT);
  __syncthreads();
  if (tid < 64) {
    float hv = 0.f;
    if (lane < 32) {
      hv = fb1[lane];
#pragma unroll 8
      for (int n = 0; n < 64; ++n) hv = fmaf(pl[0][n], fW1[n * 32 + lane], hv);
      hv = fmaxf(hv, 0.f) * fW2[lane];
    }
#pragma unroll
    for (int m = 1; m < 64; m <<= 1) hv += __shfl_xor(hv, m, 64);
    if (lane == 0) out[b] = hv + fb2[0];
  }
}

extern "C" void kernel_launch(void* const* d_in, const int* in_sizes, int n_in,
                              void* d_out, int out_size, void* d_ws, size_t ws_size,
                              hipStream_t stream) {
  const float* inputs = (const float*)d_in[0];
  const float* pos_emb = (const float*)d_in[1];
  const float* K3 = (const float*)d_in[2];
  const float* qw = (const float*)d_in[3];
  const float* qb = (const float*)d_in[4];
  const float* kw = (const float*)d_in[5];
  const float* kb = (const float*)d_in[6];
  const float* vw = (const float*)d_in[7];
  const float* vb = (const float*)d_in[8];
  const float* tqW1 = (const float*)d_in[9];
  const float* tqb1 = (const float*)d_in[10];
  const float* tqW2 = (const float*)d_in[11];
  const float* tqb2 = (const float*)d_in[12];
  const float* tqW3 = (const float*)d_in[13];
  const float* tqb3 = (const float*)d_in[14];
  const float* Wlt = (const float*)d_in[15];
  const float* ln1g = (const float*)d_in[16];
  const float* ln1b = (const float*)d_in[17];
  const float* ln2g = (const float*)d_in[18];
  const float* ln2b = (const float*)d_in[19];
  const float* sclw = (const float*)d_in[20];
  const float* sclb = (const float*)d_in[21];
  const float* elW = (const float*)d_in[22];
  const float* elb = (const float*)d_in[23];
  const float* fW1 = (const float*)d_in[24];
  const float* fb1 = (const float*)d_in[25];
  const float* fW2 = (const float*)d_in[26];
  const float* fb2 = (const float*)d_in[27];
  float* out = (float*)d_out;
  float* ws_f = (float*)d_ws;

  const size_t TN = (size_t)TT * NN;
  const size_t HTN = (size_t)HH * TT * NN;
  const size_t W1T_ELEMS = (size_t)LL * HH * NN * TT;  // ushorts
  const size_t WLT_ELEMS = (size_t)LL * 64 * 512;      // ushorts

  ushort* k3sTh = (ushort*)ws_f;
  ushort* w1Th = k3sTh + (size_t)LL * 4096;
  ushort* wth = w1Th + W1T_ELEMS;
  ushort* wtl = wth + WLT_ELEMS;
  ushort* w2Th = wtl + WLT_ELEMS;
  ushort* elWTh = w2Th + (size_t)LL * HH * 4096;
  size_t base_ush = (size_t)LL * 4096 + W1T_ELEMS + 2 * WLT_ELEMS +
                    (size_t)LL * HH * 4096 + (size_t)LL * 4096;
  const size_t base = (base_ush + 1) / 2;

  for (int l = 0; l < LL; ++l)
    k_k3s<<<16, 256, 0, stream>>>(K3, sclw + l * KSS, k3sTh + (size_t)l * 4096);
  k_tsplit<<<LL * HH * 16, 256, 0, stream>>>(tqW1, w1Th);
  k_tsplitW<<<LL * 8, 256, 0, stream>>>(Wlt, wth, wtl);
  k_tsplitSq<<<LL * HH, 256, 0, stream>>>(tqW2, w2Th);
  k_tsplitSq<<<LL, 256, 0, stream>>>(elW, elWTh);

  // per-batch f32 words: x TN + xv HTN + auv0 HTN + auv1 HTN + ls0/ls1 2*HH*TT
  //  + ush: xqh/xkh/xvTh/hoh/hol = 5*HTN/2
  const size_t per_b = TN + 3 * HTN + 2 * (size_t)HH * TT + (5 * HTN) / 2;
  size_t avail = ws_size / sizeof(float);
  avail = (avail > base) ? avail - base : 0;
  int Bc = (int)(avail / per_b);
  if (Bc > BB) Bc = BB;
  if (Bc < 1) Bc = 1;

  for (int b0 = 0; b0 < BB; b0 += Bc) {
    int bc = (BB - b0 < Bc) ? (BB - b0) : Bc;
    float* x = ws_f + base;
    float* xv = x + (size_t)bc * TN;
    float* auv0 = xv + (size_t)bc * HTN;
    float* auv1 = auv0 + (size_t)bc * HTN;
    float* ls0 = auv1 + (size_t)bc * HTN;
    float* ls1 = ls0 + (size_t)bc * HH * TT;
    ushort* xqh = (ushort*)(ls1 + (size_t)bc * HH * TT);
    ushort* xkh = xqh + (size_t)bc * HTN;
    ushort* xvTh = xkh + (size_t)bc * HTN;
    ushort* hoh = xvTh + (size_t)bc * HTN;
    ushort* hol = hoh + (size_t)bc * HTN;

    int total = bc * (int)TN;
    k_addpos<<<(total + 255) / 256, 256, 0, stream>>>(inputs + (size_t)b0 * TN, pos_emb, x,
                                                      total);
    for (int l = 0; l < LL; ++l) {
      k_gconv<<<bc * TT / 4, 256, 0, stream>>>(x, K3, qw + l * HH * KSS, qb + l * HH,
                                               kw + l * HH * KSS, kb + l * HH,
                                               vw + l * HH * KSS, vb + l * HH,
                                               xqh, xkh, xv);
      k_tsplit<<<bc * HH * 16, 256, 0, stream>>>(xv, xvTh);
      k_attn<<<bc * HH * 32, 256, 0, stream>>>(xkh, xqh, xvTh, auv0, auv1, ls0, ls1);
      k_h1g<<<bc * HH * 16, 256, 0, stream>>>(
          xkh, xqh, w1Th + (size_t)l * HH * NN * TT, ls0, ls1,
          tqb1 + l * HH * DD1, w2Th + (size_t)l * HH * 4096, tqb2 + l * HH * DD1,
          tqW3 + (size_t)l * HH * DD1 * 2, tqb3 + l * HH * 2, auv0, auv1, xv,
          hoh, hol);
      k_mrgf<<<bc * 32, 256, 0, stream>>>(
          x, hoh, hol, wth + (size_t)l * 64 * 512, wtl + (size_t)l * 64 * 512,
          ln1g + l * NN, ln1b + l * NN, sclb + l, k3sTh + (size_t)l * 4096,
          elWTh + (size_t)l * 4096, elb + l * NN, ln2g + l * NN, ln2b + l * NN);
    }
    k_final<<<bc, 256, 0, stream>>>(x, fW1, fb1, fW2, fb2, out + b0);
  }
}

// Round 13
// 227.517 us; speedup vs baseline: 3.2860x; 1.0717x over previous
//
#include <hip/hip_runtime.h>

typedef __attribute__((ext_vector_type(8))) short short8;
typedef __attribute__((ext_vector_type(4))) float f32x4;

#define BB 8
#define TT 1024
#define NN 64
#define HH 8
#define LL 2
#define KSS 3
#define DD1 64
#define EPSV 1e-6f
#define LOG2E 1.4426950408889634f

#define MFMA16(a, b, c) __builtin_amdgcn_mfma_f32_16x16x32_bf16(a, b, c, 0, 0, 0)
#define BAR() __builtin_amdgcn_s_barrier()
#define WAIT_VM5() asm volatile("s_waitcnt vmcnt(5)" ::: "memory")
#define WAIT_VM2() asm volatile("s_waitcnt vmcnt(2)" ::: "memory")
#define WAIT_VM0() asm volatile("s_waitcnt vmcnt(0)" ::: "memory")
#define WAIT_LGKM0() asm volatile("s_waitcnt lgkmcnt(0)" ::: "memory")

__device__ __forceinline__ float exp2_(float x) { return __builtin_amdgcn_exp2f(x); }
__device__ __forceinline__ float log2_(float x) { return __builtin_amdgcn_logf(x); }

// ---- truncation-based hi/lo bf16 split ----
__device__ __forceinline__ void split1(float x, ushort& hi, ushort& lo) {
  uint u = __float_as_uint(x);
  hi = (ushort)(u >> 16);
  float hf = __uint_as_float(u & 0xffff0000u);
  lo = (ushort)(__float_as_uint(x - hf) >> 16);
}
__device__ __forceinline__ uint pack2(float a, float b, uint& lo) {
  uint ua = __float_as_uint(a), ub = __float_as_uint(b);
  float ra = __uint_as_float(ua & 0xffff0000u);
  float rb = __uint_as_float(ub & 0xffff0000u);
  lo = (__float_as_uint(a - ra) >> 16) | (__float_as_uint(b - rb) & 0xffff0000u);
  return (ua >> 16) | (ub & 0xffff0000u);
}
__device__ __forceinline__ uint pack2rhu(float a, float b) {
  uint ua = __float_as_uint(a) + 0x8000u;
  uint ub = __float_as_uint(b) + 0x8000u;
  return (ua >> 16) | (ub & 0xffff0000u);
}
__device__ __forceinline__ ushort f2bfr(float x) {
  union { float f; uint u; } v; v.f = x;
  uint r = (v.u + 0x7fffu + ((v.u >> 16) & 1u)) >> 16;
  return (ushort)r;
}
__device__ __forceinline__ float bf2f(ushort b) {
  union { uint u; float f; } v; v.u = ((uint)b) << 16; return v.f;
}

// ---- async global->LDS staging ----
__device__ __forceinline__ void gl2lds16(const ushort* g, ushort* l) {
  __builtin_amdgcn_global_load_lds(
      (const __attribute__((address_space(1))) void*)g,
      (__attribute__((address_space(3))) void*)l, 16, 0, 0);
}
// 64x64 tile, chunk swizzle c ^ (r&7); 2 gl_lds/wave
__device__ __forceinline__ void stage_async(ushort* __restrict__ s,
                                            const ushort* __restrict__ g,
                                            int stride, int tid) {
  int w = tid >> 6;
  int sub = (tid & 63) >> 3, c = tid & 7;
#pragma unroll
  for (int i = 0; i < 2; ++i) {
    int rb = (i * 4 + w) * 8;
    gl2lds16(g + (size_t)(rb + sub) * stride + ((c ^ sub) << 3), s + rb * 64);
  }
}
__device__ __forceinline__ short8 frag(const ushort* __restrict__ s, int row, int ch) {
  return *(const short8*)(s + row * 64 + ((ch ^ (row & 7)) << 3));
}
// 32x64 tile; 1 gl_lds/wave
__device__ __forceinline__ void stage_q32(ushort* __restrict__ s,
                                          const ushort* __restrict__ g, int tid) {
  int w = tid >> 6;
  int sub = (tid & 63) >> 3, c = tid & 7;
  int rb = w * 8, r = rb + sub;
  gl2lds16(g + (size_t)r * 64 + ((c ^ (r & 7)) << 3), s + rb * 64);
}
// 16x64 bf16 A-tile pair: waves 0-1 -> sh (gh), waves 2-3 -> sl (gl); 1 gl_lds/wave
__device__ __forceinline__ void stage_a16pair(ushort* __restrict__ sh,
                                              ushort* __restrict__ sl,
                                              const ushort* __restrict__ gh,
                                              const ushort* __restrict__ gl,
                                              int tid) {
  int w = tid >> 6, sub = (tid & 63) >> 3, c = tid & 7;
  const ushort* g = (w & 2) ? gl : gh;
  ushort* s = (w & 2) ? sl : sh;
  int rb = (w & 1) * 8;
  int r = rb + sub;
  gl2lds16(g + (size_t)r * 64 + ((c ^ (r & 7)) << 3), s + rb * 64);
}
// 64x32 tile (stride 1024), chunk swizzle c ^ ((n>>1)&3); 1 gl_lds/wave
__device__ __forceinline__ void stage_v32(ushort* __restrict__ s,
                                          const ushort* __restrict__ g, int tid) {
  int w = tid >> 6;
  int noff = (tid & 63) >> 2, c = tid & 3;
  int nb = w * 16, n = nb + noff;
  gl2lds16(g + (size_t)n * 1024 + ((c ^ ((n >> 1) & 3)) << 3), s + nb * 32);
}
__device__ __forceinline__ short8 frag32(const ushort* __restrict__ s, int row, int g) {
  return *(const short8*)(s + row * 32 + ((g ^ ((row >> 1) & 3)) << 3));
}

// ---------- small kernels ----------

__global__ void k_addpos(const float* __restrict__ in, const float* __restrict__ pe,
                         float* __restrict__ x, int total) {
  int idx = blockIdx.x * 256 + threadIdx.x;
  if (idx < total) {
    int tn = idx & (TT * NN - 1);
    x[idx] = in[idx] + pe[tn];
  }
}

__global__ void k_k3s(const float* __restrict__ K3, const float* __restrict__ sclwl,
                      ushort* __restrict__ dh) {
  int idx = blockIdx.x * 256 + threadIdx.x;
  int n = idx >> 6, m = idx & 63;
  float v = K3[n * 192 + m] * sclwl[0] + K3[n * 192 + 64 + m] * sclwl[1] +
            K3[n * 192 + 128 + m] * sclwl[2];
  dh[m * 64 + n] = f2bfr(v);
}

// transpose, hi-only RNE: src [mat][1024][64] f32 -> dh [mat][64][1024] bf16
__global__ __launch_bounds__(256) void k_tsplit(const float* __restrict__ src,
                                                ushort* __restrict__ dh) {
  __shared__ float st[64][65];
  int blk = blockIdx.x;
  int mat = blk >> 4, rt = blk & 15;
  int tid = threadIdx.x;
  size_t sbase = ((size_t)mat * TT + rt * 64) * 64;
#pragma unroll
  for (int i = 0; i < 4; ++i) {
    int idx = tid + i * 256;
    int r = idx >> 4, c4 = idx & 15;
    float4 v = *(const float4*)(src + sbase + r * 64 + c4 * 4);
    st[r][c4 * 4 + 0] = v.x; st[r][c4 * 4 + 1] = v.y;
    st[r][c4 * 4 + 2] = v.z; st[r][c4 * 4 + 3] = v.w;
  }
  __syncthreads();
  size_t obase = (size_t)mat * (64 * (size_t)TT) + rt * 64;
#pragma unroll
  for (int i = 0; i < 2; ++i) {
    int idx = tid + i * 256;
    int n = idx >> 3, c = idx & 7;
    uint hw[4];
#pragma unroll
    for (int j = 0; j < 4; ++j)
      hw[j] = (uint)f2bfr(st[c * 8 + 2 * j][n]) | ((uint)f2bfr(st[c * 8 + 2 * j + 1][n]) << 16);
    *(uint4*)(dh + obase + (size_t)n * TT + c * 8) = make_uint4(hw[0], hw[1], hw[2], hw[3]);
  }
}

__global__ __launch_bounds__(256) void k_tsplitW(const float* __restrict__ Wlt,
                                                 ushort* __restrict__ dh,
                                                 ushort* __restrict__ dl) {
  __shared__ float st[64][65];
  int blk = blockIdx.x;
  int l = blk >> 3, rt = blk & 7;
  int tid = threadIdx.x;
  size_t sbase = ((size_t)l * 512 + rt * 64) * 64;
#pragma unroll
  for (int i = 0; i < 4; ++i) {
    int idx = tid + i * 256;
    int r = idx >> 4, c4 = idx & 15;
    float4 v = *(const float4*)(Wlt + sbase + r * 64 + c4 * 4);
    st[r][c4 * 4 + 0] = v.x; st[r][c4 * 4 + 1] = v.y;
    st[r][c4 * 4 + 2] = v.z; st[r][c4 * 4 + 3] = v.w;
  }
  __syncthreads();
  size_t obase = (size_t)l * 64 * 512 + rt * 64;
#pragma unroll
  for (int i = 0; i < 2; ++i) {
    int idx = tid + i * 256;
    int n = idx >> 3, c = idx & 7;
    uint hw[4], lw[4];
#pragma unroll
    for (int j = 0; j < 4; ++j) hw[j] = pack2(st[c * 8 + 2 * j][n], st[c * 8 + 2 * j + 1][n], lw[j]);
    *(uint4*)(dh + obase + (size_t)n * 512 + c * 8) = make_uint4(hw[0], hw[1], hw[2], hw[3]);
    *(uint4*)(dl + obase + (size_t)n * 512 + c * 8) = make_uint4(lw[0], lw[1], lw[2], lw[3]);
  }
}

__global__ __launch_bounds__(256) void k_tsplitSq(const float* __restrict__ src,
                                                  ushort* __restrict__ dh) {
  __shared__ float st[64][65];
  int mat = blockIdx.x;
  int tid = threadIdx.x;
  size_t sbase = (size_t)mat * 4096;
#pragma unroll
  for (int i = 0; i < 4; ++i) {
    int idx = tid + i * 256;
    int r = idx >> 4, c4 = idx & 15;
    float4 v = *(const float4*)(src + sbase + r * 64 + c4 * 4);
    st[r][c4 * 4 + 0] = v.x; st[r][c4 * 4 + 1] = v.y;
    st[r][c4 * 4 + 2] = v.z; st[r][c4 * 4 + 3] = v.w;
  }
  __syncthreads();
#pragma unroll
  for (int i = 0; i < 2; ++i) {
    int idx = tid + i * 256;
    int d = idx >> 3, c = idx & 7;
    uint hw[4];
#pragma unroll
    for (int j = 0; j < 4; ++j)
      hw[j] = (uint)f2bfr(st[c * 8 + 2 * j][d]) | ((uint)f2bfr(st[c * 8 + 2 * j + 1][d]) << 16);
    *(uint4*)(dh + sbase + (size_t)d * 64 + c * 8) = make_uint4(hw[0], hw[1], hw[2], hw[3]);
  }
}

// gconv: 32-t blocks, K3+x in LDS, V-transpose fused (writes xvT directly)
__global__ __launch_bounds__(256) void k_gconv(
    const float* __restrict__ x, const float* __restrict__ K3,
    const float* __restrict__ qwl, const float* __restrict__ qbl,
    const float* __restrict__ kwl, const float* __restrict__ kbl,
    const float* __restrict__ vwl, const float* __restrict__ vbl,
    ushort* __restrict__ xqh, ushort* __restrict__ xkh,
    float* __restrict__ xv, ushort* __restrict__ xvTh) {
  __shared__ float sK3[12288];
  __shared__ float sx[32][64];
  __shared__ ushort sv[32][68];
  int tid = threadIdx.x;
  int m = tid & 63, tg = tid >> 6;
#pragma unroll
  for (int i = 0; i < 12; ++i)
    ((float4*)sK3)[tid + i * 256] = ((const float4*)K3)[tid + i * 256];
  int blk = blockIdx.x;
  int b = blk >> 5, tt = blk & 31;
  size_t xbase = ((size_t)b * TT + tt * 32) * 64;
#pragma unroll
  for (int i = 0; i < 2; ++i) {
    int idx = tid + i * 256;
    int r = idx >> 4, c4 = idx & 15;
    *(float4*)&sx[r][c4 * 4] = *(const float4*)(x + xbase + r * 64 + c4 * 4);
  }
  __syncthreads();
  float A0[8], A1[8], A2[8];
#pragma unroll
  for (int i = 0; i < 8; ++i) { A0[i] = 0.f; A1[i] = 0.f; A2[i] = 0.f; }
  for (int n = 0; n < 64; ++n) {
    float k0 = sK3[n * 192 + m];
    float k1 = sK3[n * 192 + 64 + m];
    float k2 = sK3[n * 192 + 128 + m];
#pragma unroll
    for (int i = 0; i < 8; ++i) {
      float xn = sx[tg + i * 4][n];
      A0[i] = fmaf(xn, k0, A0[i]);
      A1[i] = fmaf(xn, k1, A1[i]);
      A2[i] = fmaf(xn, k2, A2[i]);
    }
  }
  float XM[8];
#pragma unroll
  for (int i = 0; i < 8; ++i) XM[i] = sx[tg + i * 4][m];
  int nrow = tid >> 2, cch = tid & 3;
  for (int hh = 0; hh < HH; ++hh) {
    float q0 = qwl[hh * 3], q1 = qwl[hh * 3 + 1], q2 = qwl[hh * 3 + 2], qb = qbl[hh];
    float k0 = kwl[hh * 3], k1 = kwl[hh * 3 + 1], k2 = kwl[hh * 3 + 2], kb = kbl[hh];
    float v0 = vwl[hh * 3], v1 = vwl[hh * 3 + 1], v2 = vwl[hh * 3 + 2], vb = vbl[hh];
    size_t rowb = ((size_t)b * HH + hh) * TT + tt * 32;
#pragma unroll
    for (int i = 0; i < 8; ++i) {
      int t = tg + i * 4;
      size_t off = (rowb + t) * 64 + m;
      float q = fmaf(q0, A0[i], fmaf(q1, A1[i], fmaf(q2, A2[i], qb + XM[i])));
      xqh[off] = f2bfr(fmaxf(q, 0.f) * (0.015625f * LOG2E));
      float k = fmaf(k0, A0[i], fmaf(k1, A1[i], fmaf(k2, A2[i], kb + XM[i])));
      xkh[off] = f2bfr(fmaxf(k, 0.f));
      float v = fmaf(v0, A0[i], fmaf(v1, A1[i], fmaf(v2, A2[i], vb + XM[i])));
      v = fmaxf(v, 0.f);
      xv[off] = v;
      sv[t][m] = f2bfr(v);
    }
    __syncthreads();
    {
      uint hw[4];
#pragma unroll
      for (int j = 0; j < 4; ++j)
        hw[j] = (uint)sv[cch * 8 + 2 * j][nrow] | ((uint)sv[cch * 8 + 2 * j + 1][nrow] << 16);
      *(uint4*)(xvTh + (((size_t)b * HH + hh) * 64 + nrow) * 1024 + tt * 32 + cch * 8) =
          make_uint4(hw[0], hw[1], hw[2], hw[3]);
    }
    __syncthreads();
  }
}

// ---------- pass A: flash attention, u-range split across 2 half-blocks ----------
__global__ __launch_bounds__(256) void k_attn(
    const ushort* __restrict__ xkh, const ushort* __restrict__ xqh,
    const ushort* __restrict__ xvTh,
    float* __restrict__ auv0, float* __restrict__ auv1,
    float* __restrict__ ls0, float* __restrict__ ls1) {
  __shared__ ushort sQh[4096];
  __shared__ ushort sVh[4096];
  __shared__ ushort sPh[2048];
  int tid = threadIdx.x;
  int lane = tid & 63, w = tid >> 6;
  int l15 = lane & 15, g = lane >> 4;
  int nb = gridDim.x, chunk = nb >> 3, bid = blockIdx.x;
  int blk = (bid & 7) * chunk + (bid >> 3);
  int bh = blk >> 5, t0 = ((blk >> 1) & 15) << 6, half = blk & 1;
  size_t bhTT = (size_t)bh * TT;
  size_t ubase = (size_t)(half << 9);
  int trow = 16 * w + l15, psw = (trow >> 1) & 3;

  stage_async(sQh, xkh + (bhTT + t0) * NN, 64, tid);
  WAIT_VM0();
  BAR();
  short8 fKh[2];
#pragma unroll
  for (int ks = 0; ks < 2; ++ks) fKh[ks] = frag(sQh, trow, g + 4 * ks);
  WAIT_LGKM0();
  BAR();
  stage_q32(sQh, xqh + (bhTT + ubase) * NN, tid);
  stage_v32(sVh, xvTh + bhTT * NN + ubase, tid);
  stage_q32(sQh + 2048, xqh + (bhTT + ubase + 32) * NN, tid);
  stage_v32(sVh + 2048, xvTh + bhTT * NN + ubase + 32, tid);

  float lsum = 0.f;
  f32x4 O[4];
#pragma unroll
  for (int ct = 0; ct < 4; ++ct)
#pragma unroll
    for (int r = 0; r < 4; ++r) O[ct][r] = 0.f;

  for (int ut = 0; ut < 16; ++ut) {
    int cur = ut & 1;
    if (ut < 15) WAIT_VM2(); else WAIT_VM0();
    BAR();
    const ushort* cQh = sQh + cur * 2048;
    const ushort* cVh = sVh + cur * 2048;

    __builtin_amdgcn_s_setprio(1);
    f32x4 S[2];
#pragma unroll
    for (int rt = 0; rt < 2; ++rt) {
      f32x4 a = {0.f, 0.f, 0.f, 0.f};
#pragma unroll
      for (int ks = 0; ks < 2; ++ks)
        a = MFMA16(frag(cQh, 16 * rt + l15, g + 4 * ks), fKh[ks], a);
      S[rt] = a;
    }
    __builtin_amdgcn_s_setprio(0);

    uint2 ph[2];
#pragma unroll
    for (int rt = 0; rt < 2; ++rt) {
      float p0 = exp2_(S[rt][0]), p1 = exp2_(S[rt][1]);
      float p2 = exp2_(S[rt][2]), p3 = exp2_(S[rt][3]);
      lsum += (p0 + p1) + (p2 + p3);
      ph[rt].x = pack2rhu(p0, p1);
      ph[rt].y = pack2rhu(p2, p3);
    }
#pragma unroll
    for (int rt = 0; rt < 2; ++rt) {
      int ch = 2 * rt + (g >> 1);
      int off = trow * 32 + ((ch ^ psw) << 3) + ((g & 1) << 2);
      *(uint2*)(sPh + off) = ph[rt];
    }
    WAIT_LGKM0();
    __builtin_amdgcn_sched_barrier(0);
    __builtin_amdgcn_s_setprio(1);
    {
      short8 aPh = frag32(sPh, trow, g);
#pragma unroll
      for (int ct = 0; ct < 4; ++ct)
        O[ct] = MFMA16(aPh, frag32(cVh, 16 * ct + l15, g), O[ct]);
    }
    __builtin_amdgcn_s_setprio(0);
    WAIT_LGKM0();
    BAR();
    if (ut < 14) {
      int tn = ut + 2;
      stage_q32(sQh + cur * 2048, xqh + (bhTT + ubase + tn * 32) * NN, tid);
      stage_v32(sVh + cur * 2048, xvTh + bhTT * NN + ubase + tn * 32, tid);
    }
  }
  lsum += __shfl_xor(lsum, 16, 64);
  lsum += __shfl_xor(lsum, 32, 64);
  float* A = half ? auv1 : auv0;
  float* L = half ? ls1 : ls0;
#pragma unroll
  for (int r = 0; r < 4; ++r) {
    size_t row = (bhTT + t0 + 16 * w + 4 * g + r) * NN;
#pragma unroll
    for (int ct = 0; ct < 4; ++ct) A[row + 16 * ct + l15] = O[ct][r];
  }
  if (g == 0) L[bhTT + t0 + trow] = lsum;
}

// ---------- pass B fused with gate; normalization folded in ----------
__global__ __launch_bounds__(256, 4) void k_h1g(
    const ushort* __restrict__ xkh, const ushort* __restrict__ xqh,
    const ushort* __restrict__ w1Th,
    const float* __restrict__ ls0, const float* __restrict__ ls1,
    const float* __restrict__ b1, const ushort* __restrict__ w2Th,
    const float* __restrict__ b2l, const float* __restrict__ W3l,
    const float* __restrict__ b3l,
    const float* __restrict__ auv0, const float* __restrict__ auv1,
    const float* __restrict__ xv, ushort* __restrict__ hoh,
    ushort* __restrict__ hol) {
  __shared__ ushort sKh[4096];
  __shared__ ushort sWh[4096];
  __shared__ ushort sPh[2048];
  __shared__ ushort sW2[4096];
  __shared__ float sL[1024];
  __shared__ float sIl[1024];
  int tid = threadIdx.x;
  int lane = tid & 63, w = tid >> 6;
  int l15 = lane & 15, g = lane >> 4;
  int nb = gridDim.x, chunk = nb >> 3, bid = blockIdx.x;
  int blk = (bid & 7) * chunk + (bid >> 3);
  int bh = blk >> 4, h = bh & (HH - 1), a0 = (blk & 15) << 6;
  size_t bhTT = (size_t)bh * TT;
  size_t wbase = (size_t)h * NN * TT;
  int arow = 16 * w + l15, psw = (arow >> 1) & 3;

  stage_async(sKh, xqh + (bhTT + a0) * NN, 64, tid);
  stage_async(sW2, w2Th + (size_t)h * 4096, 64, tid);
  WAIT_VM0();
  BAR();
  short8 fQh[2];
#pragma unroll
  for (int ks = 0; ks < 2; ++ks) fQh[ks] = frag(sKh, arow, g + 4 * ks);
#pragma unroll
  for (int i = 0; i < 4; ++i) {
    int idx = tid + i * 256;
    float l = ls0[bhTT + idx] + ls1[bhTT + idx];
    sL[idx] = log2_(l);
    sIl[idx] = 1.0f / l;
  }
  WAIT_LGKM0();
  BAR();
  stage_q32(sKh, xkh + bhTT * NN, tid);
  stage_v32(sWh, w1Th + wbase, tid);
  stage_q32(sKh + 2048, xkh + (bhTT + 32) * NN, tid);
  stage_v32(sWh + 2048, w1Th + wbase + 32, tid);

  f32x4 acc[4];
#pragma unroll
  for (int ct = 0; ct < 4; ++ct)
#pragma unroll
    for (int r = 0; r < 4; ++r) acc[ct][r] = 0.f;

  for (int tt = 0; tt < 32; ++tt) {
    int cur = tt & 1;
    if (tt < 31) WAIT_VM2(); else WAIT_VM0();
    BAR();
    const ushort* cKh = sKh + cur * 2048;
    const ushort* cWh = sWh + cur * 2048;

    __builtin_amdgcn_s_setprio(1);
    f32x4 S[2];
#pragma unroll
    for (int rt = 0; rt < 2; ++rt) {
      f32x4 a = {0.f, 0.f, 0.f, 0.f};
#pragma unroll
      for (int ks = 0; ks < 2; ++ks)
        a = MFMA16(frag(cKh, 16 * rt + l15, g + 4 * ks), fQh[ks], a);
      S[rt] = a;
    }
    __builtin_amdgcn_s_setprio(0);

    uint2 ph[2];
#pragma unroll
    for (int rt = 0; rt < 2; ++rt) {
      f32x4 lv = *(const f32x4*)(sL + tt * 32 + 16 * rt + 4 * g);
      float p0 = exp2_(S[rt][0] - lv[0]);
      float p1 = exp2_(S[rt][1] - lv[1]);
      float p2 = exp2_(S[rt][2] - lv[2]);
      float p3 = exp2_(S[rt][3] - lv[3]);
      ph[rt].x = pack2rhu(p0, p1);
      ph[rt].y = pack2rhu(p2, p3);
    }
#pragma unroll
    for (int rt = 0; rt < 2; ++rt) {
      int ch = 2 * rt + (g >> 1);
      int off = arow * 32 + ((ch ^ psw) << 3) + ((g & 1) << 2);
      *(uint2*)(sPh + off) = ph[rt];
    }
    WAIT_LGKM0();
    __builtin_amdgcn_sched_barrier(0);
    __builtin_amdgcn_s_setprio(1);
    {
      short8 aPh = frag32(sPh, arow, g);
#pragma unroll
      for (int ct = 0; ct < 4; ++ct)
        acc[ct] = MFMA16(aPh, frag32(cWh, 16 * ct + l15, g), acc[ct]);
    }
    __builtin_amdgcn_s_setprio(0);
    WAIT_LGKM0();
    BAR();
    if (tt < 30) {
      int tn = tt + 2;
      stage_q32(sKh + cur * 2048, xkh + (bhTT + tn * 32) * NN, tid);
      stage_v32(sWh + cur * 2048, w1Th + wbase + tn * 32, tid);
    }
  }
  // ---- epilogue: gate fused ----
#pragma unroll
  for (int ct = 0; ct < 4; ++ct) {
    float bb = b1[h * 64 + 16 * ct + l15];
    int cch = 2 * ct + (l15 >> 3), cin = l15 & 7;
#pragma unroll
    for (int r = 0; r < 4; ++r) {
      int row = 16 * w + 4 * g + r;
      float hv = fmaxf(acc[ct][r] + bb, 0.f);
      sWh[row * 64 + ((cch ^ (row & 7)) << 3) + cin] = f2bfr(hv);
    }
  }
  WAIT_LGKM0();
  BAR();
  f32x4 acc2[4];
#pragma unroll
  for (int rt = 0; rt < 4; ++rt)
#pragma unroll
    for (int r = 0; r < 4; ++r) acc2[rt][r] = 0.f;
#pragma unroll
  for (int ks = 0; ks < 2; ++ks) {
    short8 bB = frag(sW2, 16 * w + l15, g + 4 * ks);
#pragma unroll
    for (int rt = 0; rt < 4; ++rt)
      acc2[rt] = MFMA16(frag(sWh, 16 * rt + l15, g + 4 * ks), bB, acc2[rt]);
  }
  int col = 16 * w + l15;
  float b2c = b2l[h * 64 + col];
  float w30 = W3l[h * 128 + col * 2 + 0];
  float w31 = W3l[h * 128 + col * 2 + 1];
  float* sredf = sL;
  float* sgf = sL + 512;
#pragma unroll
  for (int rt = 0; rt < 4; ++rt)
#pragma unroll
    for (int r = 0; r < 4; ++r) {
      float v = fmaxf(acc2[rt][r] + b2c, 0.f);
      float z0 = v * w30, z1 = v * w31;
#pragma unroll
      for (int mm = 1; mm < 16; mm <<= 1) {
        z0 += __shfl_xor(z0, mm, 64);
        z1 += __shfl_xor(z1, mm, 64);
      }
      if (l15 == 0) {
        int row = 16 * rt + 4 * g + r;
        sredf[row * 4 + w] = z0;
        sredf[256 + row * 4 + w] = z1;
      }
    }
  __syncthreads();
  if (tid < 64) {
    float z0 = sredf[tid * 4] + sredf[tid * 4 + 1] + sredf[tid * 4 + 2] +
               sredf[tid * 4 + 3] + b3l[h * 2 + 0];
    float z1 = sredf[256 + tid * 4] + sredf[256 + tid * 4 + 1] +
               sredf[256 + tid * 4 + 2] + sredf[256 + tid * 4 + 3] + b3l[h * 2 + 1];
    float g0 = 1.0f / (1.0f + __expf(z1 - z0));
    sgf[tid * 2] = g0 * sIl[a0 + tid];
    sgf[tid * 2 + 1] = 1.0f - g0;
  }
  __syncthreads();
#pragma unroll
  for (int rr = 0; rr < 16; ++rr) {
    int row = 16 * w + rr;
    size_t off = (bhTT + a0 + row) * 64 + lane;
    float o = auv0[off] + auv1[off];
    float ho = sgf[row * 2] * o + sgf[row * 2 + 1] * xv[off];
    ushort hb, lb;
    split1(ho, hb, lb);
    hoh[off] = hb;
    hol[off] = lb;
  }
}

// ---------- merge fused with ffn; 16-row t-tiles (grid = bc*64) ----------
__global__ __launch_bounds__(256) void k_mrgf(
    float* __restrict__ x, const ushort* __restrict__ hoh,
    const ushort* __restrict__ hol, const ushort* __restrict__ wth,
    const ushort* __restrict__ wtl, const float* __restrict__ g1l,
    const float* __restrict__ b1l, const float* __restrict__ sclb_l,
    const ushort* __restrict__ k3sTh, const ushort* __restrict__ elWTh,
    const float* __restrict__ elbl, const float* __restrict__ g2l,
    const float* __restrict__ b2l) {
  __shared__ ushort sAh[2][1024], sAl[2][1024], sBh[2][4096], sBl[2][4096];
  __shared__ float sred[2][16][4];
  __shared__ float sfin[16][2];
  int tid = threadIdx.x;
  int lane = tid & 63, w = tid >> 6;
  int l15 = lane & 15, g = lane >> 4;
  int blk = blockIdx.x;
  int b = blk >> 6, t0 = (blk & 63) << 4;

  {
    size_t ab0 = (((size_t)b * HH + 0) * TT + t0) * NN;
    size_t ab1 = (((size_t)b * HH + 1) * TT + t0) * NN;
    stage_a16pair(sAh[0], sAl[0], hoh + ab0, hol + ab0, tid);
    stage_async(sBh[0], wth, 512, tid);
    stage_async(sBl[0], wtl, 512, tid);
    stage_a16pair(sAh[1], sAl[1], hoh + ab1, hol + ab1, tid);
    stage_async(sBh[1], wth + 64, 512, tid);
    stage_async(sBl[1], wtl + 64, 512, tid);
  }

  f32x4 acc;
#pragma unroll
  for (int r = 0; r < 4; ++r) acc[r] = 0.f;

  for (int h = 0; h < 8; ++h) {
    int cur = h & 1;
    if (h < 7) WAIT_VM5(); else WAIT_VM0();
    BAR();
    __builtin_amdgcn_s_setprio(1);
#pragma unroll
    for (int ks = 0; ks < 2; ++ks) {
      short8 bBh = frag(sBh[cur], 16 * w + l15, g + 4 * ks);
      short8 bBl = frag(sBl[cur], 16 * w + l15, g + 4 * ks);
      short8 aAh = frag(sAh[cur], l15, g + 4 * ks);
      short8 aAl = frag(sAl[cur], l15, g + 4 * ks);
      acc = MFMA16(aAh, bBh, acc);
      acc = MFMA16(aAh, bBl, acc);
      acc = MFMA16(aAl, bBh, acc);
    }
    __builtin_amdgcn_s_setprio(0);
    WAIT_LGKM0();
    BAR();
    if (h < 6) {
      int hn = h + 2;
      size_t ab = (((size_t)b * HH + hn) * TT + t0) * NN;
      stage_a16pair(sAh[cur], sAl[cur], hoh + ab, hol + ab, tid);
      stage_async(sBh[cur], wth + hn * 64, 512, tid);
      stage_async(sBl[cur], wtl + hn * 64, 512, tid);
    }
  }
  // ---- epilogue: out1 = LN1(x + acc), ffn, x = LN2 ----
  stage_async(sBh[0], k3sTh, 64, tid);
  stage_async(sBl[0], elWTh, 64, tid);
  int mcol = 16 * w + l15;
  float vv[4];
#pragma unroll
  for (int r = 0; r < 4; ++r) {
    int row = 4 * g + r;
    vv[r] = acc[r] + x[((size_t)b * TT + t0 + row) * 64 + mcol];
  }
#pragma unroll
  for (int r = 0; r < 4; ++r) {
    float s1 = vv[r], s2 = vv[r] * vv[r];
#pragma unroll
    for (int mm = 1; mm < 16; mm <<= 1) {
      s1 += __shfl_xor(s1, mm, 64);
      s2 += __shfl_xor(s2, mm, 64);
    }
    if (l15 == 0) {
      int row = 4 * g + r;
      sred[0][row][w] = s1;
      sred[1][row][w] = s2;
    }
  }
  __syncthreads();
  if (tid < 16) {
    float a1 = sred[0][tid][0] + sred[0][tid][1] + sred[0][tid][2] + sred[0][tid][3];
    float a2 = sred[1][tid][0] + sred[1][tid][1] + sred[1][tid][2] + sred[1][tid][3];
    float mean = a1 * (1.0f / 64.0f);
    float var = a2 * (1.0f / 64.0f) - mean * mean;
    sfin[tid][0] = mean;
    sfin[tid][1] = rsqrtf(var + EPSV);
  }
  __syncthreads();
  float gg = g1l[mcol], bb1 = b1l[mcol];
  float val[4];
  ushort* sH = sAh[0];
  ushort* sHl = sAl[0];
  int cch = mcol >> 3, cin = mcol & 7;
#pragma unroll
  for (int r = 0; r < 4; ++r) {
    int row = 4 * g + r;
    float v = (vv[r] - sfin[row][0]) * sfin[row][1] * gg + bb1;
    val[r] = v;
    ushort hb, lb;
    split1(v, hb, lb);
    int a = row * 64 + ((cch ^ (row & 7)) << 3) + cin;
    sH[a] = hb;
    sHl[a] = lb;
  }
  WAIT_VM0();
  WAIT_LGKM0();
  BAR();
  f32x4 acc3;
#pragma unroll
  for (int r = 0; r < 4; ++r) acc3[r] = 0.f;
#pragma unroll
  for (int ks = 0; ks < 2; ++ks) {
    short8 bB = frag(sBh[0], mcol, g + 4 * ks);
    acc3 = MFMA16(frag(sH, l15, g + 4 * ks), bB, acc3);
    acc3 = MFMA16(frag(sHl, l15, g + 4 * ks), bB, acc3);
  }
  WAIT_LGKM0();
  BAR();
  float sclb = sclb_l[0];
#pragma unroll
  for (int r = 0; r < 4; ++r) {
    int row = 4 * g + r;
    float f1 = fmaxf(acc3[r] + sclb + val[r], 0.f);
    ushort hb, lb;
    split1(f1, hb, lb);
    int a = row * 64 + ((cch ^ (row & 7)) << 3) + cin;
    sH[a] = hb;
    sHl[a] = lb;
  }
  WAIT_LGKM0();
  BAR();
  f32x4 acc4;
#pragma unroll
  for (int r = 0; r < 4; ++r) acc4[r] = 0.f;
#pragma unroll
  for (int ks = 0; ks < 2; ++ks) {
    short8 bB = frag(sBl[0], mcol, g + 4 * ks);
    acc4 = MFMA16(frag(sH, l15, g + 4 * ks), bB, acc4);
    acc4 = MFMA16(frag(sHl, l15, g + 4 * ks), bB, acc4);
  }
  float elb = elbl[mcol];
#pragma unroll
  for (int r = 0; r < 4; ++r) {
    float v = val[r] + acc4[r] + elb;
    vv[r] = v;
    float s1 = v, s2 = v * v;
#pragma unroll
    for (int mm = 1; mm < 16; mm <<= 1) {
      s1 += __shfl_xor(s1, mm, 64);
      s2 += __shfl_xor(s2, mm, 64);
    }
    if (l15 == 0) {
      int row = 4 * g + r;
      sred[0][row][w] = s1;
      sred[1][row][w] = s2;
    }
  }
  __syncthreads();
  if (tid < 16) {
    float a1 = sred[0][tid][0] + sred[0][tid][1] + sred[0][tid][2] + sred[0][tid][3];
    float a2 = sred[1][tid][0] + sred[1][tid][1] + sred[1][tid][2] + sred[1][tid][3];
    float mean = a1 * (1.0f / 64.0f);
    float var = a2 * (1.0f / 64.0f) - mean * mean;
    sfin[tid][0] = mean;
    sfin[tid][1] = rsqrtf(var + EPSV);
  }
  __syncthreads();
  float g2 = g2l[mcol], bb2 = b2l[mcol];
#pragma unroll
  for (int r = 0; r < 4; ++r) {
    int row = 4 * g + r;
    x[((size_t)b * TT + t0 + row) * 64 + mcol] =
        (vv[r] - sfin[row][0]) * sfin[row][1] * g2 + bb2;
  }
}

__global__ __launch_bounds__(256) void k_final(
    const float* __restrict__ x, const float* __restrict__ fW1,
    const float* __restrict__ fb1, const float* __restrict__ fW2,
    const float* __restrict__ fb2, float* __restrict__ out) {
  __shared__ float pl[4][64];
  int tid = threadIdx.x;
  int lane = tid & 63, w = tid >> 6;
  size_t b = blockIdx.x;
  float s = 0.f;
  for (int t = 256 * w; t < 256 * w + 256; ++t) s += x[(b * TT + t) * 64 + lane];
  pl[w][lane] = s;
  __syncthreads();
  if (tid < 64) pl[0][tid] = (pl[0][tid] + pl[1][tid] + pl[2][tid] + pl[3][tid]) * (1.0f / TT);
  __syncthreads();
  if (tid < 64) {
    float hv = 0.f;
    if (lane < 32) {
      hv = fb1[lane];
#pragma unroll 8
      for (int n = 0; n < 64; ++n) hv = fmaf(pl[0][n], fW1[n * 32 + lane], hv);
      hv = fmaxf(hv, 0.f) * fW2[lane];
    }
#pragma unroll
    for (int m = 1; m < 64; m <<= 1) hv += __shfl_xor(hv, m, 64);
    if (lane == 0) out[b] = hv + fb2[0];
  }
}

extern "C" void kernel_launch(void* const* d_in, const int* in_sizes, int n_in,
                              void* d_out, int out_size, void* d_ws, size_t ws_size,
                              hipStream_t stream) {
  const float* inputs = (const float*)d_in[0];
  const float* pos_emb = (const float*)d_in[1];
  const float* K3 = (const float*)d_in[2];
  const float* qw = (const float*)d_in[3];
  const float* qb = (const float*)d_in[4];
  const float* kw = (const float*)d_in[5];
  const float* kb = (const float*)d_in[6];
  const float* vw = (const float*)d_in[7];
  const float* vb = (const float*)d_in[8];
  const float* tqW1 = (const float*)d_in[9];
  const float* tqb1 = (const float*)d_in[10];
  const float* tqW2 = (const float*)d_in[11];
  const float* tqb2 = (const float*)d_in[12];
  const float* tqW3 = (const float*)d_in[13];
  const float* tqb3 = (const float*)d_in[14];
  const float* Wlt = (const float*)d_in[15];
  const float* ln1g = (const float*)d_in[16];
  const float* ln1b = (const float*)d_in[17];
  const float* ln2g = (const float*)d_in[18];
  const float* ln2b = (const float*)d_in[19];
  const float* sclw = (const float*)d_in[20];
  const float* sclb = (const float*)d_in[21];
  const float* elW = (const float*)d_in[22];
  const float* elb = (const float*)d_in[23];
  const float* fW1 = (const float*)d_in[24];
  const float* fb1 = (const float*)d_in[25];
  const float* fW2 = (const float*)d_in[26];
  const float* fb2 = (const float*)d_in[27];
  float* out = (float*)d_out;
  float* ws_f = (float*)d_ws;

  const size_t TN = (size_t)TT * NN;
  const size_t HTN = (size_t)HH * TT * NN;
  const size_t W1T_ELEMS = (size_t)LL * HH * NN * TT;
  const size_t WLT_ELEMS = (size_t)LL * 64 * 512;

  ushort* k3sTh = (ushort*)ws_f;
  ushort* w1Th = k3sTh + (size_t)LL * 4096;
  ushort* wth = w1Th + W1T_ELEMS;
  ushort* wtl = wth + WLT_ELEMS;
  ushort* w2Th = wtl + WLT_ELEMS;
  ushort* elWTh = w2Th + (size_t)LL * HH * 4096;
  size_t base_ush = (size_t)LL * 4096 + W1T_ELEMS + 2 * WLT_ELEMS +
                    (size_t)LL * HH * 4096 + (size_t)LL * 4096;
  const size_t base = (base_ush + 1) / 2;

  for (int l = 0; l < LL; ++l)
    k_k3s<<<16, 256, 0, stream>>>(K3, sclw + l * KSS, k3sTh + (size_t)l * 4096);
  k_tsplit<<<LL * HH * 16, 256, 0, stream>>>(tqW1, w1Th);
  k_tsplitW<<<LL * 8, 256, 0, stream>>>(Wlt, wth, wtl);
  k_tsplitSq<<<LL * HH, 256, 0, stream>>>(tqW2, w2Th);
  k_tsplitSq<<<LL, 256, 0, stream>>>(elW, elWTh);

  const size_t per_b = TN + 3 * HTN + 2 * (size_t)HH * TT + (5 * HTN) / 2;
  size_t avail = ws_size / sizeof(float);
  avail = (avail > base) ? avail - base : 0;
  int Bc = (int)(avail / per_b);
  if (Bc > BB) Bc = BB;
  if (Bc < 1) Bc = 1;

  for (int b0 = 0; b0 < BB; b0 += Bc) {
    int bc = (BB - b0 < Bc) ? (BB - b0) : Bc;
    float* x = ws_f + base;
    float* xv = x + (size_t)bc * TN;
    float* auv0 = xv + (size_t)bc * HTN;
    float* auv1 = auv0 + (size_t)bc * HTN;
    float* ls0 = auv1 + (size_t)bc * HTN;
    float* ls1 = ls0 + (size_t)bc * HH * TT;
    ushort* xqh = (ushort*)(ls1 + (size_t)bc * HH * TT);
    ushort* xkh = xqh + (size_t)bc * HTN;
    ushort* xvTh = xkh + (size_t)bc * HTN;
    ushort* hoh = xvTh + (size_t)bc * HTN;
    ushort* hol = hoh + (size_t)bc * HTN;

    int total = bc * (int)TN;
    k_addpos<<<(total + 255) / 256, 256, 0, stream>>>(inputs + (size_t)b0 * TN, pos_emb, x,
                                                      total);
    for (int l = 0; l < LL; ++l) {
      k_gconv<<<bc * 32, 256, 0, stream>>>(x, K3, qw + l * HH * KSS, qb + l * HH,
                                           kw + l * HH * KSS, kb + l * HH,
                                           vw + l * HH * KSS, vb + l * HH,
                                           xqh, xkh, xv, xvTh);
      k_attn<<<bc * HH * 32, 256, 0, stream>>>(xkh, xqh, xvTh, auv0, auv1, ls0, ls1);
      k_h1g<<<bc * HH * 16, 256, 0, stream>>>(
          xkh, xqh, w1Th + (size_t)l * HH * NN * TT, ls0, ls1,
          tqb1 + l * HH * DD1, w2Th + (size_t)l * HH * 4096, tqb2 + l * HH * DD1,
          tqW3 + (size_t)l * HH * DD1 * 2, tqb3 + l * HH * 2, auv0, auv1, xv,
          hoh, hol);
      k_mrgf<<<bc * 64, 256, 0, stream>>>(
          x, hoh, hol, wth + (size_t)l * 64 * 512, wtl + (size_t)l * 64 * 512,
          ln1g + l * NN, ln1b + l * NN, sclb + l, k3sTh + (size_t)l * 4096,
          elWTh + (size_t)l * 4096, elb + l * NN, ln2g + l * NN, ln2b + l * NN);
    }
    k_final<<<bc, 256, 0, stream>>>(x, fW1, fb1, fW2, fb2, out + b0);
  }
}